// Round 6
// baseline (2313.383 us; speedup 1.0000x reference)
//
#include <hip/hip_runtime.h>

#define N_ATOMS 100000
#define E_ATOMS 200000
#define N_AMINO 10240
#define E_AMINO 20480
#define NGRAPH 512
#define DIN0 40
#define D_E 11
#define HD 20
#define D_AA 8
#define HA 128
#define KS 3
#define TL 7
#define F1 256
#define F2 128
#define F3 64

typedef unsigned short u16;
typedef unsigned int u32;

__device__ __forceinline__ float b2f(u16 u) {
    union { u32 i; float f; } v; v.i = ((u32)u) << 16; return v.f;
}
__device__ __forceinline__ u16 f2b(float f) {
    union { float f; u32 i; } v; v.f = f;
    u32 x = v.i;
    return (u16)((x + (((x >> 16) & 1u) + 0x7fffu)) >> 16);
}

// ---------------------------------------------------------------------------
// CSR build helpers
__global__ __launch_bounds__(256) void k_zero_i(int* __restrict__ p, int n) {
    int t = blockIdx.x * 256 + threadIdx.x;
    if (t < n) p[t] = 0;
}
__global__ __launch_bounds__(256) void k_count(const int* __restrict__ dst,
                                               int* __restrict__ cnt, int E) {
    int e = blockIdx.x * 256 + threadIdx.x;
    if (e < E) atomicAdd(cnt + dst[e], 1);
}
// Exclusive scan of cnt[0..n) -> off[0..n]; single block, 256 threads.
__global__ __launch_bounds__(256) void k_scan(const int* __restrict__ cnt,
                                              int* __restrict__ off, int n) {
    __shared__ int wsum[4];
    __shared__ int carry;
    int tx = threadIdx.x, lane = tx & 63, w = tx >> 6;
    if (tx == 0) carry = 0;
    __syncthreads();
    for (int base = 0; base < n; base += 256) {
        int v = (base + tx < n) ? cnt[base + tx] : 0;
        int s = v;
#pragma unroll
        for (int d = 1; d < 64; d <<= 1) {
            int u = __shfl_up(s, d, 64);
            if (lane >= d) s += u;
        }
        if (lane == 63) wsum[w] = s;
        __syncthreads();
        int wo = 0;
        for (int i = 0; i < w; ++i) wo += wsum[i];
        int excl = carry + wo + s - v;
        if (base + tx < n) off[base + tx] = excl;
        __syncthreads();
        if (tx == 0) carry += wsum[0] + wsum[1] + wsum[2] + wsum[3];
        __syncthreads();
    }
    if (tx == 0) off[n] = carry;
}
__global__ __launch_bounds__(256) void k_cpy(const int* __restrict__ a,
                                             int* __restrict__ b, int n) {
    int t = blockIdx.x * 256 + threadIdx.x;
    if (t < n) b[t] = a[t];
}
__global__ __launch_bounds__(256) void k_fill(const int* __restrict__ dst,
                                              int* __restrict__ cur,
                                              int* __restrict__ eid, int E) {
    int e = blockIdx.x * 256 + threadIdx.x;
    if (e >= E) return;
    int p = atomicAdd(cur + dst[e], 1);
    eid[p] = e;
}

// ---------------------------------------------------------------------------
// M[i*240 + k*20+o] = nn_w[k, i*20+o]; M[i*240+220+o] = nn_b[i*20+o]
__global__ __launch_bounds__(256) void build_M(
    const float* __restrict__ w1, const float* __restrict__ b1,
    const float* __restrict__ w2, const float* __restrict__ b2,
    const float* __restrict__ w3, const float* __restrict__ b3,
    float* __restrict__ M1, float* __restrict__ M2, float* __restrict__ M3) {
    int t = blockIdx.x * 256 + threadIdx.x;
    if (t < 9600) {
        int i = t / 240, c = t % 240;
        M1[t] = (c < 220) ? w1[(c / 20) * 800 + i * 20 + (c % 20)] : b1[i * 20 + (c - 220)];
    } else if (t < 14400) {
        int tt = t - 9600, i = tt / 240, c = tt % 240;
        M2[tt] = (c < 220) ? w2[(c / 20) * 400 + i * 20 + (c % 20)] : b2[i * 20 + (c - 220)];
    } else if (t < 19200) {
        int tt = t - 14400, i = tt / 240, c = tt % 240;
        M3[tt] = (c < 220) ? w3[(c / 20) * 400 + i * 20 + (c % 20)] : b3[i * 20 + (c - 220)];
    }
}

// ---------------------------------------------------------------------------
// CSR-gather NNConv, fused root+bias+relu. One thread per node.
// out_n[o] = relu( sum_{e into n} sum_i x[src,i]*(b_nn[i,o]+sum_k ea[e,k]*w_nn[k,i,o])
//                  + x[n,:]@root[:,o] + bias[o] )
// FUSE: scatter into aa[lbl[n]*28+o] instead of storing h.
template <int DIN, bool RAW, bool FUSE>
__global__ __launch_bounds__(256) void k_nnconv(
    const void* __restrict__ xin, const float* __restrict__ ea,
    const int* __restrict__ esrc, const int* __restrict__ off,
    const int* __restrict__ eid, const float* __restrict__ M,
    const float* __restrict__ root, const float* __restrict__ bias,
    u16* __restrict__ hout, float* __restrict__ aa, const int* __restrict__ lbl) {
    int n = blockIdx.x * 256 + threadIdx.x;
    if (n >= N_ATOMS) return;
    float acc[HD];
#pragma unroll
    for (int o = 0; o < HD; ++o) acc[o] = 0.f;
    int j1 = off[n + 1];
    for (int j = off[n]; j < j1; ++j) {
        int e = eid[j], s = esrc[e];
        float ev[D_E];
#pragma unroll
        for (int k = 0; k < D_E; ++k) ev[k] = ea[e * D_E + k];
        const u16* xb = (const u16*)xin + (size_t)s * DIN;
        const float* xf = (const float*)xin + (size_t)s * DIN;
        for (int i = 0; i < DIN; ++i) {
            float xv = RAW ? xf[i] : b2f(xb[i]);
            const float* mi = M + i * 240;
#pragma unroll
            for (int o = 0; o < HD; ++o) {
                float we = mi[220 + o];
#pragma unroll
                for (int k = 0; k < D_E; ++k) we += ev[k] * mi[k * HD + o];
                acc[o] += xv * we;
            }
        }
    }
    const u16* sb = (const u16*)xin + (size_t)n * DIN;
    const float* sf = (const float*)xin + (size_t)n * DIN;
    float xs[DIN];
#pragma unroll
    for (int i = 0; i < DIN; ++i) xs[i] = RAW ? sf[i] : b2f(sb[i]);
#pragma unroll
    for (int o = 0; o < HD; ++o) {
        float r = bias[o];
#pragma unroll
        for (int i = 0; i < DIN; ++i) r += xs[i] * root[i * HD + o];
        float v = fmaxf(acc[o] + r, 0.f);
        if (FUSE) atomicAdd(aa + lbl[n] * 28 + o, v);
        else hout[n * HD + o] = f2b(v);
    }
}

// ---------------------------------------------------------------------------
// Amino init: zero aa sum-columns, fill features; zero g.
__global__ __launch_bounds__(256) void aa_init(
    const float* __restrict__ af, float* __restrict__ aa, float* __restrict__ g) {
    int t = blockIdx.x * 256 + threadIdx.x;
    if (t < N_AMINO) {
        float* r = aa + t * 28;
#pragma unroll
        for (int o = 0; o < HD; ++o) r[o] = 0.f;
#pragma unroll
        for (int j = 0; j < D_AA; ++j) r[HD + j] = af[t * D_AA + j];
    }
    if (t < NGRAPH * HA) g[t] = 0.f;
}

// Edge norm from CSR in-degrees: nrm[e] = dinv[src]*dinv[dst].
__global__ __launch_bounds__(256) void k_anorm(
    const int* __restrict__ aei, const int* __restrict__ aoff,
    float* __restrict__ nrm) {
    int e = blockIdx.x * 256 + threadIdx.x;
    if (e >= E_AMINO) return;
    int s = aei[e], d = aei[E_AMINO + e];
    int ds = aoff[s + 1] - aoff[s], dd = aoff[d + 1] - aoff[d];
    float a = ds > 0 ? rsqrtf((float)ds) : 0.f;
    float b = dd > 0 ? rsqrtf((float)dd) : 0.f;
    nrm[e] = a * b;
}

// ---------------------------------------------------------------------------
// ARMA (k-sequential), fp32 H/O. One thread per (n, 8 cols).
__global__ __launch_bounds__(256) void arma_gemm28(
    const float* __restrict__ A, const float* __restrict__ W,
    float* __restrict__ H) {
    int t = blockIdx.x * 256 + threadIdx.x;
    if (t >= N_AMINO * 16) return;
    int n = t >> 4, c0 = (t & 15) * 8;
    float a[28];
    const float* ar = A + n * 28;
#pragma unroll
    for (int i = 0; i < 28; ++i) a[i] = ar[i];
    float acc[8];
#pragma unroll
    for (int j = 0; j < 8; ++j) acc[j] = 0.f;
    for (int f = 0; f < 28; ++f) {
        const float* wr = W + f * HA + c0;
        float4 w0 = *(const float4*)wr, w1 = *(const float4*)(wr + 4);
        float av = a[f];
        acc[0] += av * w0.x; acc[1] += av * w0.y; acc[2] += av * w0.z; acc[3] += av * w0.w;
        acc[4] += av * w1.x; acc[5] += av * w1.y; acc[6] += av * w1.z; acc[7] += av * w1.w;
    }
    float* hp = H + n * HA + c0;
    *(float4*)hp       = make_float4(acc[0], acc[1], acc[2], acc[3]);
    *(float4*)(hp + 4) = make_float4(acc[4], acc[5], acc[6], acc[7]);
}

__global__ __launch_bounds__(256) void arma_gemm128(
    const float* __restrict__ A, const float* __restrict__ W,
    float* __restrict__ H) {
    int t = blockIdx.x * 256 + threadIdx.x;
    if (t >= N_AMINO * 16) return;
    int n = t >> 4, c0 = (t & 15) * 8;
    const float* ar = A + n * HA;
    float acc[8];
#pragma unroll
    for (int j = 0; j < 8; ++j) acc[j] = 0.f;
    for (int f = 0; f < HA; ++f) {
        float av = ar[f];
        const float* wr = W + f * HA + c0;
        float4 w0 = *(const float4*)wr, w1 = *(const float4*)(wr + 4);
        acc[0] += av * w0.x; acc[1] += av * w0.y; acc[2] += av * w0.z; acc[3] += av * w0.w;
        acc[4] += av * w1.x; acc[5] += av * w1.y; acc[6] += av * w1.z; acc[7] += av * w1.w;
    }
    float* hp = H + n * HA + c0;
    *(float4*)hp       = make_float4(acc[0], acc[1], acc[2], acc[3]);
    *(float4*)(hp + 4) = make_float4(acc[4], acc[5], acc[6], acc[7]);
}

// O[n,:] = relu( sum_{e into n} nrm[e]*H[src] + aa[n,:]@rootW + bias ).
// If bat != null (last layer): g[bat[n],:] += O/3.
__global__ __launch_bounds__(256) void arma_out(
    const float* __restrict__ H, const float* __restrict__ aa,
    const float* __restrict__ rw, const float* __restrict__ bw,
    const int* __restrict__ aei, const int* __restrict__ aoff,
    const int* __restrict__ aeid, const float* __restrict__ nrm,
    float* __restrict__ O, const int* __restrict__ bat, float* __restrict__ g) {
    int t = blockIdx.x * 256 + threadIdx.x;
    if (t >= N_AMINO * 16) return;
    int n = t >> 4, c0 = (t & 15) * 8;
    float acc[8];
#pragma unroll
    for (int j = 0; j < 8; ++j) acc[j] = bw[c0 + j];
    int j1 = aoff[n + 1];
    for (int jj = aoff[n]; jj < j1; ++jj) {
        int e = aeid[jj], s = aei[e];
        float nm = nrm[e];
        const float* hr = H + s * HA + c0;
#pragma unroll
        for (int j = 0; j < 8; ++j) acc[j] += nm * hr[j];
    }
    float a[28];
    const float* ar = aa + n * 28;
#pragma unroll
    for (int i = 0; i < 28; ++i) a[i] = ar[i];
    for (int f = 0; f < 28; ++f) {
        const float* wr = rw + f * HA + c0;
        float4 w0 = *(const float4*)wr, w1 = *(const float4*)(wr + 4);
        float av = a[f];
        acc[0] += av * w0.x; acc[1] += av * w0.y; acc[2] += av * w0.z; acc[3] += av * w0.w;
        acc[4] += av * w1.x; acc[5] += av * w1.y; acc[6] += av * w1.z; acc[7] += av * w1.w;
    }
#pragma unroll
    for (int j = 0; j < 8; ++j) acc[j] = fmaxf(acc[j], 0.f);
    float* op = O + n * HA + c0;
    *(float4*)op       = make_float4(acc[0], acc[1], acc[2], acc[3]);
    *(float4*)(op + 4) = make_float4(acc[4], acc[5], acc[6], acc[7]);
    if (bat) {
        float* gp = g + bat[n] * HA + c0;
#pragma unroll
        for (int j = 0; j < 8; ++j) atomicAdd(gp + j, acc[j] * (1.f / 3.f));
    }
}

// ---------------------------------------------------------------------------
// MLP head: one block per graph. OUTPUT IS FP32.
__global__ __launch_bounds__(256) void head(
    const float* __restrict__ g,
    const float* __restrict__ l1w, const float* __restrict__ l1b,
    const float* __restrict__ l2w, const float* __restrict__ l2b,
    const float* __restrict__ l3w, const float* __restrict__ l3b,
    const float* __restrict__ l4w, const float* __restrict__ l4b,
    float* __restrict__ outp) {
    __shared__ float sg[HA], sp1[F1], sp2[F2], sp3[F3];
    int b = blockIdx.x, tx = threadIdx.x;
    if (tx < HA) sg[tx] = g[b * HA + tx];
    __syncthreads();
    {   float acc = l1b[tx];
        for (int f = 0; f < HA; ++f) acc += sg[f] * l1w[f * F1 + tx];
        sp1[tx] = fmaxf(acc, 0.f); }
    __syncthreads();
    if (tx < F2) {
        float acc = l2b[tx];
        for (int f = 0; f < F1; ++f) acc += sp1[f] * l2w[f * F2 + tx];
        sp2[tx] = fmaxf(acc, 0.f); }
    __syncthreads();
    if (tx < F3) {
        float acc = l3b[tx];
        for (int f = 0; f < F2; ++f) acc += sp2[f] * l3w[f * F3 + tx];
        sp3[tx] = fmaxf(acc, 0.f); }
    __syncthreads();
    if (tx < 64) {
        float p = sp3[tx] * l4w[tx];
        for (int off = 32; off > 0; off >>= 1) p += __shfl_down(p, off, 64);
        if (tx == 0) outp[b] = p + l4b[0];
    }
}

// ---------------------------------------------------------------------------
// Workspace: TOTAL 13,376,768 B.
#define OFF_M1   ((size_t)0)               // 38,400
#define OFF_M2   ((size_t)38400)           // 19,200
#define OFF_M3   ((size_t)57600)           // 19,200 -> 76,800
#define OFF_OFF  ((size_t)76800)           // 400,128 -> 476,928 (atom CSR offsets)
#define OFF_EID  ((size_t)476928)          // 800,000 -> 1,276,928 (atom CSR edge ids)
#define OFF_AOFF ((size_t)1276928)         // 41,216 -> 1,318,144 (amino CSR offsets)
#define OFF_AEID ((size_t)1318144)         // 81,920 -> 1,400,064
#define OFF_NRM  ((size_t)1400064)         // 81,920 -> 1,481,984
#define OFF_AA   ((size_t)1481984)         // 1,146,880 -> 2,628,864
#define OFF_G    ((size_t)2628864)         // 262,144 -> 2,891,008
#define OFF_HA   ((size_t)2891008)         // bf16 h1: 4,000,000 -> 6,891,008
#define OFF_HB   ((size_t)6891008)         // bf16 h2: 4,000,000 -> 10,891,008
// Overlays: CSR-build scratch in hB (dead until layer-2 writes);
// ARMA fp32 H/O over hA/hB after layer 3 (both dead).
#define OFF_CNT  (OFF_HB)                  // 400,128
#define OFF_CUR  (OFF_HB + 400128)         // 400,128
#define OFF_ACNT (OFF_HB + 800256)         // 41,216
#define OFF_ACUR (OFF_HB + 841472)         // 41,216
#define OFF_HM   (OFF_HA)                  // ARMA H fp32: 5,242,880 -> 8,133,888
#define OFF_OB   (OFF_HA + 5242880)        // ARMA O fp32: 5,242,880 -> 13,376,768

extern "C" void kernel_launch(void* const* d_in, const int* in_sizes, int n_in,
                              void* d_out, int out_size, void* d_ws, size_t ws_size,
                              hipStream_t stream) {
    (void)in_sizes; (void)n_in; (void)out_size; (void)ws_size;
    const float* x   = (const float*)d_in[0];
    const int*   ei  = (const int*)d_in[1];
    const float* ea  = (const float*)d_in[2];
    const int*   lbl = (const int*)d_in[3];
    const float* af  = (const float*)d_in[4];
    const int*   aei = (const int*)d_in[5];
    const int*   bat = (const int*)d_in[6];
    const float* nn1w = (const float*)d_in[7];  const float* nn1b = (const float*)d_in[8];
    const float* rt1  = (const float*)d_in[9];  const float* b1   = (const float*)d_in[10];
    const float* nn2w = (const float*)d_in[11]; const float* nn2b = (const float*)d_in[12];
    const float* rt2  = (const float*)d_in[13]; const float* b2   = (const float*)d_in[14];
    const float* nn3w = (const float*)d_in[15]; const float* nn3b = (const float*)d_in[16];
    const float* rt3  = (const float*)d_in[17]; const float* b3   = (const float*)d_in[18];
    const float* ai   = (const float*)d_in[19]; const float* aw   = (const float*)d_in[20];
    const float* arw  = (const float*)d_in[21]; const float* abi  = (const float*)d_in[22];
    const float* l1w  = (const float*)d_in[23]; const float* l1b  = (const float*)d_in[24];
    const float* l2w  = (const float*)d_in[25]; const float* l2b  = (const float*)d_in[26];
    const float* l3w  = (const float*)d_in[27]; const float* l3b  = (const float*)d_in[28];
    const float* l4w  = (const float*)d_in[29]; const float* l4b  = (const float*)d_in[30];
    float* outp = (float*)d_out;   // fp32 output per reference

    char* ws = (char*)d_ws;
    float* M1   = (float*)(ws + OFF_M1);
    float* M2   = (float*)(ws + OFF_M2);
    float* M3   = (float*)(ws + OFF_M3);
    int*   off  = (int*)(ws + OFF_OFF);
    int*   eid  = (int*)(ws + OFF_EID);
    int*   aoff = (int*)(ws + OFF_AOFF);
    int*   aeid = (int*)(ws + OFF_AEID);
    float* nrm  = (float*)(ws + OFF_NRM);
    float* aa   = (float*)(ws + OFF_AA);
    float* g    = (float*)(ws + OFF_G);
    u16*   hA   = (u16*)(ws + OFF_HA);
    u16*   hB   = (u16*)(ws + OFF_HB);
    int*   cnt  = (int*)(ws + OFF_CNT);
    int*   cur  = (int*)(ws + OFF_CUR);
    int*   acnt = (int*)(ws + OFF_ACNT);
    int*   acur = (int*)(ws + OFF_ACUR);
    float* Hb   = (float*)(ws + OFF_HM);
    float* Ob   = (float*)(ws + OFF_OB);

    const int* edst  = ei + E_ATOMS;    // dst row of atom graph
    const int* adst  = aei + E_AMINO;   // dst row of amino graph

    build_M<<<75, 256, 0, stream>>>(nn1w, nn1b, nn2w, nn2b, nn3w, nn3b, M1, M2, M3);

    // Atom CSR (by dst)
    k_zero_i<<<391, 256, 0, stream>>>(cnt, N_ATOMS);
    k_count<<<782, 256, 0, stream>>>(edst, cnt, E_ATOMS);
    k_scan<<<1, 256, 0, stream>>>(cnt, off, N_ATOMS);
    k_cpy<<<392, 256, 0, stream>>>(off, cur, N_ATOMS + 1);
    k_fill<<<782, 256, 0, stream>>>(edst, cur, eid, E_ATOMS);
    // Amino CSR (by dst)
    k_zero_i<<<40, 256, 0, stream>>>(acnt, N_AMINO);
    k_count<<<80, 256, 0, stream>>>(adst, acnt, E_AMINO);
    k_scan<<<1, 256, 0, stream>>>(acnt, aoff, N_AMINO);
    k_cpy<<<41, 256, 0, stream>>>(aoff, acur, N_AMINO + 1);
    k_fill<<<80, 256, 0, stream>>>(adst, acur, aeid, E_AMINO);
    k_anorm<<<80, 256, 0, stream>>>(aei, aoff, nrm);

    aa_init<<<256, 256, 0, stream>>>(af, aa, g);

    // NNConv layers (CSR gather, fused finish)
    k_nnconv<DIN0, true,  false><<<391, 256, 0, stream>>>(
        x,  ea, ei, off, eid, M1, rt1, b1, hA, nullptr, nullptr);
    k_nnconv<HD,   false, false><<<391, 256, 0, stream>>>(
        hA, ea, ei, off, eid, M2, rt2, b2, hB, nullptr, nullptr);
    k_nnconv<HD,   false, true ><<<391, 256, 0, stream>>>(
        hB, ea, ei, off, eid, M3, rt3, b3, nullptr, aa, lbl);

    // ARMA: K stacks sequentially, T layers each (fp32 throughout)
    for (int k = 0; k < KS; ++k) {
        for (int t = 0; t < TL; ++t) {
            if (t == 0)
                arma_gemm28<<<640, 256, 0, stream>>>(aa, ai + k * 28 * HA, Hb);
            else
                arma_gemm128<<<640, 256, 0, stream>>>(
                    Ob, aw + ((t - 1) * KS + k) * HA * HA, Hb);
            arma_out<<<640, 256, 0, stream>>>(
                Hb, aa, arw + (t * KS + k) * 28 * HA, abi + (t * KS + k) * HA,
                aei, aoff, aeid, nrm, Ob,
                (t == TL - 1) ? bat : (const int*)nullptr, g);
        }
    }

    head<<<NGRAPH, 256, 0, stream>>>(g, l1w, l1b, l2w, l2b, l3w, l3b, l4w, l4b, outp);
}

// Round 7
// 1564.553 us; speedup vs baseline: 1.4786x; 1.4786x over previous
//
#include <hip/hip_runtime.h>

#define N_ATOMS 100000
#define E_ATOMS 200000
#define N_AMINO 10240
#define E_AMINO 20480
#define NGRAPH 512
#define DIN0 40
#define D_E 11
#define HD 20
#define D_AA 8
#define HA 128
#define KS 3
#define TL 7
#define F1 256
#define F2 128
#define F3 64

typedef unsigned short u16;
typedef unsigned int u32;

__device__ __forceinline__ float b2f(u16 u) {
    union { u32 i; float f; } v; v.i = ((u32)u) << 16; return v.f;
}
__device__ __forceinline__ u16 f2b(float f) {
    union { float f; u32 i; } v; v.f = f;
    u32 x = v.i;
    return (u16)((x + (((x >> 16) & 1u) + 0x7fffu)) >> 16);
}

// ---------------------------------------------------------------------------
// prep0: build M matrices + init aa (features, zero sums) + zero g.
// M[i*240 + k*20+o] = nn_w[k, i*20+o]; M[i*240+220+o] = nn_b[i*20+o]
__global__ __launch_bounds__(256) void k_prep0(
    const float* __restrict__ w1, const float* __restrict__ b1,
    const float* __restrict__ w2, const float* __restrict__ b2,
    const float* __restrict__ w3, const float* __restrict__ b3,
    float* __restrict__ M1, float* __restrict__ M2, float* __restrict__ M3,
    const float* __restrict__ af, float* __restrict__ aa, float* __restrict__ g) {
    int t = blockIdx.x * 256 + threadIdx.x;
    if (t < 9600) {
        int i = t / 240, c = t % 240;
        M1[t] = (c < 220) ? w1[(c / 20) * 800 + i * 20 + (c % 20)] : b1[i * 20 + (c - 220)];
    } else if (t < 14400) {
        int tt = t - 9600, i = tt / 240, c = tt % 240;
        M2[tt] = (c < 220) ? w2[(c / 20) * 400 + i * 20 + (c % 20)] : b2[i * 20 + (c - 220)];
    } else if (t < 19200) {
        int tt = t - 14400, i = tt / 240, c = tt % 240;
        M3[tt] = (c < 220) ? w3[(c / 20) * 400 + i * 20 + (c % 20)] : b3[i * 20 + (c - 220)];
    } else if (t < 19200 + N_AMINO) {
        int n = t - 19200;
        float* r = aa + n * 28;
#pragma unroll
        for (int o = 0; o < HD; ++o) r[o] = 0.f;
#pragma unroll
        for (int j = 0; j < D_AA; ++j) r[HD + j] = af[n * D_AA + j];
    } else if (t < 19200 + N_AMINO + NGRAPH * HA) {
        g[t - 19200 - N_AMINO] = 0.f;
    }
}

// ---------------------------------------------------------------------------
// CSR build (both graphs, merged launches)
__global__ __launch_bounds__(256) void k_csr_zero(int* __restrict__ cnt,
                                                  int* __restrict__ acnt) {
    int t = blockIdx.x * 256 + threadIdx.x;
    if (t < N_ATOMS) cnt[t] = 0;
    else if (t < N_ATOMS + N_AMINO) acnt[t - N_ATOMS] = 0;
}
__global__ __launch_bounds__(256) void k_csr_count(
    const int* __restrict__ edst, const int* __restrict__ adst,
    int* __restrict__ cnt, int* __restrict__ acnt) {
    int t = blockIdx.x * 256 + threadIdx.x;
    if (t < E_ATOMS) atomicAdd(cnt + edst[t], 1);
    else if (t < E_ATOMS + E_AMINO) atomicAdd(acnt + adst[t - E_ATOMS], 1);
}
// blockIdx 0: atoms, 1: aminos. Single 256-thread block each.
__global__ __launch_bounds__(256) void k_csr_scan(
    const int* __restrict__ c0, int* __restrict__ o0,
    const int* __restrict__ c1, int* __restrict__ o1) {
    const int* cnt = blockIdx.x ? c1 : c0;
    int*       off = blockIdx.x ? o1 : o0;
    int n = blockIdx.x ? N_AMINO : N_ATOMS;
    __shared__ int wsum[4];
    __shared__ int carry;
    int tx = threadIdx.x, lane = tx & 63, w = tx >> 6;
    if (tx == 0) carry = 0;
    __syncthreads();
    for (int base = 0; base < n; base += 256) {
        int v = (base + tx < n) ? cnt[base + tx] : 0;
        int s = v;
#pragma unroll
        for (int d = 1; d < 64; d <<= 1) {
            int u = __shfl_up(s, d, 64);
            if (lane >= d) s += u;
        }
        if (lane == 63) wsum[w] = s;
        __syncthreads();
        int wo = 0;
        for (int i = 0; i < w; ++i) wo += wsum[i];
        int excl = carry + wo + s - v;
        if (base + tx < n) off[base + tx] = excl;
        __syncthreads();
        if (tx == 0) carry += wsum[0] + wsum[1] + wsum[2] + wsum[3];
        __syncthreads();
    }
    if (tx == 0) off[n] = carry;
}
__global__ __launch_bounds__(256) void k_csr_cpy(
    const int* __restrict__ a0, int* __restrict__ b0,
    const int* __restrict__ a1, int* __restrict__ b1) {
    int t = blockIdx.x * 256 + threadIdx.x;
    if (t < N_ATOMS + 1) b0[t] = a0[t];
    else if (t < N_ATOMS + 1 + N_AMINO + 1) b1[t - N_ATOMS - 1] = a1[t - N_ATOMS - 1];
}
// fill both CSRs + amino edge norm
__global__ __launch_bounds__(256) void k_csr_fill(
    const int* __restrict__ edst, int* __restrict__ cur, int* __restrict__ eid,
    const int* __restrict__ aei, int* __restrict__ acur, int* __restrict__ aeid,
    const int* __restrict__ aoff, float* __restrict__ nrm) {
    int t = blockIdx.x * 256 + threadIdx.x;
    if (t < E_ATOMS) {
        int p = atomicAdd(cur + edst[t], 1);
        eid[p] = t;
    } else if (t < E_ATOMS + E_AMINO) {
        int e = t - E_ATOMS;
        int p = atomicAdd(acur + aei[E_AMINO + e], 1);
        aeid[p] = e;
    } else if (t < E_ATOMS + 2 * E_AMINO) {
        int e = t - E_ATOMS - E_AMINO;
        int s = aei[e], d = aei[E_AMINO + e];
        int ds = aoff[s + 1] - aoff[s], dd = aoff[d + 1] - aoff[d];
        float a = ds > 0 ? rsqrtf((float)ds) : 0.f;
        float b = dd > 0 ? rsqrtf((float)dd) : 0.f;
        nrm[e] = a * b;
    }
}

// ---------------------------------------------------------------------------
// NNConv: one WAVE per dst node. For each incoming edge, 60 lanes build
// y[240] = x[src] @ M into LDS (ds_read_b128 of M, wave-uniform s_loads of x),
// then 20 lanes contract with ea. Root+bias+relu fused; layer 3 scatters to aa.
template <int DIN, bool RAW, bool FUSE>
__global__ __launch_bounds__(256) void nnconv_gather(
    const void* __restrict__ xin, const float* __restrict__ ea,
    const int* __restrict__ esrc, const int* __restrict__ doff,
    const int* __restrict__ deid, const float* __restrict__ Mg,
    const float* __restrict__ root, const float* __restrict__ bias,
    u16* __restrict__ hout, float* __restrict__ aa, const int* __restrict__ lbl) {
    __shared__ float Ml[DIN * 240];
    __shared__ float Rl[DIN * HD + HD];
    __shared__ float yl[4][240];
    for (int t = threadIdx.x; t < DIN * 240; t += 256) Ml[t] = Mg[t];
    for (int t = threadIdx.x; t < DIN * HD; t += 256) Rl[t] = root[t];
    if (threadIdx.x < HD) Rl[DIN * HD + threadIdx.x] = bias[threadIdx.x];
    __syncthreads();
    int wave = threadIdx.x >> 6, lane = threadIdx.x & 63;
    int c0 = lane * 4;
    float* yw = yl[wave];
    for (int grp = blockIdx.x; grp < N_ATOMS / 4; grp += gridDim.x) {
        int n = __builtin_amdgcn_readfirstlane(grp * 4 + wave);
        int j0 = doff[n], j1 = doff[n + 1];
        float acc = 0.f;                       // lanes 0..19: msg accum for o=lane
        for (int j = j0; j < j1; ++j) {
            int e = deid[j];
            int s = esrc[e];
            if (lane < 60) {
                float y0 = 0.f, y1 = 0.f, y2 = 0.f, y3 = 0.f;
                const float* xf = (const float*)xin + (size_t)s * DIN;
                const u16*   xb = (const u16*)xin + (size_t)s * DIN;
#pragma unroll
                for (int i = 0; i < DIN; ++i) {
                    float xv = RAW ? xf[i] : b2f(xb[i]);
                    float4 m = *(const float4*)&Ml[i * 240 + c0];
                    y0 += xv * m.x; y1 += xv * m.y; y2 += xv * m.z; y3 += xv * m.w;
                }
                *(float4*)&yw[c0] = make_float4(y0, y1, y2, y3);
            }
            __builtin_amdgcn_wave_barrier();   // keep write->read order in-wave
            if (lane < HD) {
                const float* er = ea + (size_t)e * D_E;
                float m = yw[220 + lane];
#pragma unroll
                for (int k = 0; k < D_E; ++k) m += er[k] * yw[k * HD + lane];
                acc += m;
            }
            __builtin_amdgcn_wave_barrier();   // keep read->next-write order
        }
        if (lane < HD) {
            float r = Rl[DIN * HD + lane];
            const float* xf = (const float*)xin + (size_t)n * DIN;
            const u16*   xb = (const u16*)xin + (size_t)n * DIN;
#pragma unroll
            for (int i = 0; i < DIN; ++i) {
                float xv = RAW ? xf[i] : b2f(xb[i]);
                r += xv * Rl[i * HD + lane];
            }
            float v = fmaxf(acc + r, 0.f);
            if (FUSE) atomicAdd(aa + (size_t)lbl[n] * 28 + lane, v);
            else hout[(size_t)n * HD + lane] = f2b(v);
        }
    }
}

// ---------------------------------------------------------------------------
// ARMA, k = blockIdx.y (strides 0-effective when grid.y==1 and bases pre-offset)
__global__ __launch_bounds__(256) void arma_gemm28(
    const float* __restrict__ A, const float* __restrict__ W, size_t wstride,
    float* __restrict__ H, size_t hstride) {
    int t = blockIdx.x * 256 + threadIdx.x;
    int n = t >> 4, c0 = (t & 15) * 8;
    const float* Wk = W + blockIdx.y * wstride;
    float* Hk = H + blockIdx.y * hstride;
    float a[28];
    const float* ar = A + n * 28;
#pragma unroll
    for (int i = 0; i < 28; ++i) a[i] = ar[i];
    float acc[8];
#pragma unroll
    for (int j = 0; j < 8; ++j) acc[j] = 0.f;
    for (int f = 0; f < 28; ++f) {
        const float* wr = Wk + f * HA + c0;
        float4 w0 = *(const float4*)wr, w1 = *(const float4*)(wr + 4);
        float av = a[f];
        acc[0] += av * w0.x; acc[1] += av * w0.y; acc[2] += av * w0.z; acc[3] += av * w0.w;
        acc[4] += av * w1.x; acc[5] += av * w1.y; acc[6] += av * w1.z; acc[7] += av * w1.w;
    }
    float* hp = Hk + n * HA + c0;
    *(float4*)hp       = make_float4(acc[0], acc[1], acc[2], acc[3]);
    *(float4*)(hp + 4) = make_float4(acc[4], acc[5], acc[6], acc[7]);
}

// 16-row A tile in LDS (pad 129 to break the 16-way bank conflict)
__global__ __launch_bounds__(256) void arma_gemm128(
    const float* __restrict__ A, size_t astride,
    const float* __restrict__ W, size_t wstride,
    float* __restrict__ H, size_t hstride) {
    __shared__ float Al[16][HA + 1];
    const float* Ak = A + blockIdx.y * astride;
    const float* Wk = W + blockIdx.y * wstride;
    float* Hk = H + blockIdx.y * hstride;
    int row0 = blockIdx.x * 16;
    for (int t = threadIdx.x; t < 16 * HA; t += 256)
        Al[t >> 7][t & 127] = Ak[(size_t)(row0 + (t >> 7)) * HA + (t & 127)];
    __syncthreads();
    int r = threadIdx.x >> 4, c0 = (threadIdx.x & 15) * 8;
    float acc[8];
#pragma unroll
    for (int j = 0; j < 8; ++j) acc[j] = 0.f;
    for (int f = 0; f < HA; ++f) {
        float av = Al[r][f];
        const float* wr = Wk + f * HA + c0;
        float4 w0 = *(const float4*)wr, w1 = *(const float4*)(wr + 4);
        acc[0] += av * w0.x; acc[1] += av * w0.y; acc[2] += av * w0.z; acc[3] += av * w0.w;
        acc[4] += av * w1.x; acc[5] += av * w1.y; acc[6] += av * w1.z; acc[7] += av * w1.w;
    }
    float* hp = Hk + (size_t)(row0 + r) * HA + c0;
    *(float4*)hp       = make_float4(acc[0], acc[1], acc[2], acc[3]);
    *(float4*)(hp + 4) = make_float4(acc[4], acc[5], acc[6], acc[7]);
}

__global__ __launch_bounds__(256) void arma_out(
    const float* __restrict__ H, size_t hstride,
    const float* __restrict__ aa,
    const float* __restrict__ rw, size_t rstride,
    const float* __restrict__ bw, size_t bstride,
    const int* __restrict__ aei, const int* __restrict__ aoff,
    const int* __restrict__ aeid, const float* __restrict__ nrm,
    float* __restrict__ O, size_t ostride,
    const int* __restrict__ bat, float* __restrict__ g) {
    int t = blockIdx.x * 256 + threadIdx.x;
    int n = t >> 4, c0 = (t & 15) * 8;
    const float* Hk = H + blockIdx.y * hstride;
    const float* rwk = rw + blockIdx.y * rstride;
    const float* bwk = bw + blockIdx.y * bstride;
    float* Ok = O + blockIdx.y * ostride;
    float acc[8];
#pragma unroll
    for (int j = 0; j < 8; ++j) acc[j] = bwk[c0 + j];
    int j1 = aoff[n + 1];
    for (int jj = aoff[n]; jj < j1; ++jj) {
        int e = aeid[jj], s = aei[e];
        float nm = nrm[e];
        const float* hr = Hk + (size_t)s * HA + c0;
#pragma unroll
        for (int j = 0; j < 8; ++j) acc[j] += nm * hr[j];
    }
    float a[28];
    const float* ar = aa + n * 28;
#pragma unroll
    for (int i = 0; i < 28; ++i) a[i] = ar[i];
    for (int f = 0; f < 28; ++f) {
        const float* wr = rwk + f * HA + c0;
        float4 w0 = *(const float4*)wr, w1 = *(const float4*)(wr + 4);
        float av = a[f];
        acc[0] += av * w0.x; acc[1] += av * w0.y; acc[2] += av * w0.z; acc[3] += av * w0.w;
        acc[4] += av * w1.x; acc[5] += av * w1.y; acc[6] += av * w1.z; acc[7] += av * w1.w;
    }
#pragma unroll
    for (int j = 0; j < 8; ++j) acc[j] = fmaxf(acc[j], 0.f);
    float* op = Ok + (size_t)n * HA + c0;
    *(float4*)op       = make_float4(acc[0], acc[1], acc[2], acc[3]);
    *(float4*)(op + 4) = make_float4(acc[4], acc[5], acc[6], acc[7]);
    if (bat) {
        float* gp = g + (size_t)bat[n] * HA + c0;
#pragma unroll
        for (int j = 0; j < 8; ++j) atomicAdd(gp + j, acc[j] * (1.f / 3.f));
    }
}

// ---------------------------------------------------------------------------
__global__ __launch_bounds__(256) void head(
    const float* __restrict__ g,
    const float* __restrict__ l1w, const float* __restrict__ l1b,
    const float* __restrict__ l2w, const float* __restrict__ l2b,
    const float* __restrict__ l3w, const float* __restrict__ l3b,
    const float* __restrict__ l4w, const float* __restrict__ l4b,
    float* __restrict__ outp) {
    __shared__ float sg[HA], sp1[F1], sp2[F2], sp3[F3];
    int b = blockIdx.x, tx = threadIdx.x;
    if (tx < HA) sg[tx] = g[b * HA + tx];
    __syncthreads();
    {   float acc = l1b[tx];
        for (int f = 0; f < HA; ++f) acc += sg[f] * l1w[f * F1 + tx];
        sp1[tx] = fmaxf(acc, 0.f); }
    __syncthreads();
    if (tx < F2) {
        float acc = l2b[tx];
        for (int f = 0; f < F1; ++f) acc += sp1[f] * l2w[f * F2 + tx];
        sp2[tx] = fmaxf(acc, 0.f); }
    __syncthreads();
    if (tx < F3) {
        float acc = l3b[tx];
        for (int f = 0; f < F2; ++f) acc += sp2[f] * l3w[f * F3 + tx];
        sp3[tx] = fmaxf(acc, 0.f); }
    __syncthreads();
    if (tx < 64) {
        float p = sp3[tx] * l4w[tx];
        for (int off = 32; off > 0; off >>= 1) p += __shfl_down(p, off, 64);
        if (tx == 0) outp[b] = p + l4b[0];
    }
}

// ---------------------------------------------------------------------------
// Workspace. Base (always used) = 10,891,008 B. ARMA overlays hA/hB (dead
// after layer 3): sequential H/O fp32 -> total 13,376,768 (== round 6, proven);
// K-parallel H/O (3x) -> total 34,348,288, used only when ws_size allows.
#define OFF_M1   ((size_t)0)
#define OFF_M2   ((size_t)38400)
#define OFF_M3   ((size_t)57600)
#define OFF_DOFF ((size_t)76800)
#define OFF_DEID ((size_t)476928)
#define OFF_AOFF ((size_t)1276928)
#define OFF_AEID ((size_t)1318144)
#define OFF_NRM  ((size_t)1400064)
#define OFF_AA   ((size_t)1481984)
#define OFF_G    ((size_t)2628864)
#define OFF_HA   ((size_t)2891008)          // bf16 h1 (4,000,000)
#define OFF_HB   ((size_t)6891008)          // bf16 h2 (4,000,000)
// CSR-build scratch overlays hA/hB (dead until layer-1 output)
#define OFF_CNT  (OFF_HA)
#define OFF_CUR  (OFF_HA + 400128)
#define OFF_ACNT (OFF_HA + 800256)
#define OFF_ACUR (OFF_HA + 841472)
// ARMA overlays
#define OFF_H    (OFF_HA)                   // fp32 H
#define SZ_K1    ((size_t)N_AMINO * HA * 4) // 5,242,880
#define SZ_K3    (SZ_K1 * KS)               // 15,728,640
#define WS_PAR   (OFF_H + 2 * SZ_K3)        // 34,348,288

extern "C" void kernel_launch(void* const* d_in, const int* in_sizes, int n_in,
                              void* d_out, int out_size, void* d_ws, size_t ws_size,
                              hipStream_t stream) {
    (void)in_sizes; (void)n_in; (void)out_size;
    const float* x   = (const float*)d_in[0];
    const int*   ei  = (const int*)d_in[1];
    const float* ea  = (const float*)d_in[2];
    const int*   lbl = (const int*)d_in[3];
    const float* af  = (const float*)d_in[4];
    const int*   aei = (const int*)d_in[5];
    const int*   bat = (const int*)d_in[6];
    const float* nn1w = (const float*)d_in[7];  const float* nn1b = (const float*)d_in[8];
    const float* rt1  = (const float*)d_in[9];  const float* b1   = (const float*)d_in[10];
    const float* nn2w = (const float*)d_in[11]; const float* nn2b = (const float*)d_in[12];
    const float* rt2  = (const float*)d_in[13]; const float* b2   = (const float*)d_in[14];
    const float* nn3w = (const float*)d_in[15]; const float* nn3b = (const float*)d_in[16];
    const float* rt3  = (const float*)d_in[17]; const float* b3   = (const float*)d_in[18];
    const float* ai   = (const float*)d_in[19]; const float* aw   = (const float*)d_in[20];
    const float* arw  = (const float*)d_in[21]; const float* abi  = (const float*)d_in[22];
    const float* l1w  = (const float*)d_in[23]; const float* l1b  = (const float*)d_in[24];
    const float* l2w  = (const float*)d_in[25]; const float* l2b  = (const float*)d_in[26];
    const float* l3w  = (const float*)d_in[27]; const float* l3b  = (const float*)d_in[28];
    const float* l4w  = (const float*)d_in[29]; const float* l4b  = (const float*)d_in[30];
    float* outp = (float*)d_out;

    char* ws = (char*)d_ws;
    float* M1   = (float*)(ws + OFF_M1);
    float* M2   = (float*)(ws + OFF_M2);
    float* M3   = (float*)(ws + OFF_M3);
    int*   doff = (int*)(ws + OFF_DOFF);
    int*   deid = (int*)(ws + OFF_DEID);
    int*   aoff = (int*)(ws + OFF_AOFF);
    int*   aeid = (int*)(ws + OFF_AEID);
    float* nrm  = (float*)(ws + OFF_NRM);
    float* aa   = (float*)(ws + OFF_AA);
    float* g    = (float*)(ws + OFF_G);
    u16*   hA   = (u16*)(ws + OFF_HA);
    u16*   hB   = (u16*)(ws + OFF_HB);
    int*   cnt  = (int*)(ws + OFF_CNT);
    int*   cur  = (int*)(ws + OFF_CUR);
    int*   acnt = (int*)(ws + OFF_ACNT);
    int*   acur = (int*)(ws + OFF_ACUR);
    float* Hb   = (float*)(ws + OFF_H);

    const int* edst = ei + E_ATOMS;
    const int* adst = aei + E_AMINO;
    const bool par = ws_size >= WS_PAR;
    const size_t osz = par ? SZ_K3 : SZ_K1;
    float* Ob = (float*)(ws + OFF_H + osz);
    const int py = par ? KS : 1;

    // prep (6 launches)
    k_prep0<<<(19200 + N_AMINO + NGRAPH * HA + 255) / 256, 256, 0, stream>>>(
        nn1w, nn1b, nn2w, nn2b, nn3w, nn3b, M1, M2, M3, af, aa, g);
    k_csr_zero<<<(N_ATOMS + N_AMINO + 255) / 256, 256, 0, stream>>>(cnt, acnt);
    k_csr_count<<<(E_ATOMS + E_AMINO + 255) / 256, 256, 0, stream>>>(edst, adst, cnt, acnt);
    k_csr_scan<<<2, 256, 0, stream>>>(cnt, doff, acnt, aoff);
    k_csr_cpy<<<(N_ATOMS + N_AMINO + 2 + 255) / 256, 256, 0, stream>>>(doff, cur, aoff, acur);
    k_csr_fill<<<(E_ATOMS + 2 * E_AMINO + 255) / 256, 256, 0, stream>>>(
        edst, cur, deid, aei, acur, aeid, aoff, nrm);

    // NNConv (3 launches, wave-per-node)
    nnconv_gather<DIN0, true,  false><<<2048, 256, 0, stream>>>(
        x,  ea, ei, doff, deid, M1, rt1, b1, hA, nullptr, nullptr);
    nnconv_gather<HD,   false, false><<<2048, 256, 0, stream>>>(
        hA, ea, ei, doff, deid, M2, rt2, b2, hB, nullptr, nullptr);
    nnconv_gather<HD,   false, true ><<<2048, 256, 0, stream>>>(
        hB, ea, ei, doff, deid, M3, rt3, b3, nullptr, aa, lbl);

    // ARMA
    const size_t KH = (size_t)N_AMINO * HA;        // per-k element stride
    if (par) {
        for (int t = 0; t < TL; ++t) {
            if (t == 0)
                arma_gemm28<<<dim3(640, KS), 256, 0, stream>>>(aa, ai, 28 * HA, Hb, KH);
            else
                arma_gemm128<<<dim3(640, KS), 256, 0, stream>>>(
                    Ob, KH, aw + (size_t)(t - 1) * KS * HA * HA, HA * HA, Hb, KH);
            arma_out<<<dim3(640, KS), 256, 0, stream>>>(
                Hb, KH, aa, arw + (size_t)t * KS * 28 * HA, 28 * HA,
                abi + (size_t)t * KS * HA, HA, aei, aoff, aeid, nrm, Ob, KH,
                (t == TL - 1) ? bat : (const int*)nullptr, g);
        }
    } else {
        for (int k = 0; k < KS; ++k) {
            for (int t = 0; t < TL; ++t) {
                if (t == 0)
                    arma_gemm28<<<dim3(640, 1), 256, 0, stream>>>(
                        aa, ai + (size_t)k * 28 * HA, 0, Hb, 0);
                else
                    arma_gemm128<<<dim3(640, 1), 256, 0, stream>>>(
                        Ob, 0, aw + (size_t)((t - 1) * KS + k) * HA * HA, 0, Hb, 0);
                arma_out<<<dim3(640, 1), 256, 0, stream>>>(
                    Hb, 0, aa, arw + (size_t)(t * KS + k) * 28 * HA, 0,
                    abi + (size_t)(t * KS + k) * HA, 0, aei, aoff, aeid, nrm, Ob, 0,
                    (t == TL - 1) ? bat : (const int*)nullptr, g);
            }
        }
    }

    head<<<NGRAPH, 256, 0, stream>>>(g, l1w, l1b, l2w, l2b, l3w, l3b, l4w, l4b, outp);
}

// Round 8
// 1284.166 us; speedup vs baseline: 1.8015x; 1.2183x over previous
//
#include <hip/hip_runtime.h>

#define N_ATOMS 100000
#define E_ATOMS 200000
#define N_AMINO 10240
#define E_AMINO 20480
#define NGRAPH 512
#define DIN0 40
#define D_E 11
#define HD 20
#define D_AA 8
#define HA 128
#define KS 3
#define TL 7
#define F1 256
#define F2 128
#define F3 64

#define NB_ATOM 98   // ceil(N_ATOMS/1024)
#define NB_AM   10   // ceil(N_AMINO/1024)

typedef unsigned short u16;
typedef unsigned int u32;

__device__ __forceinline__ float b2f(u16 u) {
    union { u32 i; float f; } v; v.i = ((u32)u) << 16; return v.f;
}
__device__ __forceinline__ u16 f2b(float f) {
    union { float f; u32 i; } v; v.f = f;
    u32 x = v.i;
    return (u16)((x + (((x >> 16) & 1u) + 0x7fffu)) >> 16);
}

// ---------------------------------------------------------------------------
// prep0: build M matrices + init aa (features, zero sums) + zero g.
__global__ __launch_bounds__(256) void k_prep0(
    const float* __restrict__ w1, const float* __restrict__ b1,
    const float* __restrict__ w2, const float* __restrict__ b2,
    const float* __restrict__ w3, const float* __restrict__ b3,
    float* __restrict__ M1, float* __restrict__ M2, float* __restrict__ M3,
    const float* __restrict__ af, float* __restrict__ aa, float* __restrict__ g) {
    int t = blockIdx.x * 256 + threadIdx.x;
    if (t < 9600) {
        int i = t / 240, c = t % 240;
        M1[t] = (c < 220) ? w1[(c / 20) * 800 + i * 20 + (c % 20)] : b1[i * 20 + (c - 220)];
    } else if (t < 14400) {
        int tt = t - 9600, i = tt / 240, c = tt % 240;
        M2[tt] = (c < 220) ? w2[(c / 20) * 400 + i * 20 + (c % 20)] : b2[i * 20 + (c - 220)];
    } else if (t < 19200) {
        int tt = t - 14400, i = tt / 240, c = tt % 240;
        M3[tt] = (c < 220) ? w3[(c / 20) * 400 + i * 20 + (c % 20)] : b3[i * 20 + (c - 220)];
    } else if (t < 19200 + N_AMINO) {
        int n = t - 19200;
        float* r = aa + n * 28;
#pragma unroll
        for (int o = 0; o < HD; ++o) r[o] = 0.f;
#pragma unroll
        for (int j = 0; j < D_AA; ++j) r[HD + j] = af[n * D_AA + j];
    } else if (t < 19200 + N_AMINO + NGRAPH * HA) {
        g[t - 19200 - N_AMINO] = 0.f;
    }
}

// ---------------------------------------------------------------------------
// CSR build
__global__ __launch_bounds__(256) void k_csr_zero(int* __restrict__ cnt,
                                                  int* __restrict__ acnt) {
    int t = blockIdx.x * 256 + threadIdx.x;
    if (t < N_ATOMS) cnt[t] = 0;
    else if (t < N_ATOMS + N_AMINO) acnt[t - N_ATOMS] = 0;
}
__global__ __launch_bounds__(256) void k_csr_count(
    const int* __restrict__ edst, const int* __restrict__ adst,
    int* __restrict__ cnt, int* __restrict__ acnt) {
    int t = blockIdx.x * 256 + threadIdx.x;
    if (t < E_ATOMS) atomicAdd(cnt + edst[t], 1);
    else if (t < E_ATOMS + E_AMINO) atomicAdd(acnt + adst[t - E_ATOMS], 1);
}
// --- 3-phase hierarchical scan (atoms: blocks [0,98), aminos: [98,108)) ---
// Phase 1: block-local exclusive prefix (1024 elems/block) + block totals.
__global__ __launch_bounds__(256) void k_scan1(
    const int* __restrict__ cnt, int* __restrict__ off,
    const int* __restrict__ acnt, int* __restrict__ aoff,
    int* __restrict__ bsum) {
    bool atom = blockIdx.x < NB_ATOM;
    const int* c = atom ? cnt : acnt;
    int* o = atom ? off : aoff;
    int n = atom ? N_ATOMS : N_AMINO;
    int blk = atom ? blockIdx.x : blockIdx.x - NB_ATOM;
    int tx = threadIdx.x, lane = tx & 63, w = tx >> 6;
    int i0 = blk * 1024 + tx * 4;
    int v[4];
#pragma unroll
    for (int q = 0; q < 4; ++q) v[q] = (i0 + q < n) ? c[i0 + q] : 0;
    int s = v[0] + v[1] + v[2] + v[3];
    int inc = s;
#pragma unroll
    for (int d = 1; d < 64; d <<= 1) {
        int u = __shfl_up(inc, d, 64);
        if (lane >= d) inc += u;
    }
    __shared__ int wsum[4];
    if (lane == 63) wsum[w] = inc;
    __syncthreads();
    int wo = 0;
    for (int i = 0; i < w; ++i) wo += wsum[i];
    int run = wo + inc - s;   // exclusive prefix of this thread within block
#pragma unroll
    for (int q = 0; q < 4; ++q) {
        if (i0 + q < n) o[i0 + q] = run;
        run += v[q];
    }
    if (tx == 255) bsum[blockIdx.x] = wo + inc;   // block total
}
// Phase 2: scan the block totals (block 0: atoms, block 1: aminos).
__global__ __launch_bounds__(128) void k_scan2(int* __restrict__ bsum,
                                               int* __restrict__ off,
                                               int* __restrict__ aoff) {
    int nb = blockIdx.x ? NB_AM : NB_ATOM;
    int* b = bsum + (blockIdx.x ? NB_ATOM : 0);
    int tx = threadIdx.x, lane = tx & 63;
    int v = (tx < nb) ? b[tx] : 0;
    int inc = v;
#pragma unroll
    for (int d = 1; d < 64; d <<= 1) {
        int u = __shfl_up(inc, d, 64);
        if (lane >= d) inc += u;
    }
    __shared__ int w0;
    if (tx == 63) w0 = inc;
    __syncthreads();
    int excl = inc - v + ((tx >= 64) ? w0 : 0);
    if (tx < nb) b[tx] = excl;
    if (tx == nb - 1) {
        int tot = excl + v;
        if (blockIdx.x) aoff[N_AMINO] = tot; else off[N_ATOMS] = tot;
    }
}
// Phase 3: add block bases; also materialize cur (= final offsets) for fill.
__global__ __launch_bounds__(256) void k_scan3(
    int* __restrict__ off, int* __restrict__ aoff,
    const int* __restrict__ bsum, int* __restrict__ cur, int* __restrict__ acur) {
    bool atom = blockIdx.x < NB_ATOM;
    int* o  = atom ? off : aoff;
    int* cu = atom ? cur : acur;
    int n = atom ? N_ATOMS : N_AMINO;
    int blk = atom ? blockIdx.x : blockIdx.x - NB_ATOM;
    int add = bsum[blockIdx.x];
    int i0 = blk * 1024 + threadIdx.x * 4;
#pragma unroll
    for (int q = 0; q < 4; ++q)
        if (i0 + q < n) { int val = o[i0 + q] + add; o[i0 + q] = val; cu[i0 + q] = val; }
}
// fill both CSRs + amino edge norm
__global__ __launch_bounds__(256) void k_csr_fill(
    const int* __restrict__ edst, int* __restrict__ cur, int* __restrict__ eid,
    const int* __restrict__ aei, int* __restrict__ acur, int* __restrict__ aeid,
    const int* __restrict__ aoff, float* __restrict__ nrm) {
    int t = blockIdx.x * 256 + threadIdx.x;
    if (t < E_ATOMS) {
        int p = atomicAdd(cur + edst[t], 1);
        eid[p] = t;
    } else if (t < E_ATOMS + E_AMINO) {
        int e = t - E_ATOMS;
        int p = atomicAdd(acur + aei[E_AMINO + e], 1);
        aeid[p] = e;
    } else if (t < E_ATOMS + 2 * E_AMINO) {
        int e = t - E_ATOMS - E_AMINO;
        int s = aei[e], d = aei[E_AMINO + e];
        int ds = aoff[s + 1] - aoff[s], dd = aoff[d + 1] - aoff[d];
        float a = ds > 0 ? rsqrtf((float)ds) : 0.f;
        float b = dd > 0 ? rsqrtf((float)dd) : 0.f;
        nrm[e] = a * b;
    }
}

// ---------------------------------------------------------------------------
// NNConv: one WAVE per dst node (unchanged from round 7).
template <int DIN, bool RAW, bool FUSE>
__global__ __launch_bounds__(256) void nnconv_gather(
    const void* __restrict__ xin, const float* __restrict__ ea,
    const int* __restrict__ esrc, const int* __restrict__ doff,
    const int* __restrict__ deid, const float* __restrict__ Mg,
    const float* __restrict__ root, const float* __restrict__ bias,
    u16* __restrict__ hout, float* __restrict__ aa, const int* __restrict__ lbl) {
    __shared__ float Ml[DIN * 240];
    __shared__ float Rl[DIN * HD + HD];
    __shared__ float yl[4][240];
    for (int t = threadIdx.x; t < DIN * 240; t += 256) Ml[t] = Mg[t];
    for (int t = threadIdx.x; t < DIN * HD; t += 256) Rl[t] = root[t];
    if (threadIdx.x < HD) Rl[DIN * HD + threadIdx.x] = bias[threadIdx.x];
    __syncthreads();
    int wave = threadIdx.x >> 6, lane = threadIdx.x & 63;
    int c0 = lane * 4;
    float* yw = yl[wave];
    for (int grp = blockIdx.x; grp < N_ATOMS / 4; grp += gridDim.x) {
        int n = __builtin_amdgcn_readfirstlane(grp * 4 + wave);
        int j0 = doff[n], j1 = doff[n + 1];
        float acc = 0.f;
        for (int j = j0; j < j1; ++j) {
            int e = deid[j];
            int s = esrc[e];
            if (lane < 60) {
                float y0 = 0.f, y1 = 0.f, y2 = 0.f, y3 = 0.f;
                const float* xf = (const float*)xin + (size_t)s * DIN;
                const u16*   xb = (const u16*)xin + (size_t)s * DIN;
#pragma unroll
                for (int i = 0; i < DIN; ++i) {
                    float xv = RAW ? xf[i] : b2f(xb[i]);
                    float4 m = *(const float4*)&Ml[i * 240 + c0];
                    y0 += xv * m.x; y1 += xv * m.y; y2 += xv * m.z; y3 += xv * m.w;
                }
                *(float4*)&yw[c0] = make_float4(y0, y1, y2, y3);
            }
            __builtin_amdgcn_wave_barrier();
            if (lane < HD) {
                const float* er = ea + (size_t)e * D_E;
                float m = yw[220 + lane];
#pragma unroll
                for (int k = 0; k < D_E; ++k) m += er[k] * yw[k * HD + lane];
                acc += m;
            }
            __builtin_amdgcn_wave_barrier();
        }
        if (lane < HD) {
            float r = Rl[DIN * HD + lane];
            const float* xf = (const float*)xin + (size_t)n * DIN;
            const u16*   xb = (const u16*)xin + (size_t)n * DIN;
#pragma unroll
            for (int i = 0; i < DIN; ++i) {
                float xv = RAW ? xf[i] : b2f(xb[i]);
                r += xv * Rl[i * HD + lane];
            }
            float v = fmaxf(acc + r, 0.f);
            if (FUSE) atomicAdd(aa + (size_t)lbl[n] * 28 + lane, v);
            else hout[(size_t)n * HD + lane] = f2b(v);
        }
    }
}

// ---------------------------------------------------------------------------
// ARMA, k = blockIdx.y
__global__ __launch_bounds__(256) void arma_gemm28(
    const float* __restrict__ A, const float* __restrict__ W, size_t wstride,
    float* __restrict__ H, size_t hstride) {
    int t = blockIdx.x * 256 + threadIdx.x;
    int n = t >> 4, c0 = (t & 15) * 8;
    const float* Wk = W + blockIdx.y * wstride;
    float* Hk = H + blockIdx.y * hstride;
    float a[28];
    const float* ar = A + n * 28;
#pragma unroll
    for (int i = 0; i < 28; ++i) a[i] = ar[i];
    float acc[8];
#pragma unroll
    for (int j = 0; j < 8; ++j) acc[j] = 0.f;
    for (int f = 0; f < 28; ++f) {
        const float* wr = Wk + f * HA + c0;
        float4 w0 = *(const float4*)wr, w1 = *(const float4*)(wr + 4);
        float av = a[f];
        acc[0] += av * w0.x; acc[1] += av * w0.y; acc[2] += av * w0.z; acc[3] += av * w0.w;
        acc[4] += av * w1.x; acc[5] += av * w1.y; acc[6] += av * w1.z; acc[7] += av * w1.w;
    }
    float* hp = Hk + n * HA + c0;
    *(float4*)hp       = make_float4(acc[0], acc[1], acc[2], acc[3]);
    *(float4*)(hp + 4) = make_float4(acc[4], acc[5], acc[6], acc[7]);
}

__global__ __launch_bounds__(256) void arma_gemm128(
    const float* __restrict__ A, size_t astride,
    const float* __restrict__ W, size_t wstride,
    float* __restrict__ H, size_t hstride) {
    __shared__ float Al[16][HA + 1];
    const float* Ak = A + blockIdx.y * astride;
    const float* Wk = W + blockIdx.y * wstride;
    float* Hk = H + blockIdx.y * hstride;
    int row0 = blockIdx.x * 16;
    for (int t = threadIdx.x; t < 16 * HA; t += 256)
        Al[t >> 7][t & 127] = Ak[(size_t)(row0 + (t >> 7)) * HA + (t & 127)];
    __syncthreads();
    int r = threadIdx.x >> 4, c0 = (threadIdx.x & 15) * 8;
    float acc[8];
#pragma unroll
    for (int j = 0; j < 8; ++j) acc[j] = 0.f;
    for (int f = 0; f < HA; ++f) {
        float av = Al[r][f];
        const float* wr = Wk + f * HA + c0;
        float4 w0 = *(const float4*)wr, w1 = *(const float4*)(wr + 4);
        acc[0] += av * w0.x; acc[1] += av * w0.y; acc[2] += av * w0.z; acc[3] += av * w0.w;
        acc[4] += av * w1.x; acc[5] += av * w1.y; acc[6] += av * w1.z; acc[7] += av * w1.w;
    }
    float* hp = Hk + (size_t)(row0 + r) * HA + c0;
    *(float4*)hp       = make_float4(acc[0], acc[1], acc[2], acc[3]);
    *(float4*)(hp + 4) = make_float4(acc[4], acc[5], acc[6], acc[7]);
}

__global__ __launch_bounds__(256) void arma_out(
    const float* __restrict__ H, size_t hstride,
    const float* __restrict__ aa,
    const float* __restrict__ rw, size_t rstride,
    const float* __restrict__ bw, size_t bstride,
    const int* __restrict__ aei, const int* __restrict__ aoff,
    const int* __restrict__ aeid, const float* __restrict__ nrm,
    float* __restrict__ O, size_t ostride,
    const int* __restrict__ bat, float* __restrict__ g) {
    int t = blockIdx.x * 256 + threadIdx.x;
    int n = t >> 4, c0 = (t & 15) * 8;
    const float* Hk = H + blockIdx.y * hstride;
    const float* rwk = rw + blockIdx.y * rstride;
    const float* bwk = bw + blockIdx.y * bstride;
    float* Ok = O + blockIdx.y * ostride;
    float acc[8];
#pragma unroll
    for (int j = 0; j < 8; ++j) acc[j] = bwk[c0 + j];
    int j1 = aoff[n + 1];
    for (int jj = aoff[n]; jj < j1; ++jj) {
        int e = aeid[jj], s = aei[e];
        float nm = nrm[e];
        const float* hr = Hk + (size_t)s * HA + c0;
#pragma unroll
        for (int j = 0; j < 8; ++j) acc[j] += nm * hr[j];
    }
    float a[28];
    const float* ar = aa + n * 28;
#pragma unroll
    for (int i = 0; i < 28; ++i) a[i] = ar[i];
    for (int f = 0; f < 28; ++f) {
        const float* wr = rwk + f * HA + c0;
        float4 w0 = *(const float4*)wr, w1 = *(const float4*)(wr + 4);
        float av = a[f];
        acc[0] += av * w0.x; acc[1] += av * w0.y; acc[2] += av * w0.z; acc[3] += av * w0.w;
        acc[4] += av * w1.x; acc[5] += av * w1.y; acc[6] += av * w1.z; acc[7] += av * w1.w;
    }
#pragma unroll
    for (int j = 0; j < 8; ++j) acc[j] = fmaxf(acc[j], 0.f);
    float* op = Ok + (size_t)n * HA + c0;
    *(float4*)op       = make_float4(acc[0], acc[1], acc[2], acc[3]);
    *(float4*)(op + 4) = make_float4(acc[4], acc[5], acc[6], acc[7]);
    if (bat) {
        float* gp = g + (size_t)bat[n] * HA + c0;
#pragma unroll
        for (int j = 0; j < 8; ++j) atomicAdd(gp + j, acc[j] * (1.f / 3.f));
    }
}

// ---------------------------------------------------------------------------
__global__ __launch_bounds__(256) void head(
    const float* __restrict__ g,
    const float* __restrict__ l1w, const float* __restrict__ l1b,
    const float* __restrict__ l2w, const float* __restrict__ l2b,
    const float* __restrict__ l3w, const float* __restrict__ l3b,
    const float* __restrict__ l4w, const float* __restrict__ l4b,
    float* __restrict__ outp) {
    __shared__ float sg[HA], sp1[F1], sp2[F2], sp3[F3];
    int b = blockIdx.x, tx = threadIdx.x;
    if (tx < HA) sg[tx] = g[b * HA + tx];
    __syncthreads();
    {   float acc = l1b[tx];
        for (int f = 0; f < HA; ++f) acc += sg[f] * l1w[f * F1 + tx];
        sp1[tx] = fmaxf(acc, 0.f); }
    __syncthreads();
    if (tx < F2) {
        float acc = l2b[tx];
        for (int f = 0; f < F1; ++f) acc += sp1[f] * l2w[f * F2 + tx];
        sp2[tx] = fmaxf(acc, 0.f); }
    __syncthreads();
    if (tx < F3) {
        float acc = l3b[tx];
        for (int f = 0; f < F2; ++f) acc += sp2[f] * l3w[f * F3 + tx];
        sp3[tx] = fmaxf(acc, 0.f); }
    __syncthreads();
    if (tx < 64) {
        float p = sp3[tx] * l4w[tx];
        for (int off = 32; off > 0; off >>= 1) p += __shfl_down(p, off, 64);
        if (tx == 0) outp[b] = p + l4b[0];
    }
}

// ---------------------------------------------------------------------------
// Workspace. Base = 10,891,008 B; ARMA seq total 13,376,768 (proven round 6);
// K-parallel total 34,348,288 used only when ws_size allows.
#define OFF_M1   ((size_t)0)
#define OFF_M2   ((size_t)38400)
#define OFF_M3   ((size_t)57600)
#define OFF_DOFF ((size_t)76800)
#define OFF_DEID ((size_t)476928)
#define OFF_AOFF ((size_t)1276928)
#define OFF_AEID ((size_t)1318144)
#define OFF_NRM  ((size_t)1400064)
#define OFF_AA   ((size_t)1481984)
#define OFF_G    ((size_t)2628864)
#define OFF_HA   ((size_t)2891008)          // bf16 h1 (4,000,000)
#define OFF_HB   ((size_t)6891008)          // bf16 h2 (4,000,000)
// CSR-build scratch overlays hA (dead until layer-1 output)
#define OFF_CNT  (OFF_HA)
#define OFF_CUR  (OFF_HA + 400128)
#define OFF_ACNT (OFF_HA + 800256)
#define OFF_ACUR (OFF_HA + 841472)
#define OFF_BSUM (OFF_HA + 882688)          // 108 ints
// ARMA overlays
#define OFF_H    (OFF_HA)
#define SZ_K1    ((size_t)N_AMINO * HA * 4)
#define SZ_K3    (SZ_K1 * KS)
#define WS_PAR   (OFF_H + 2 * SZ_K3)

extern "C" void kernel_launch(void* const* d_in, const int* in_sizes, int n_in,
                              void* d_out, int out_size, void* d_ws, size_t ws_size,
                              hipStream_t stream) {
    (void)in_sizes; (void)n_in; (void)out_size;
    const float* x   = (const float*)d_in[0];
    const int*   ei  = (const int*)d_in[1];
    const float* ea  = (const float*)d_in[2];
    const int*   lbl = (const int*)d_in[3];
    const float* af  = (const float*)d_in[4];
    const int*   aei = (const int*)d_in[5];
    const int*   bat = (const int*)d_in[6];
    const float* nn1w = (const float*)d_in[7];  const float* nn1b = (const float*)d_in[8];
    const float* rt1  = (const float*)d_in[9];  const float* b1   = (const float*)d_in[10];
    const float* nn2w = (const float*)d_in[11]; const float* nn2b = (const float*)d_in[12];
    const float* rt2  = (const float*)d_in[13]; const float* b2   = (const float*)d_in[14];
    const float* nn3w = (const float*)d_in[15]; const float* nn3b = (const float*)d_in[16];
    const float* rt3  = (const float*)d_in[17]; const float* b3   = (const float*)d_in[18];
    const float* ai   = (const float*)d_in[19]; const float* aw   = (const float*)d_in[20];
    const float* arw  = (const float*)d_in[21]; const float* abi  = (const float*)d_in[22];
    const float* l1w  = (const float*)d_in[23]; const float* l1b  = (const float*)d_in[24];
    const float* l2w  = (const float*)d_in[25]; const float* l2b  = (const float*)d_in[26];
    const float* l3w  = (const float*)d_in[27]; const float* l3b  = (const float*)d_in[28];
    const float* l4w  = (const float*)d_in[29]; const float* l4b  = (const float*)d_in[30];
    float* outp = (float*)d_out;

    char* ws = (char*)d_ws;
    float* M1   = (float*)(ws + OFF_M1);
    float* M2   = (float*)(ws + OFF_M2);
    float* M3   = (float*)(ws + OFF_M3);
    int*   doff = (int*)(ws + OFF_DOFF);
    int*   deid = (int*)(ws + OFF_DEID);
    int*   aoff = (int*)(ws + OFF_AOFF);
    int*   aeid = (int*)(ws + OFF_AEID);
    float* nrm  = (float*)(ws + OFF_NRM);
    float* aa   = (float*)(ws + OFF_AA);
    float* g    = (float*)(ws + OFF_G);
    u16*   hA   = (u16*)(ws + OFF_HA);
    u16*   hB   = (u16*)(ws + OFF_HB);
    int*   cnt  = (int*)(ws + OFF_CNT);
    int*   cur  = (int*)(ws + OFF_CUR);
    int*   acnt = (int*)(ws + OFF_ACNT);
    int*   acur = (int*)(ws + OFF_ACUR);
    int*   bsum = (int*)(ws + OFF_BSUM);
    float* Hb   = (float*)(ws + OFF_H);

    const int* edst = ei + E_ATOMS;
    const int* adst = aei + E_AMINO;
    const bool par = ws_size >= WS_PAR;
    const size_t osz = par ? SZ_K3 : SZ_K1;
    float* Ob = (float*)(ws + OFF_H + osz);

    // prep (7 launches; scan now hierarchical/parallel)
    k_prep0<<<(19200 + N_AMINO + NGRAPH * HA + 255) / 256, 256, 0, stream>>>(
        nn1w, nn1b, nn2w, nn2b, nn3w, nn3b, M1, M2, M3, af, aa, g);
    k_csr_zero<<<(N_ATOMS + N_AMINO + 255) / 256, 256, 0, stream>>>(cnt, acnt);
    k_csr_count<<<(E_ATOMS + E_AMINO + 255) / 256, 256, 0, stream>>>(edst, adst, cnt, acnt);
    k_scan1<<<NB_ATOM + NB_AM, 256, 0, stream>>>(cnt, doff, acnt, aoff, bsum);
    k_scan2<<<2, 128, 0, stream>>>(bsum, doff, aoff);
    k_scan3<<<NB_ATOM + NB_AM, 256, 0, stream>>>(doff, aoff, bsum, cur, acur);
    k_csr_fill<<<(E_ATOMS + 2 * E_AMINO + 255) / 256, 256, 0, stream>>>(
        edst, cur, deid, aei, acur, aeid, aoff, nrm);

    // NNConv (3 launches, wave-per-node)
    nnconv_gather<DIN0, true,  false><<<2048, 256, 0, stream>>>(
        x,  ea, ei, doff, deid, M1, rt1, b1, hA, nullptr, nullptr);
    nnconv_gather<HD,   false, false><<<2048, 256, 0, stream>>>(
        hA, ea, ei, doff, deid, M2, rt2, b2, hB, nullptr, nullptr);
    nnconv_gather<HD,   false, true ><<<2048, 256, 0, stream>>>(
        hB, ea, ei, doff, deid, M3, rt3, b3, nullptr, aa, lbl);

    // ARMA
    const size_t KH = (size_t)N_AMINO * HA;
    if (par) {
        for (int t = 0; t < TL; ++t) {
            if (t == 0)
                arma_gemm28<<<dim3(640, KS), 256, 0, stream>>>(aa, ai, 28 * HA, Hb, KH);
            else
                arma_gemm128<<<dim3(640, KS), 256, 0, stream>>>(
                    Ob, KH, aw + (size_t)(t - 1) * KS * HA * HA, HA * HA, Hb, KH);
            arma_out<<<dim3(640, KS), 256, 0, stream>>>(
                Hb, KH, aa, arw + (size_t)t * KS * 28 * HA, 28 * HA,
                abi + (size_t)t * KS * HA, HA, aei, aoff, aeid, nrm, Ob, KH,
                (t == TL - 1) ? bat : (const int*)nullptr, g);
        }
    } else {
        for (int k = 0; k < KS; ++k) {
            for (int t = 0; t < TL; ++t) {
                if (t == 0)
                    arma_gemm28<<<dim3(640, 1), 256, 0, stream>>>(
                        aa, ai + (size_t)k * 28 * HA, 0, Hb, 0);
                else
                    arma_gemm128<<<dim3(640, 1), 256, 0, stream>>>(
                        Ob, 0, aw + (size_t)((t - 1) * KS + k) * HA * HA, 0, Hb, 0);
                arma_out<<<dim3(640, 1), 256, 0, stream>>>(
                    Hb, 0, aa, arw + (size_t)(t * KS + k) * 28 * HA, 0,
                    abi + (size_t)(t * KS + k) * HA, 0, aei, aoff, aeid, nrm, Ob, 0,
                    (t == TL - 1) ? bat : (const int*)nullptr, g);
            }
        }
    }

    head<<<NGRAPH, 256, 0, stream>>>(g, l1w, l1b, l2w, l2b, l3w, l3b, l4w, l4b, outp);
}

// Round 9
// 1206.846 us; speedup vs baseline: 1.9169x; 1.0641x over previous
//
#include <hip/hip_runtime.h>

#define N_ATOMS 100000
#define E_ATOMS 200000
#define N_AMINO 10240
#define E_AMINO 20480
#define NGRAPH 512
#define DIN0 40
#define D_E 11
#define HD 20
#define D_AA 8
#define HA 128
#define KS 3
#define TL 7
#define F1 256
#define F2 128
#define F3 64

#define NB_ATOM 98   // ceil(N_ATOMS/1024)
#define NB_AM   10   // ceil(N_AMINO/1024)
#define TILE 64      // nodes per block in nnconv_tile

typedef unsigned short u16;
typedef unsigned int u32;

__device__ __forceinline__ float b2f(u16 u) {
    union { u32 i; float f; } v; v.i = ((u32)u) << 16; return v.f;
}
__device__ __forceinline__ u16 f2b(float f) {
    union { float f; u32 i; } v; v.f = f;
    u32 x = v.i;
    return (u16)((x + (((x >> 16) & 1u) + 0x7fffu)) >> 16);
}

// ---------------------------------------------------------------------------
// prep0: build M matrices + init aa + zero g (+ zero agg on fast path).
__global__ __launch_bounds__(256) void k_prep0(
    const float* __restrict__ w1, const float* __restrict__ b1,
    const float* __restrict__ w2, const float* __restrict__ b2,
    const float* __restrict__ w3, const float* __restrict__ b3,
    float* __restrict__ M1, float* __restrict__ M2, float* __restrict__ M3,
    const float* __restrict__ af, float* __restrict__ aa, float* __restrict__ g,
    float* __restrict__ agg, int nagg) {
    int t = blockIdx.x * 256 + threadIdx.x;
    if (t < 9600) {
        int i = t / 240, c = t % 240;
        M1[t] = (c < 220) ? w1[(c / 20) * 800 + i * 20 + (c % 20)] : b1[i * 20 + (c - 220)];
    } else if (t < 14400) {
        int tt = t - 9600, i = tt / 240, c = tt % 240;
        M2[tt] = (c < 220) ? w2[(c / 20) * 400 + i * 20 + (c % 20)] : b2[i * 20 + (c - 220)];
    } else if (t < 19200) {
        int tt = t - 14400, i = tt / 240, c = tt % 240;
        M3[tt] = (c < 220) ? w3[(c / 20) * 400 + i * 20 + (c % 20)] : b3[i * 20 + (c - 220)];
    } else if (t < 19200 + N_AMINO) {
        int n = t - 19200;
        float* r = aa + n * 28;
#pragma unroll
        for (int o = 0; o < HD; ++o) r[o] = 0.f;
#pragma unroll
        for (int j = 0; j < D_AA; ++j) r[HD + j] = af[n * D_AA + j];
    } else if (t < 19200 + N_AMINO + NGRAPH * HA) {
        g[t - 19200 - N_AMINO] = 0.f;
    } else if (t < 19200 + N_AMINO + NGRAPH * HA + nagg) {
        agg[t - 19200 - N_AMINO - NGRAPH * HA] = 0.f;
    }
}

// ---------------------------------------------------------------------------
// CSR build (key = src on fast path, dst on fallback; amino always dst)
__global__ __launch_bounds__(256) void k_csr_zero(int* __restrict__ cnt,
                                                  int* __restrict__ acnt) {
    int t = blockIdx.x * 256 + threadIdx.x;
    if (t < N_ATOMS) cnt[t] = 0;
    else if (t < N_ATOMS + N_AMINO) acnt[t - N_ATOMS] = 0;
}
__global__ __launch_bounds__(256) void k_csr_count(
    const int* __restrict__ ekey, const int* __restrict__ adst,
    int* __restrict__ cnt, int* __restrict__ acnt) {
    int t = blockIdx.x * 256 + threadIdx.x;
    if (t < E_ATOMS) atomicAdd(cnt + ekey[t], 1);
    else if (t < E_ATOMS + E_AMINO) atomicAdd(acnt + adst[t - E_ATOMS], 1);
}
__global__ __launch_bounds__(256) void k_scan1(
    const int* __restrict__ cnt, int* __restrict__ off,
    const int* __restrict__ acnt, int* __restrict__ aoff,
    int* __restrict__ bsum) {
    bool atom = blockIdx.x < NB_ATOM;
    const int* c = atom ? cnt : acnt;
    int* o = atom ? off : aoff;
    int n = atom ? N_ATOMS : N_AMINO;
    int blk = atom ? blockIdx.x : blockIdx.x - NB_ATOM;
    int tx = threadIdx.x, lane = tx & 63, w = tx >> 6;
    int i0 = blk * 1024 + tx * 4;
    int v[4];
#pragma unroll
    for (int q = 0; q < 4; ++q) v[q] = (i0 + q < n) ? c[i0 + q] : 0;
    int s = v[0] + v[1] + v[2] + v[3];
    int inc = s;
#pragma unroll
    for (int d = 1; d < 64; d <<= 1) {
        int u = __shfl_up(inc, d, 64);
        if (lane >= d) inc += u;
    }
    __shared__ int wsum[4];
    if (lane == 63) wsum[w] = inc;
    __syncthreads();
    int wo = 0;
    for (int i = 0; i < w; ++i) wo += wsum[i];
    int run = wo + inc - s;
#pragma unroll
    for (int q = 0; q < 4; ++q) {
        if (i0 + q < n) o[i0 + q] = run;
        run += v[q];
    }
    if (tx == 255) bsum[blockIdx.x] = wo + inc;
}
__global__ __launch_bounds__(128) void k_scan2(int* __restrict__ bsum,
                                               int* __restrict__ off,
                                               int* __restrict__ aoff) {
    int nb = blockIdx.x ? NB_AM : NB_ATOM;
    int* b = bsum + (blockIdx.x ? NB_ATOM : 0);
    int tx = threadIdx.x, lane = tx & 63;
    int v = (tx < nb) ? b[tx] : 0;
    int inc = v;
#pragma unroll
    for (int d = 1; d < 64; d <<= 1) {
        int u = __shfl_up(inc, d, 64);
        if (lane >= d) inc += u;
    }
    __shared__ int w0;
    if (tx == 63) w0 = inc;
    __syncthreads();
    int excl = inc - v + ((tx >= 64) ? w0 : 0);
    if (tx < nb) b[tx] = excl;
    if (tx == nb - 1) {
        int tot = excl + v;
        if (blockIdx.x) aoff[N_AMINO] = tot; else off[N_ATOMS] = tot;
    }
}
__global__ __launch_bounds__(256) void k_scan3(
    int* __restrict__ off, int* __restrict__ aoff,
    const int* __restrict__ bsum, int* __restrict__ cur, int* __restrict__ acur) {
    bool atom = blockIdx.x < NB_ATOM;
    int* o  = atom ? off : aoff;
    int* cu = atom ? cur : acur;
    int n = atom ? N_ATOMS : N_AMINO;
    int blk = atom ? blockIdx.x : blockIdx.x - NB_ATOM;
    int add = bsum[blockIdx.x];
    int i0 = blk * 1024 + threadIdx.x * 4;
#pragma unroll
    for (int q = 0; q < 4; ++q)
        if (i0 + q < n) { int val = o[i0 + q] + add; o[i0 + q] = val; cu[i0 + q] = val; }
}
__global__ __launch_bounds__(256) void k_csr_fill(
    const int* __restrict__ ekey, int* __restrict__ cur, int* __restrict__ eid,
    const int* __restrict__ aei, int* __restrict__ acur, int* __restrict__ aeid,
    const int* __restrict__ aoff, float* __restrict__ nrm) {
    int t = blockIdx.x * 256 + threadIdx.x;
    if (t < E_ATOMS) {
        int p = atomicAdd(cur + ekey[t], 1);
        eid[p] = t;
    } else if (t < E_ATOMS + E_AMINO) {
        int e = t - E_ATOMS;
        int p = atomicAdd(acur + aei[E_AMINO + e], 1);
        aeid[p] = e;
    } else if (t < E_ATOMS + 2 * E_AMINO) {
        int e = t - E_ATOMS - E_AMINO;
        int s = aei[e], d = aei[E_AMINO + e];
        int ds = aoff[s + 1] - aoff[s], dd = aoff[d + 1] - aoff[d];
        float a = ds > 0 ? rsqrtf((float)ds) : 0.f;
        float b = dd > 0 ? rsqrtf((float)dd) : 0.f;
        nrm[e] = a * b;
    }
}

// ---------------------------------------------------------------------------
// FAST PATH NNConv: tiled node-parallel. Block = 64-node tile.
// Phase 1: thread c (<240) holds M[:,c] in regs; y[nl][c] = x[n]@M[:,c] -> LDS.
// Phase 2: walk src-CSR edge range of the tile; msg -> atomicAdd agg[dst].
template <int DIN, bool RAW>
__global__ __launch_bounds__(256) void nnconv_tile(
    const void* __restrict__ xin, const float* __restrict__ ea,
    const int* __restrict__ esrc, const int* __restrict__ edst,
    const int* __restrict__ soff, const int* __restrict__ seid,
    const float* __restrict__ Mg, float* __restrict__ agg) {
    __shared__ float y[TILE * 240];
    int tx = threadIdx.x;
    int n0 = blockIdx.x * TILE;
    int nT = min(TILE, N_ATOMS - n0);
    float m[DIN];
    if (tx < 240) {
#pragma unroll
        for (int i = 0; i < DIN; ++i) m[i] = Mg[i * 240 + tx];
        for (int nl = 0; nl < nT; ++nl) {
            const float* xf = (const float*)xin + (size_t)(n0 + nl) * DIN;
            const u16*   xb = (const u16*)xin + (size_t)(n0 + nl) * DIN;
            float acc = 0.f;
#pragma unroll
            for (int i = 0; i < DIN; ++i)
                acc += (RAW ? xf[i] : b2f(xb[i])) * m[i];
            y[nl * 240 + tx] = acc;
        }
    }
    __syncthreads();
    int j0 = soff[n0], j1 = soff[n0 + nT];
    if (tx < 240) {
        int o = tx % 20;
        for (int jj = j0 + tx / 20; jj < j1; jj += 12) {
            int e = seid[jj];
            int s = esrc[e], d = edst[e];
            int sl = s - n0;
            const float* er = ea + (size_t)e * D_E;
            float msg = y[sl * 240 + 220 + o];
#pragma unroll
            for (int k = 0; k < D_E; ++k) msg += er[k] * y[sl * 240 + k * HD + o];
            atomicAdd(agg + (size_t)d * HD + o, msg);
        }
    }
}

// finish: h[n,o] = relu(agg + x@root + bias); zeroes agg for next layer.
// FUSE: scatter into aa instead of writing h.
template <int DIN, bool RAW, bool FUSE>
__global__ __launch_bounds__(256) void nnconv_finish2(
    const void* __restrict__ xin, const float* __restrict__ root,
    const float* __restrict__ bias, float* __restrict__ agg,
    u16* __restrict__ hout, float* __restrict__ aa, const int* __restrict__ lbl) {
    __shared__ float Rl[DIN * HD + HD];
    for (int t = threadIdx.x; t < DIN * HD; t += 256) Rl[t] = root[t];
    if (threadIdx.x < HD) Rl[DIN * HD + threadIdx.x] = bias[threadIdx.x];
    __syncthreads();
    int t = blockIdx.x * 256 + threadIdx.x;
    if (t >= N_ATOMS * HD) return;
    int n = t / HD, o = t % HD;
    float acc = agg[t] + Rl[DIN * HD + o];
    agg[t] = 0.f;
    const float* xf = (const float*)xin + (size_t)n * DIN;
    const u16*   xb = (const u16*)xin + (size_t)n * DIN;
#pragma unroll
    for (int i = 0; i < DIN; ++i)
        acc += (RAW ? xf[i] : b2f(xb[i])) * Rl[i * HD + o];
    float v = fmaxf(acc, 0.f);
    if (FUSE) atomicAdd(aa + (size_t)lbl[n] * 28 + o, v);
    else hout[t] = f2b(v);
}

// ---------------------------------------------------------------------------
// FALLBACK NNConv (round-8 proven): one wave per dst node, dst-CSR.
template <int DIN, bool RAW, bool FUSE>
__global__ __launch_bounds__(256) void nnconv_gather(
    const void* __restrict__ xin, const float* __restrict__ ea,
    const int* __restrict__ esrc, const int* __restrict__ doff,
    const int* __restrict__ deid, const float* __restrict__ Mg,
    const float* __restrict__ root, const float* __restrict__ bias,
    u16* __restrict__ hout, float* __restrict__ aa, const int* __restrict__ lbl) {
    __shared__ float Ml[DIN * 240];
    __shared__ float Rl[DIN * HD + HD];
    __shared__ float yl[4][240];
    for (int t = threadIdx.x; t < DIN * 240; t += 256) Ml[t] = Mg[t];
    for (int t = threadIdx.x; t < DIN * HD; t += 256) Rl[t] = root[t];
    if (threadIdx.x < HD) Rl[DIN * HD + threadIdx.x] = bias[threadIdx.x];
    __syncthreads();
    int wave = threadIdx.x >> 6, lane = threadIdx.x & 63;
    int c0 = lane * 4;
    float* yw = yl[wave];
    for (int grp = blockIdx.x; grp < N_ATOMS / 4; grp += gridDim.x) {
        int n = __builtin_amdgcn_readfirstlane(grp * 4 + wave);
        int j0 = doff[n], j1 = doff[n + 1];
        float acc = 0.f;
        for (int j = j0; j < j1; ++j) {
            int e = deid[j];
            int s = esrc[e];
            if (lane < 60) {
                float y0 = 0.f, y1 = 0.f, y2 = 0.f, y3 = 0.f;
                const float* xf = (const float*)xin + (size_t)s * DIN;
                const u16*   xb = (const u16*)xin + (size_t)s * DIN;
#pragma unroll
                for (int i = 0; i < DIN; ++i) {
                    float xv = RAW ? xf[i] : b2f(xb[i]);
                    float4 m = *(const float4*)&Ml[i * 240 + c0];
                    y0 += xv * m.x; y1 += xv * m.y; y2 += xv * m.z; y3 += xv * m.w;
                }
                *(float4*)&yw[c0] = make_float4(y0, y1, y2, y3);
            }
            __builtin_amdgcn_wave_barrier();
            if (lane < HD) {
                const float* er = ea + (size_t)e * D_E;
                float m = yw[220 + lane];
#pragma unroll
                for (int k = 0; k < D_E; ++k) m += er[k] * yw[k * HD + lane];
                acc += m;
            }
            __builtin_amdgcn_wave_barrier();
        }
        if (lane < HD) {
            float r = Rl[DIN * HD + lane];
            const float* xf = (const float*)xin + (size_t)n * DIN;
            const u16*   xb = (const u16*)xin + (size_t)n * DIN;
#pragma unroll
            for (int i = 0; i < DIN; ++i) {
                float xv = RAW ? xf[i] : b2f(xb[i]);
                r += xv * Rl[i * HD + lane];
            }
            float v = fmaxf(acc + r, 0.f);
            if (FUSE) atomicAdd(aa + (size_t)lbl[n] * 28 + lane, v);
            else hout[(size_t)n * HD + lane] = f2b(v);
        }
    }
}

// ---------------------------------------------------------------------------
// ARMA (unchanged from round 8)
__global__ __launch_bounds__(256) void arma_gemm28(
    const float* __restrict__ A, const float* __restrict__ W, size_t wstride,
    float* __restrict__ H, size_t hstride) {
    int t = blockIdx.x * 256 + threadIdx.x;
    int n = t >> 4, c0 = (t & 15) * 8;
    const float* Wk = W + blockIdx.y * wstride;
    float* Hk = H + blockIdx.y * hstride;
    float a[28];
    const float* ar = A + n * 28;
#pragma unroll
    for (int i = 0; i < 28; ++i) a[i] = ar[i];
    float acc[8];
#pragma unroll
    for (int j = 0; j < 8; ++j) acc[j] = 0.f;
    for (int f = 0; f < 28; ++f) {
        const float* wr = Wk + f * HA + c0;
        float4 w0 = *(const float4*)wr, w1 = *(const float4*)(wr + 4);
        float av = a[f];
        acc[0] += av * w0.x; acc[1] += av * w0.y; acc[2] += av * w0.z; acc[3] += av * w0.w;
        acc[4] += av * w1.x; acc[5] += av * w1.y; acc[6] += av * w1.z; acc[7] += av * w1.w;
    }
    float* hp = Hk + n * HA + c0;
    *(float4*)hp       = make_float4(acc[0], acc[1], acc[2], acc[3]);
    *(float4*)(hp + 4) = make_float4(acc[4], acc[5], acc[6], acc[7]);
}

__global__ __launch_bounds__(256) void arma_gemm128(
    const float* __restrict__ A, size_t astride,
    const float* __restrict__ W, size_t wstride,
    float* __restrict__ H, size_t hstride) {
    __shared__ float Al[16][HA + 1];
    const float* Ak = A + blockIdx.y * astride;
    const float* Wk = W + blockIdx.y * wstride;
    float* Hk = H + blockIdx.y * hstride;
    int row0 = blockIdx.x * 16;
    for (int t = threadIdx.x; t < 16 * HA; t += 256)
        Al[t >> 7][t & 127] = Ak[(size_t)(row0 + (t >> 7)) * HA + (t & 127)];
    __syncthreads();
    int r = threadIdx.x >> 4, c0 = (threadIdx.x & 15) * 8;
    float acc[8];
#pragma unroll
    for (int j = 0; j < 8; ++j) acc[j] = 0.f;
    for (int f = 0; f < HA; ++f) {
        float av = Al[r][f];
        const float* wr = Wk + f * HA + c0;
        float4 w0 = *(const float4*)wr, w1 = *(const float4*)(wr + 4);
        acc[0] += av * w0.x; acc[1] += av * w0.y; acc[2] += av * w0.z; acc[3] += av * w0.w;
        acc[4] += av * w1.x; acc[5] += av * w1.y; acc[6] += av * w1.z; acc[7] += av * w1.w;
    }
    float* hp = Hk + (size_t)(row0 + r) * HA + c0;
    *(float4*)hp       = make_float4(acc[0], acc[1], acc[2], acc[3]);
    *(float4*)(hp + 4) = make_float4(acc[4], acc[5], acc[6], acc[7]);
}

__global__ __launch_bounds__(256) void arma_out(
    const float* __restrict__ H, size_t hstride,
    const float* __restrict__ aa,
    const float* __restrict__ rw, size_t rstride,
    const float* __restrict__ bw, size_t bstride,
    const int* __restrict__ aei, const int* __restrict__ aoff,
    const int* __restrict__ aeid, const float* __restrict__ nrm,
    float* __restrict__ O, size_t ostride,
    const int* __restrict__ bat, float* __restrict__ g) {
    int t = blockIdx.x * 256 + threadIdx.x;
    int n = t >> 4, c0 = (t & 15) * 8;
    const float* Hk = H + blockIdx.y * hstride;
    const float* rwk = rw + blockIdx.y * rstride;
    const float* bwk = bw + blockIdx.y * bstride;
    float* Ok = O + blockIdx.y * ostride;
    float acc[8];
#pragma unroll
    for (int j = 0; j < 8; ++j) acc[j] = bwk[c0 + j];
    int j1 = aoff[n + 1];
    for (int jj = aoff[n]; jj < j1; ++jj) {
        int e = aeid[jj], s = aei[e];
        float nm = nrm[e];
        const float* hr = Hk + (size_t)s * HA + c0;
#pragma unroll
        for (int j = 0; j < 8; ++j) acc[j] += nm * hr[j];
    }
    float a[28];
    const float* ar = aa + n * 28;
#pragma unroll
    for (int i = 0; i < 28; ++i) a[i] = ar[i];
    for (int f = 0; f < 28; ++f) {
        const float* wr = rwk + f * HA + c0;
        float4 w0 = *(const float4*)wr, w1 = *(const float4*)(wr + 4);
        float av = a[f];
        acc[0] += av * w0.x; acc[1] += av * w0.y; acc[2] += av * w0.z; acc[3] += av * w0.w;
        acc[4] += av * w1.x; acc[5] += av * w1.y; acc[6] += av * w1.z; acc[7] += av * w1.w;
    }
#pragma unroll
    for (int j = 0; j < 8; ++j) acc[j] = fmaxf(acc[j], 0.f);
    float* op = Ok + (size_t)n * HA + c0;
    *(float4*)op       = make_float4(acc[0], acc[1], acc[2], acc[3]);
    *(float4*)(op + 4) = make_float4(acc[4], acc[5], acc[6], acc[7]);
    if (bat) {
        float* gp = g + (size_t)bat[n] * HA + c0;
#pragma unroll
        for (int j = 0; j < 8; ++j) atomicAdd(gp + j, acc[j] * (1.f / 3.f));
    }
}

// ---------------------------------------------------------------------------
__global__ __launch_bounds__(256) void head(
    const float* __restrict__ g,
    const float* __restrict__ l1w, const float* __restrict__ l1b,
    const float* __restrict__ l2w, const float* __restrict__ l2b,
    const float* __restrict__ l3w, const float* __restrict__ l3b,
    const float* __restrict__ l4w, const float* __restrict__ l4b,
    float* __restrict__ outp) {
    __shared__ float sg[HA], sp1[F1], sp2[F2], sp3[F3];
    int b = blockIdx.x, tx = threadIdx.x;
    if (tx < HA) sg[tx] = g[b * HA + tx];
    __syncthreads();
    {   float acc = l1b[tx];
        for (int f = 0; f < HA; ++f) acc += sg[f] * l1w[f * F1 + tx];
        sp1[tx] = fmaxf(acc, 0.f); }
    __syncthreads();
    if (tx < F2) {
        float acc = l2b[tx];
        for (int f = 0; f < F1; ++f) acc += sp1[f] * l2w[f * F2 + tx];
        sp2[tx] = fmaxf(acc, 0.f); }
    __syncthreads();
    if (tx < F3) {
        float acc = l3b[tx];
        for (int f = 0; f < F2; ++f) acc += sp2[f] * l3w[f * F3 + tx];
        sp3[tx] = fmaxf(acc, 0.f); }
    __syncthreads();
    if (tx < 64) {
        float p = sp3[tx] * l4w[tx];
        for (int off = 32; off > 0; off >>= 1) p += __shfl_down(p, off, 64);
        if (tx == 0) outp[b] = p + l4b[0];
    }
}

// ---------------------------------------------------------------------------
// Workspace. Base 10,891,008. Fast path adds agg (8 MB) -> 18,891,008.
// ARMA overlays (time-disjoint with agg/h): seq 13,376,768 / par 34,348,288.
#define OFF_M1   ((size_t)0)
#define OFF_M2   ((size_t)38400)
#define OFF_M3   ((size_t)57600)
#define OFF_DOFF ((size_t)76800)
#define OFF_DEID ((size_t)476928)
#define OFF_AOFF ((size_t)1276928)
#define OFF_AEID ((size_t)1318144)
#define OFF_NRM  ((size_t)1400064)
#define OFF_AA   ((size_t)1481984)
#define OFF_G    ((size_t)2628864)
#define OFF_HA   ((size_t)2891008)
#define OFF_HB   ((size_t)6891008)
#define OFF_AGG  ((size_t)10891008)
#define WS_TILE  (OFF_AGG + (size_t)N_ATOMS * HD * 4)   // 18,891,008
// CSR-build scratch overlays hA (dead until layer-1 output)
#define OFF_CNT  (OFF_HA)
#define OFF_CUR  (OFF_HA + 400128)
#define OFF_ACNT (OFF_HA + 800256)
#define OFF_ACUR (OFF_HA + 841472)
#define OFF_BSUM (OFF_HA + 882688)
// ARMA overlays
#define OFF_H    (OFF_HA)
#define SZ_K1    ((size_t)N_AMINO * HA * 4)
#define SZ_K3    (SZ_K1 * KS)
#define WS_PAR   (OFF_H + 2 * SZ_K3)

extern "C" void kernel_launch(void* const* d_in, const int* in_sizes, int n_in,
                              void* d_out, int out_size, void* d_ws, size_t ws_size,
                              hipStream_t stream) {
    (void)in_sizes; (void)n_in; (void)out_size;
    const float* x   = (const float*)d_in[0];
    const int*   ei  = (const int*)d_in[1];
    const float* ea  = (const float*)d_in[2];
    const int*   lbl = (const int*)d_in[3];
    const float* af  = (const float*)d_in[4];
    const int*   aei = (const int*)d_in[5];
    const int*   bat = (const int*)d_in[6];
    const float* nn1w = (const float*)d_in[7];  const float* nn1b = (const float*)d_in[8];
    const float* rt1  = (const float*)d_in[9];  const float* b1   = (const float*)d_in[10];
    const float* nn2w = (const float*)d_in[11]; const float* nn2b = (const float*)d_in[12];
    const float* rt2  = (const float*)d_in[13]; const float* b2   = (const float*)d_in[14];
    const float* nn3w = (const float*)d_in[15]; const float* nn3b = (const float*)d_in[16];
    const float* rt3  = (const float*)d_in[17]; const float* b3   = (const float*)d_in[18];
    const float* ai   = (const float*)d_in[19]; const float* aw   = (const float*)d_in[20];
    const float* arw  = (const float*)d_in[21]; const float* abi  = (const float*)d_in[22];
    const float* l1w  = (const float*)d_in[23]; const float* l1b  = (const float*)d_in[24];
    const float* l2w  = (const float*)d_in[25]; const float* l2b  = (const float*)d_in[26];
    const float* l3w  = (const float*)d_in[27]; const float* l3b  = (const float*)d_in[28];
    const float* l4w  = (const float*)d_in[29]; const float* l4b  = (const float*)d_in[30];
    float* outp = (float*)d_out;

    char* ws = (char*)d_ws;
    float* M1   = (float*)(ws + OFF_M1);
    float* M2   = (float*)(ws + OFF_M2);
    float* M3   = (float*)(ws + OFF_M3);
    int*   doff = (int*)(ws + OFF_DOFF);
    int*   deid = (int*)(ws + OFF_DEID);
    int*   aoff = (int*)(ws + OFF_AOFF);
    int*   aeid = (int*)(ws + OFF_AEID);
    float* nrm  = (float*)(ws + OFF_NRM);
    float* aa   = (float*)(ws + OFF_AA);
    float* g    = (float*)(ws + OFF_G);
    u16*   hA   = (u16*)(ws + OFF_HA);
    u16*   hB   = (u16*)(ws + OFF_HB);
    float* agg  = (float*)(ws + OFF_AGG);
    int*   cnt  = (int*)(ws + OFF_CNT);
    int*   cur  = (int*)(ws + OFF_CUR);
    int*   acnt = (int*)(ws + OFF_ACNT);
    int*   acur = (int*)(ws + OFF_ACUR);
    int*   bsum = (int*)(ws + OFF_BSUM);
    float* Hb   = (float*)(ws + OFF_H);

    const int* esrc = ei;
    const int* edst = ei + E_ATOMS;
    const int* adst = aei + E_AMINO;
    const bool tile = ws_size >= WS_TILE;       // fast NNConv path
    const bool par  = ws_size >= WS_PAR;        // K-parallel ARMA
    const size_t osz = par ? SZ_K3 : SZ_K1;
    float* Ob = (float*)(ws + OFF_H + osz);
    const int* ekey = tile ? esrc : edst;       // CSR sort key for atom graph

    // prep
    int nagg = tile ? N_ATOMS * HD : 0;
    k_prep0<<<(19200 + N_AMINO + NGRAPH * HA + nagg + 255) / 256, 256, 0, stream>>>(
        nn1w, nn1b, nn2w, nn2b, nn3w, nn3b, M1, M2, M3, af, aa, g, agg, nagg);
    k_csr_zero<<<(N_ATOMS + N_AMINO + 255) / 256, 256, 0, stream>>>(cnt, acnt);
    k_csr_count<<<(E_ATOMS + E_AMINO + 255) / 256, 256, 0, stream>>>(ekey, adst, cnt, acnt);
    k_scan1<<<NB_ATOM + NB_AM, 256, 0, stream>>>(cnt, doff, acnt, aoff, bsum);
    k_scan2<<<2, 128, 0, stream>>>(bsum, doff, aoff);
    k_scan3<<<NB_ATOM + NB_AM, 256, 0, stream>>>(doff, aoff, bsum, cur, acur);
    k_csr_fill<<<(E_ATOMS + 2 * E_AMINO + 255) / 256, 256, 0, stream>>>(
        ekey, cur, deid, aei, acur, aeid, aoff, nrm);

    // NNConv
    if (tile) {
        const int GT = (N_ATOMS + TILE - 1) / TILE;   // 1563
        const int GF = (N_ATOMS * HD + 255) / 256;    // 7813
        nnconv_tile<DIN0, true ><<<GT, 256, 0, stream>>>(x,  ea, esrc, edst, doff, deid, M1, agg);
        nnconv_finish2<DIN0, true,  false><<<GF, 256, 0, stream>>>(x,  rt1, b1, agg, hA, nullptr, nullptr);
        nnconv_tile<HD,   false><<<GT, 256, 0, stream>>>(hA, ea, esrc, edst, doff, deid, M2, agg);
        nnconv_finish2<HD,   false, false><<<GF, 256, 0, stream>>>(hA, rt2, b2, agg, hB, nullptr, nullptr);
        nnconv_tile<HD,   false><<<GT, 256, 0, stream>>>(hB, ea, esrc, edst, doff, deid, M3, agg);
        nnconv_finish2<HD,   false, true ><<<GF, 256, 0, stream>>>(hB, rt3, b3, agg, nullptr, aa, lbl);
    } else {
        nnconv_gather<DIN0, true,  false><<<2048, 256, 0, stream>>>(
            x,  ea, esrc, doff, deid, M1, rt1, b1, hA, nullptr, nullptr);
        nnconv_gather<HD,   false, false><<<2048, 256, 0, stream>>>(
            hA, ea, esrc, doff, deid, M2, rt2, b2, hB, nullptr, nullptr);
        nnconv_gather<HD,   false, true ><<<2048, 256, 0, stream>>>(
            hB, ea, esrc, doff, deid, M3, rt3, b3, nullptr, aa, lbl);
    }

    // ARMA
    const size_t KH = (size_t)N_AMINO * HA;
    if (par) {
        for (int t = 0; t < TL; ++t) {
            if (t == 0)
                arma_gemm28<<<dim3(640, KS), 256, 0, stream>>>(aa, ai, 28 * HA, Hb, KH);
            else
                arma_gemm128<<<dim3(640, KS), 256, 0, stream>>>(
                    Ob, KH, aw + (size_t)(t - 1) * KS * HA * HA, HA * HA, Hb, KH);
            arma_out<<<dim3(640, KS), 256, 0, stream>>>(
                Hb, KH, aa, arw + (size_t)t * KS * 28 * HA, 28 * HA,
                abi + (size_t)t * KS * HA, HA, aei, aoff, aeid, nrm, Ob, KH,
                (t == TL - 1) ? bat : (const int*)nullptr, g);
        }
    } else {
        for (int k = 0; k < KS; ++k) {
            for (int t = 0; t < TL; ++t) {
                if (t == 0)
                    arma_gemm28<<<dim3(640, 1), 256, 0, stream>>>(
                        aa, ai + (size_t)k * 28 * HA, 0, Hb, 0);
                else
                    arma_gemm128<<<dim3(640, 1), 256, 0, stream>>>(
                        Ob, 0, aw + (size_t)((t - 1) * KS + k) * HA * HA, 0, Hb, 0);
                arma_out<<<dim3(640, 1), 256, 0, stream>>>(
                    Hb, 0, aa, arw + (size_t)(t * KS + k) * 28 * HA, 0,
                    abi + (size_t)(t * KS + k) * HA, 0, aei, aoff, aeid, nrm, Ob, 0,
                    (t == TL - 1) ? bat : (const int*)nullptr, g);
            }
        }
    }

    head<<<NGRAPH, 256, 0, stream>>>(g, l1w, l1b, l2w, l2b, l3w, l3b, l4w, l4b, outp);
}

// Round 10
// 1115.756 us; speedup vs baseline: 2.0734x; 1.0816x over previous
//
#include <hip/hip_runtime.h>

#define N_ATOMS 100000
#define E_ATOMS 200000
#define N_AMINO 10240
#define E_AMINO 20480
#define NGRAPH 512
#define DIN0 40
#define D_E 11
#define HD 20
#define D_AA 8
#define HA 128
#define KS 3
#define TL 7
#define F1 256
#define F2 128
#define F3 64
#define TILE 64

typedef unsigned short u16;
typedef unsigned int u32;

__device__ __forceinline__ float b2f(u16 u) {
    union { u32 i; float f; } v; v.i = ((u32)u) << 16; return v.f;
}
__device__ __forceinline__ u16 f2b(float f) {
    union { float f; u32 i; } v; v.f = f;
    u32 x = v.i;
    return (u16)((x + (((x >> 16) & 1u) + 0x7fffu)) >> 16);
}

// ---------------------------------------------------------------------------
// prep0: M matrices + aa feature columns (sum columns written by aa_gather).
__global__ __launch_bounds__(256) void k_prep0(
    const float* __restrict__ w1, const float* __restrict__ b1,
    const float* __restrict__ w2, const float* __restrict__ b2,
    const float* __restrict__ w3, const float* __restrict__ b3,
    float* __restrict__ M1, float* __restrict__ M2, float* __restrict__ M3,
    const float* __restrict__ af, float* __restrict__ aa) {
    int t = blockIdx.x * 256 + threadIdx.x;
    if (t < 9600) {
        int i = t / 240, c = t % 240;
        M1[t] = (c < 220) ? w1[(c / 20) * 800 + i * 20 + (c % 20)] : b1[i * 20 + (c - 220)];
    } else if (t < 14400) {
        int tt = t - 9600, i = tt / 240, c = tt % 240;
        M2[tt] = (c < 220) ? w2[(c / 20) * 400 + i * 20 + (c % 20)] : b2[i * 20 + (c - 220)];
    } else if (t < 19200) {
        int tt = t - 14400, i = tt / 240, c = tt % 240;
        M3[tt] = (c < 220) ? w3[(c / 20) * 400 + i * 20 + (c % 20)] : b3[i * 20 + (c - 220)];
    } else if (t < 19200 + N_AMINO * D_AA) {
        int idx = t - 19200, m = idx / D_AA, j = idx % D_AA;
        aa[m * 28 + HD + j] = af[idx];
    }
}

// ---------------------------------------------------------------------------
// CSR builds: src(atom), dst(atom, storing src-slots), amino(dst), label(atom)
// scan segments: [0,98) src | [98,196) dst | [196,206) amino | [206,216) label
#define NBS 98
#define NBA 10

__global__ __launch_bounds__(256) void k_csr_zero(
    int* __restrict__ cs, int* __restrict__ cd,
    int* __restrict__ ca, int* __restrict__ cl) {
    int t = blockIdx.x * 256 + threadIdx.x;
    if (t < N_ATOMS) cs[t] = 0;
    else if (t < 2 * N_ATOMS) cd[t - N_ATOMS] = 0;
    else if (t < 2 * N_ATOMS + N_AMINO) ca[t - 2 * N_ATOMS] = 0;
    else if (t < 2 * N_ATOMS + 2 * N_AMINO) cl[t - 2 * N_ATOMS - N_AMINO] = 0;
}
__global__ __launch_bounds__(256) void k_csr_count(
    const int* __restrict__ esrc, const int* __restrict__ edst,
    const int* __restrict__ adst, const int* __restrict__ lbl,
    int* __restrict__ cs, int* __restrict__ cd,
    int* __restrict__ ca, int* __restrict__ cl) {
    int t = blockIdx.x * 256 + threadIdx.x;
    if (t < E_ATOMS) atomicAdd(cs + esrc[t], 1);
    else if (t < 2 * E_ATOMS) atomicAdd(cd + edst[t - E_ATOMS], 1);
    else if (t < 2 * E_ATOMS + E_AMINO) atomicAdd(ca + adst[t - 2 * E_ATOMS], 1);
    else if (t < 2 * E_ATOMS + E_AMINO + N_ATOMS) atomicAdd(cl + lbl[t - 2 * E_ATOMS - E_AMINO], 1);
}
__device__ __forceinline__ void seg_decode(int bx, int* blk, int* n, int* which) {
    if (bx < NBS)            { *which = 0; *blk = bx;             *n = N_ATOMS; }
    else if (bx < 2 * NBS)   { *which = 1; *blk = bx - NBS;       *n = N_ATOMS; }
    else if (bx < 2 * NBS + NBA) { *which = 2; *blk = bx - 2 * NBS; *n = N_AMINO; }
    else                     { *which = 3; *blk = bx - 2 * NBS - NBA; *n = N_AMINO; }
}
__global__ __launch_bounds__(256) void k_scan1(
    const int* __restrict__ cs, int* __restrict__ soff,
    const int* __restrict__ cd, int* __restrict__ doff,
    const int* __restrict__ ca, int* __restrict__ aoff,
    const int* __restrict__ cl, int* __restrict__ loff,
    int* __restrict__ bsum) {
    int blk, n, which;
    seg_decode(blockIdx.x, &blk, &n, &which);
    const int* c = which == 0 ? cs : which == 1 ? cd : which == 2 ? ca : cl;
    int* o = which == 0 ? soff : which == 1 ? doff : which == 2 ? aoff : loff;
    int tx = threadIdx.x, lane = tx & 63, w = tx >> 6;
    int i0 = blk * 1024 + tx * 4;
    int v[4];
#pragma unroll
    for (int q = 0; q < 4; ++q) v[q] = (i0 + q < n) ? c[i0 + q] : 0;
    int s = v[0] + v[1] + v[2] + v[3];
    int inc = s;
#pragma unroll
    for (int d = 1; d < 64; d <<= 1) {
        int u = __shfl_up(inc, d, 64);
        if (lane >= d) inc += u;
    }
    __shared__ int wsum[4];
    if (lane == 63) wsum[w] = inc;
    __syncthreads();
    int wo = 0;
    for (int i = 0; i < w; ++i) wo += wsum[i];
    int run = wo + inc - s;
#pragma unroll
    for (int q = 0; q < 4; ++q) {
        if (i0 + q < n) o[i0 + q] = run;
        run += v[q];
    }
    if (tx == 255) bsum[blockIdx.x] = wo + inc;
}
__global__ __launch_bounds__(128) void k_scan2(
    int* __restrict__ bsum, int* __restrict__ soff, int* __restrict__ doff,
    int* __restrict__ aoff, int* __restrict__ loff) {
    int bx = blockIdx.x;
    int nb   = (bx < 2) ? NBS : NBA;
    int base = (bx == 0) ? 0 : (bx == 1) ? NBS : (bx == 2) ? 2 * NBS : 2 * NBS + NBA;
    int* b = bsum + base;
    int tx = threadIdx.x, lane = tx & 63;
    int v = (tx < nb) ? b[tx] : 0;
    int inc = v;
#pragma unroll
    for (int d = 1; d < 64; d <<= 1) {
        int u = __shfl_up(inc, d, 64);
        if (lane >= d) inc += u;
    }
    __shared__ int w0;
    if (tx == 63) w0 = inc;
    __syncthreads();
    int excl = inc - v + ((tx >= 64) ? w0 : 0);
    if (tx < nb) b[tx] = excl;
    if (tx == nb - 1) {
        int tot = excl + v;
        if (bx == 0) soff[N_ATOMS] = tot;
        else if (bx == 1) doff[N_ATOMS] = tot;
        else if (bx == 2) aoff[N_AMINO] = tot;
        else loff[N_AMINO] = tot;
    }
}
__global__ __launch_bounds__(256) void k_scan3(
    int* __restrict__ soff, int* __restrict__ doff,
    int* __restrict__ aoff, int* __restrict__ loff,
    const int* __restrict__ bsum,
    int* __restrict__ us, int* __restrict__ ud,
    int* __restrict__ ua, int* __restrict__ ul) {
    int blk, n, which;
    seg_decode(blockIdx.x, &blk, &n, &which);
    int* o = which == 0 ? soff : which == 1 ? doff : which == 2 ? aoff : loff;
    int* cu = which == 0 ? us : which == 1 ? ud : which == 2 ? ua : ul;
    int add = bsum[blockIdx.x];
    int i0 = blk * 1024 + threadIdx.x * 4;
#pragma unroll
    for (int q = 0; q < 4; ++q)
        if (i0 + q < n) { int val = o[i0 + q] + add; o[i0 + q] = val; cu[i0 + q] = val; }
}
// fill: src slots (and dst->slot), amino eids + nrm, label->node
__global__ __launch_bounds__(256) void k_csr_fill(
    const int* __restrict__ esrc, const int* __restrict__ edst,
    int* __restrict__ us, int* __restrict__ seid,
    int* __restrict__ ud, int* __restrict__ dslot,
    const int* __restrict__ aei, int* __restrict__ ua, int* __restrict__ aeid,
    const int* __restrict__ aoff, float* __restrict__ nrm,
    const int* __restrict__ lbl, int* __restrict__ ul, int* __restrict__ lnid) {
    int t = blockIdx.x * 256 + threadIdx.x;
    if (t < E_ATOMS) {
        int jj = atomicAdd(us + esrc[t], 1);
        seid[jj] = t;
        int p = atomicAdd(ud + edst[t], 1);
        dslot[p] = jj;
    } else if (t < E_ATOMS + E_AMINO) {
        int e = t - E_ATOMS;
        int p = atomicAdd(ua + aei[E_AMINO + e], 1);
        aeid[p] = e;
    } else if (t < E_ATOMS + 2 * E_AMINO) {
        int e = t - E_ATOMS - E_AMINO;
        int s = aei[e], d = aei[E_AMINO + e];
        int ds = aoff[s + 1] - aoff[s], dd = aoff[d + 1] - aoff[d];
        float a = ds > 0 ? rsqrtf((float)ds) : 0.f;
        float b = dd > 0 ? rsqrtf((float)dd) : 0.f;
        nrm[e] = a * b;
    } else if (t < E_ATOMS + 2 * E_AMINO + N_ATOMS) {
        int n = t - E_ATOMS - 2 * E_AMINO;
        int p = atomicAdd(ul + lbl[n], 1);
        lnid[p] = n;
    }
}

// ---------------------------------------------------------------------------
// NNConv edge phase: src-tiled, y in LDS, writes per-edge msg (bf16, slot-
// ordered, contiguous) — NO atomics.
template <int DIN, bool RAW>
__global__ __launch_bounds__(256) void nnconv_edge(
    const void* __restrict__ xin, const float* __restrict__ ea,
    const int* __restrict__ soff, const int* __restrict__ seid,
    const float* __restrict__ Mg, u16* __restrict__ msg) {
    __shared__ float y[TILE * 240];
    int tx = threadIdx.x;
    int n0 = blockIdx.x * TILE;
    int nT = min(TILE, N_ATOMS - n0);
    float m[DIN];
    if (tx < 240) {
#pragma unroll
        for (int i = 0; i < DIN; ++i) m[i] = Mg[i * 240 + tx];
        for (int nl = 0; nl < nT; ++nl) {
            const float* xf = (const float*)xin + (size_t)(n0 + nl) * DIN;
            const u16*   xb = (const u16*)xin + (size_t)(n0 + nl) * DIN;
            float acc = 0.f;
#pragma unroll
            for (int i = 0; i < DIN; ++i)
                acc += (RAW ? xf[i] : b2f(xb[i])) * m[i];
            y[nl * 240 + tx] = acc;
        }
    }
    __syncthreads();
    int j0 = soff[n0], j1 = soff[n0 + nT];
    if (tx < 240) {
        int o = tx % 20;
        for (int jj = j0 + tx / 20; jj < j1; jj += 12) {
            int e = seid[jj];
            int sl = /* src in tile */ 0;
            // src = esrc[e] is in [n0,n0+nT); recover local row from y layout:
            // we need esrc; pass via seid-encoded? simpler: re-derive from edge.
            (void)sl;
            // NOTE: esrc lookup below
            o = o; // keep structure
            break;
        }
    }
    // (real edge loop below — separated for esrc parameter)
}

// Actual edge kernel with esrc (kept single definition for clarity)
template <int DIN, bool RAW>
__global__ __launch_bounds__(256) void nnconv_edge2(
    const void* __restrict__ xin, const float* __restrict__ ea,
    const int* __restrict__ esrc,
    const int* __restrict__ soff, const int* __restrict__ seid,
    const float* __restrict__ Mg, u16* __restrict__ msg) {
    __shared__ float y[TILE * 240];
    int tx = threadIdx.x;
    int n0 = blockIdx.x * TILE;
    int nT = min(TILE, N_ATOMS - n0);
    float m[DIN];
    if (tx < 240) {
#pragma unroll
        for (int i = 0; i < DIN; ++i) m[i] = Mg[i * 240 + tx];
        for (int nl = 0; nl < nT; ++nl) {
            const float* xf = (const float*)xin + (size_t)(n0 + nl) * DIN;
            const u16*   xb = (const u16*)xin + (size_t)(n0 + nl) * DIN;
            float acc = 0.f;
#pragma unroll
            for (int i = 0; i < DIN; ++i)
                acc += (RAW ? xf[i] : b2f(xb[i])) * m[i];
            y[nl * 240 + tx] = acc;
        }
    }
    __syncthreads();
    int j0 = soff[n0], j1 = soff[n0 + nT];
    if (tx < 240) {
        int o = tx % 20;
        for (int jj = j0 + tx / 20; jj < j1; jj += 12) {
            int e = seid[jj];
            int sl = esrc[e] - n0;
            const float* er = ea + (size_t)e * D_E;
            float mv = y[sl * 240 + 220 + o];
#pragma unroll
            for (int k = 0; k < D_E; ++k) mv += er[k] * y[sl * 240 + k * HD + o];
            msg[(size_t)jj * 20 + o] = f2b(mv);
        }
    }
}

// NNConv reduce: per (n,o) gather msg via dst->slot CSR + root+bias+relu.
template <int DIN, bool RAW>
__global__ __launch_bounds__(256) void nnconv_reduce(
    const void* __restrict__ xin, const float* __restrict__ root,
    const float* __restrict__ bias, const int* __restrict__ doff,
    const int* __restrict__ dslot, const u16* __restrict__ msg,
    u16* __restrict__ hout) {
    __shared__ float Rl[DIN * HD + HD];
    for (int t = threadIdx.x; t < DIN * HD; t += 256) Rl[t] = root[t];
    if (threadIdx.x < HD) Rl[DIN * HD + threadIdx.x] = bias[threadIdx.x];
    __syncthreads();
    int t = blockIdx.x * 256 + threadIdx.x;
    if (t >= N_ATOMS * HD) return;
    int n = t / HD, o = t % HD;
    float acc = Rl[DIN * HD + o];
    int j1 = doff[n + 1];
    for (int j = doff[n]; j < j1; ++j)
        acc += b2f(msg[(size_t)dslot[j] * 20 + o]);
    const float* xf = (const float*)xin + (size_t)n * DIN;
    const u16*   xb = (const u16*)xin + (size_t)n * DIN;
#pragma unroll
    for (int i = 0; i < DIN; ++i)
        acc += (RAW ? xf[i] : b2f(xb[i])) * Rl[i * HD + o];
    hout[t] = f2b(fmaxf(acc, 0.f));
}

// aa gather: label-CSR segmented sum of h3 (no atomics)
__global__ __launch_bounds__(256) void aa_gather(
    const u16* __restrict__ h3, const int* __restrict__ loff,
    const int* __restrict__ lnid, float* __restrict__ aa) {
    int t = blockIdx.x * 256 + threadIdx.x;
    if (t >= N_AMINO * HD) return;
    int m = t / HD, o = t % HD;
    float s = 0.f;
    int j1 = loff[m + 1];
    for (int j = loff[m]; j < j1; ++j)
        s += b2f(h3[(size_t)lnid[j] * HD + o]);
    aa[m * 28 + o] = s;
}

// ---------------------------------------------------------------------------
// ARMA (K-parallel via blockIdx.y; no atomics anywhere)
__global__ __launch_bounds__(256) void arma_gemm28(
    const float* __restrict__ A, const float* __restrict__ W, size_t wstride,
    float* __restrict__ H, size_t hstride) {
    int t = blockIdx.x * 256 + threadIdx.x;
    int n = t >> 4, c0 = (t & 15) * 8;
    const float* Wk = W + blockIdx.y * wstride;
    float* Hk = H + blockIdx.y * hstride;
    float a[28];
    const float* ar = A + n * 28;
#pragma unroll
    for (int i = 0; i < 28; ++i) a[i] = ar[i];
    float acc[8];
#pragma unroll
    for (int j = 0; j < 8; ++j) acc[j] = 0.f;
    for (int f = 0; f < 28; ++f) {
        const float* wr = Wk + f * HA + c0;
        float4 w0 = *(const float4*)wr, w1 = *(const float4*)(wr + 4);
        float av = a[f];
        acc[0] += av * w0.x; acc[1] += av * w0.y; acc[2] += av * w0.z; acc[3] += av * w0.w;
        acc[4] += av * w1.x; acc[5] += av * w1.y; acc[6] += av * w1.z; acc[7] += av * w1.w;
    }
    float* hp = Hk + n * HA + c0;
    *(float4*)hp       = make_float4(acc[0], acc[1], acc[2], acc[3]);
    *(float4*)(hp + 4) = make_float4(acc[4], acc[5], acc[6], acc[7]);
}

__global__ __launch_bounds__(256) void arma_gemm128(
    const float* __restrict__ A, size_t astride,
    const float* __restrict__ W, size_t wstride,
    float* __restrict__ H, size_t hstride) {
    __shared__ float Al[16][HA + 1];
    const float* Ak = A + blockIdx.y * astride;
    const float* Wk = W + blockIdx.y * wstride;
    float* Hk = H + blockIdx.y * hstride;
    int row0 = blockIdx.x * 16;
    for (int t = threadIdx.x; t < 16 * HA; t += 256)
        Al[t >> 7][t & 127] = Ak[(size_t)(row0 + (t >> 7)) * HA + (t & 127)];
    __syncthreads();
    int r = threadIdx.x >> 4, c0 = (threadIdx.x & 15) * 8;
    float acc[8];
#pragma unroll
    for (int j = 0; j < 8; ++j) acc[j] = 0.f;
    for (int f = 0; f < HA; ++f) {
        float av = Al[r][f];
        const float* wr = Wk + f * HA + c0;
        float4 w0 = *(const float4*)wr, w1 = *(const float4*)(wr + 4);
        acc[0] += av * w0.x; acc[1] += av * w0.y; acc[2] += av * w0.z; acc[3] += av * w0.w;
        acc[4] += av * w1.x; acc[5] += av * w1.y; acc[6] += av * w1.z; acc[7] += av * w1.w;
    }
    float* hp = Hk + (size_t)(row0 + r) * HA + c0;
    *(float4*)hp       = make_float4(acc[0], acc[1], acc[2], acc[3]);
    *(float4*)(hp + 4) = make_float4(acc[4], acc[5], acc[6], acc[7]);
}

__global__ __launch_bounds__(256) void arma_out(
    const float* __restrict__ H, size_t hstride,
    const float* __restrict__ aa,
    const float* __restrict__ rw, size_t rstride,
    const float* __restrict__ bw, size_t bstride,
    const int* __restrict__ aei, const int* __restrict__ aoff,
    const int* __restrict__ aeid, const float* __restrict__ nrm,
    float* __restrict__ O, size_t ostride) {
    int t = blockIdx.x * 256 + threadIdx.x;
    int n = t >> 4, c0 = (t & 15) * 8;
    const float* Hk = H + blockIdx.y * hstride;
    const float* rwk = rw + blockIdx.y * rstride;
    const float* bwk = bw + blockIdx.y * bstride;
    float* Ok = O + blockIdx.y * ostride;
    float acc[8];
#pragma unroll
    for (int j = 0; j < 8; ++j) acc[j] = bwk[c0 + j];
    int j1 = aoff[n + 1];
    for (int jj = aoff[n]; jj < j1; ++jj) {
        int e = aeid[jj], s = aei[e];
        float nm = nrm[e];
        const float* hr = Hk + (size_t)s * HA + c0;
#pragma unroll
        for (int j = 0; j < 8; ++j) acc[j] += nm * hr[j];
    }
    float a[28];
    const float* ar = aa + n * 28;
#pragma unroll
    for (int i = 0; i < 28; ++i) a[i] = ar[i];
    for (int f = 0; f < 28; ++f) {
        const float* wr = rwk + f * HA + c0;
        float4 w0 = *(const float4*)wr, w1 = *(const float4*)(wr + 4);
        float av = a[f];
        acc[0] += av * w0.x; acc[1] += av * w0.y; acc[2] += av * w0.z; acc[3] += av * w0.w;
        acc[4] += av * w1.x; acc[5] += av * w1.y; acc[6] += av * w1.z; acc[7] += av * w1.w;
    }
#pragma unroll
    for (int j = 0; j < 8; ++j) acc[j] = fmaxf(acc[j], 0.f);
    float* op = Ok + (size_t)n * HA + c0;
    *(float4*)op       = make_float4(acc[0], acc[1], acc[2], acc[3]);
    *(float4*)(op + 4) = make_float4(acc[4], acc[5], acc[6], acc[7]);
}

// Readout: amino_batch is SORTED -> segmented sum per graph, no atomics.
__global__ __launch_bounds__(128) void k_readout(
    const float* __restrict__ O, size_t kstride,
    const int* __restrict__ bat, float* __restrict__ g) {
    int b = blockIdx.x, tx = threadIdx.x;
    int lo = 0, hi = N_AMINO;
    while (lo < hi) { int mid = (lo + hi) >> 1; if (bat[mid] < b) lo = mid + 1; else hi = mid; }
    int s = lo;
    lo = 0; hi = N_AMINO;
    while (lo < hi) { int mid = (lo + hi) >> 1; if (bat[mid] < b + 1) lo = mid + 1; else hi = mid; }
    int e = lo;
    float acc = 0.f;
    for (int n = s; n < e; ++n)
        acc += O[(size_t)n * HA + tx] + O[kstride + (size_t)n * HA + tx]
             + O[2 * kstride + (size_t)n * HA + tx];
    g[b * HA + tx] = acc * (1.f / 3.f);
}

// ---------------------------------------------------------------------------
__global__ __launch_bounds__(256) void head(
    const float* __restrict__ g,
    const float* __restrict__ l1w, const float* __restrict__ l1b,
    const float* __restrict__ l2w, const float* __restrict__ l2b,
    const float* __restrict__ l3w, const float* __restrict__ l3b,
    const float* __restrict__ l4w, const float* __restrict__ l4b,
    float* __restrict__ outp) {
    __shared__ float sg[HA], sp1[F1], sp2[F2], sp3[F3];
    int b = blockIdx.x, tx = threadIdx.x;
    if (tx < HA) sg[tx] = g[b * HA + tx];
    __syncthreads();
    {   float acc = l1b[tx];
        for (int f = 0; f < HA; ++f) acc += sg[f] * l1w[f * F1 + tx];
        sp1[tx] = fmaxf(acc, 0.f); }
    __syncthreads();
    if (tx < F2) {
        float acc = l2b[tx];
        for (int f = 0; f < F1; ++f) acc += sp1[f] * l2w[f * F2 + tx];
        sp2[tx] = fmaxf(acc, 0.f); }
    __syncthreads();
    if (tx < F3) {
        float acc = l3b[tx];
        for (int f = 0; f < F2; ++f) acc += sp2[f] * l3w[f * F3 + tx];
        sp3[tx] = fmaxf(acc, 0.f); }
    __syncthreads();
    if (tx < 64) {
        float p = sp3[tx] * l4w[tx];
        for (int off = 32; off > 0; off >>= 1) p += __shfl_down(p, off, 64);
        if (tx == 0) outp[b] = p + l4b[0];
    }
}

// ---------------------------------------------------------------------------
// Workspace (fits exactly in proven ws_size >= 34,348,288 B).
// Region A (persists through ARMA): M, aoff, aeid, nrm, aa, g.
#define OFF_M1    ((size_t)0)
#define OFF_M2    ((size_t)38400)
#define OFF_M3    ((size_t)57600)
#define OFF_AOFF  ((size_t)76800)
#define OFF_AEID  ((size_t)118016)
#define OFF_NRM   ((size_t)199936)
#define OFF_AA    ((size_t)281856)
#define OFF_G     ((size_t)1428736)     // ends 1,690,880
// Region B (NNConv phase; dead before ARMA):
#define OFF_HA    ((size_t)2891008)
#define OFF_HB    ((size_t)6891008)
#define OFF_MSG   ((size_t)10891008)    // bf16 msg[200K*20] = 8,000,000
#define OFF_SOFF  ((size_t)18891008)
#define OFF_SEID  ((size_t)19291136)
#define OFF_DOFF  ((size_t)20091136)
#define OFF_DSLOT ((size_t)20491264)
#define OFF_LOFF  ((size_t)21291264)
#define OFF_LNID  ((size_t)21332228)
#define OFF_CS    ((size_t)21732228)
#define OFF_CD    ((size_t)22132228)
#define OFF_CA    ((size_t)22532228)
#define OFF_CL    ((size_t)22573188)
#define OFF_US    ((size_t)22614148)
#define OFF_UD    ((size_t)23014148)
#define OFF_UA    ((size_t)23414148)
#define OFF_UL    ((size_t)23455108)
#define OFF_BSUM  ((size_t)23496068)    // ends 23,496,932
// ARMA overlay (after NNConv): H, O — ends exactly 34,348,288.
#define OFF_ARH   ((size_t)2891008)
#define SZ_K3     ((size_t)KS * N_AMINO * HA * 4)   // 15,728,640
#define OFF_ARO   (OFF_ARH + SZ_K3)                 // 18,619,648

extern "C" void kernel_launch(void* const* d_in, const int* in_sizes, int n_in,
                              void* d_out, int out_size, void* d_ws, size_t ws_size,
                              hipStream_t stream) {
    (void)in_sizes; (void)n_in; (void)out_size; (void)ws_size;
    const float* x   = (const float*)d_in[0];
    const int*   ei  = (const int*)d_in[1];
    const float* ea  = (const float*)d_in[2];
    const int*   lbl = (const int*)d_in[3];
    const float* af  = (const float*)d_in[4];
    const int*   aei = (const int*)d_in[5];
    const int*   bat = (const int*)d_in[6];
    const float* nn1w = (const float*)d_in[7];  const float* nn1b = (const float*)d_in[8];
    const float* rt1  = (const float*)d_in[9];  const float* b1   = (const float*)d_in[10];
    const float* nn2w = (const float*)d_in[11]; const float* nn2b = (const float*)d_in[12];
    const float* rt2  = (const float*)d_in[13]; const float* b2   = (const float*)d_in[14];
    const float* nn3w = (const float*)d_in[15]; const float* nn3b = (const float*)d_in[16];
    const float* rt3  = (const float*)d_in[17]; const float* b3   = (const float*)d_in[18];
    const float* ai   = (const float*)d_in[19]; const float* aw   = (const float*)d_in[20];
    const float* arw  = (const float*)d_in[21]; const float* abi  = (const float*)d_in[22];
    const float* l1w  = (const float*)d_in[23]; const float* l1b  = (const float*)d_in[24];
    const float* l2w  = (const float*)d_in[25]; const float* l2b  = (const float*)d_in[26];
    const float* l3w  = (const float*)d_in[27]; const float* l3b  = (const float*)d_in[28];
    const float* l4w  = (const float*)d_in[29]; const float* l4b  = (const float*)d_in[30];
    float* outp = (float*)d_out;

    char* ws = (char*)d_ws;
    float* M1    = (float*)(ws + OFF_M1);
    float* M2    = (float*)(ws + OFF_M2);
    float* M3    = (float*)(ws + OFF_M3);
    int*   aoff  = (int*)(ws + OFF_AOFF);
    int*   aeid  = (int*)(ws + OFF_AEID);
    float* nrm   = (float*)(ws + OFF_NRM);
    float* aa    = (float*)(ws + OFF_AA);
    float* g     = (float*)(ws + OFF_G);
    u16*   hA    = (u16*)(ws + OFF_HA);
    u16*   hB    = (u16*)(ws + OFF_HB);
    u16*   msg   = (u16*)(ws + OFF_MSG);
    int*   soff  = (int*)(ws + OFF_SOFF);
    int*   seid  = (int*)(ws + OFF_SEID);
    int*   doff  = (int*)(ws + OFF_DOFF);
    int*   dslot = (int*)(ws + OFF_DSLOT);
    int*   loff  = (int*)(ws + OFF_LOFF);
    int*   lnid  = (int*)(ws + OFF_LNID);
    int*   cs    = (int*)(ws + OFF_CS);
    int*   cd    = (int*)(ws + OFF_CD);
    int*   ca    = (int*)(ws + OFF_CA);
    int*   cl    = (int*)(ws + OFF_CL);
    int*   us    = (int*)(ws + OFF_US);
    int*   ud    = (int*)(ws + OFF_UD);
    int*   ua    = (int*)(ws + OFF_UA);
    int*   ul    = (int*)(ws + OFF_UL);
    int*   bsum  = (int*)(ws + OFF_BSUM);
    float* Hb    = (float*)(ws + OFF_ARH);
    float* Ob    = (float*)(ws + OFF_ARO);

    const int* esrc = ei;
    const int* edst = ei + E_ATOMS;
    const int* adst = aei + E_AMINO;

    // prep: params + 4 CSRs
    k_prep0<<<(19200 + N_AMINO * D_AA + 255) / 256, 256, 0, stream>>>(
        nn1w, nn1b, nn2w, nn2b, nn3w, nn3b, M1, M2, M3, af, aa);
    k_csr_zero<<<(2 * N_ATOMS + 2 * N_AMINO + 255) / 256, 256, 0, stream>>>(cs, cd, ca, cl);
    k_csr_count<<<(2 * E_ATOMS + E_AMINO + N_ATOMS + 255) / 256, 256, 0, stream>>>(
        esrc, edst, adst, lbl, cs, cd, ca, cl);
    k_scan1<<<2 * NBS + 2 * NBA, 256, 0, stream>>>(cs, soff, cd, doff, ca, aoff, cl, loff, bsum);
    k_scan2<<<4, 128, 0, stream>>>(bsum, soff, doff, aoff, loff);
    k_scan3<<<2 * NBS + 2 * NBA, 256, 0, stream>>>(soff, doff, aoff, loff, bsum, us, ud, ua, ul);
    k_csr_fill<<<(E_ATOMS + 2 * E_AMINO + N_ATOMS + 255) / 256, 256, 0, stream>>>(
        esrc, edst, us, seid, ud, dslot, aei, ua, aeid, aoff, nrm, lbl, ul, lnid);

    // NNConv: edge(msg) + reduce, atomic-free
    const int GT = (N_ATOMS + TILE - 1) / TILE;   // 1563
    const int GF = (N_ATOMS * HD + 255) / 256;    // 7813
    nnconv_edge2<DIN0, true ><<<GT, 256, 0, stream>>>(x,  ea, esrc, soff, seid, M1, msg);
    nnconv_reduce<DIN0, true ><<<GF, 256, 0, stream>>>(x,  rt1, b1, doff, dslot, msg, hA);
    nnconv_edge2<HD,   false><<<GT, 256, 0, stream>>>(hA, ea, esrc, soff, seid, M2, msg);
    nnconv_reduce<HD,   false><<<GF, 256, 0, stream>>>(hA, rt2, b2, doff, dslot, msg, hB);
    nnconv_edge2<HD,   false><<<GT, 256, 0, stream>>>(hB, ea, esrc, soff, seid, M3, msg);
    nnconv_reduce<HD,   false><<<GF, 256, 0, stream>>>(hB, rt3, b3, doff, dslot, msg, hA);
    aa_gather<<<(N_AMINO * HD + 255) / 256, 256, 0, stream>>>(hA, loff, lnid, aa);

    // ARMA: K-parallel, T layers
    const size_t KH = (size_t)N_AMINO * HA;
    for (int t = 0; t < TL; ++t) {
        if (t == 0)
            arma_gemm28<<<dim3(640, KS), 256, 0, stream>>>(aa, ai, 28 * HA, Hb, KH);
        else
            arma_gemm128<<<dim3(640, KS), 256, 0, stream>>>(
                Ob, KH, aw + (size_t)(t - 1) * KS * HA * HA, HA * HA, Hb, KH);
        arma_out<<<dim3(640, KS), 256, 0, stream>>>(
            Hb, KH, aa, arw + (size_t)t * KS * 28 * HA, 28 * HA,
            abi + (size_t)t * KS * HA, HA, aei, aoff, aeid, nrm, Ob, KH);
    }

    k_readout<<<NGRAPH, 128, 0, stream>>>(Ob, KH, bat, g);
    head<<<NGRAPH, 256, 0, stream>>>(g, l1w, l1b, l2w, l2b, l3w, l3b, l4w, l4b, outp);
}

// Round 12
// 1030.365 us; speedup vs baseline: 2.2452x; 1.0829x over previous
//
#include <hip/hip_runtime.h>

#define N_ATOMS 100000
#define E_ATOMS 200000
#define N_AMINO 10240
#define E_AMINO 20480
#define NGRAPH 512
#define DIN0 40
#define D_E 11
#define HD 20
#define D_AA 8
#define HA 128
#define KS 3
#define TL 7
#define F1 256
#define F2 128
#define F3 64
#define TILE 32

typedef unsigned short u16;
typedef unsigned int u32;

__device__ __forceinline__ float b2f(u16 u) {
    union { u32 i; float f; } v; v.i = ((u32)u) << 16; return v.f;
}
__device__ __forceinline__ u16 f2b(float f) {
    union { float f; u32 i; } v; v.f = f;
    u32 x = v.i;
    return (u16)((x + (((x >> 16) & 1u) + 0x7fffu)) >> 16);
}

// ---------------------------------------------------------------------------
// prep0: M matrices + aa feature columns.
__global__ __launch_bounds__(256) void k_prep0(
    const float* __restrict__ w1, const float* __restrict__ b1,
    const float* __restrict__ w2, const float* __restrict__ b2,
    const float* __restrict__ w3, const float* __restrict__ b3,
    float* __restrict__ M1, float* __restrict__ M2, float* __restrict__ M3,
    const float* __restrict__ af, float* __restrict__ aa) {
    int t = blockIdx.x * 256 + threadIdx.x;
    if (t < 9600) {
        int i = t / 240, c = t % 240;
        M1[t] = (c < 220) ? w1[(c / 20) * 800 + i * 20 + (c % 20)] : b1[i * 20 + (c - 220)];
    } else if (t < 14400) {
        int tt = t - 9600, i = tt / 240, c = tt % 240;
        M2[tt] = (c < 220) ? w2[(c / 20) * 400 + i * 20 + (c % 20)] : b2[i * 20 + (c - 220)];
    } else if (t < 19200) {
        int tt = t - 14400, i = tt / 240, c = tt % 240;
        M3[tt] = (c < 220) ? w3[(c / 20) * 400 + i * 20 + (c % 20)] : b3[i * 20 + (c - 220)];
    } else if (t < 19200 + N_AMINO * D_AA) {
        int idx = t - 19200, m = idx / D_AA, j = idx % D_AA;
        aa[m * 28 + HD + j] = af[idx];
    }
}

// ---------------------------------------------------------------------------
// CSR builds: src(atom), dst(atom->slot), amino(dst), label(atom)
#define NBS 98
#define NBA 10

__global__ __launch_bounds__(256) void k_csr_zero(
    int* __restrict__ cs, int* __restrict__ cd,
    int* __restrict__ ca, int* __restrict__ cl) {
    int t = blockIdx.x * 256 + threadIdx.x;
    if (t < N_ATOMS) cs[t] = 0;
    else if (t < 2 * N_ATOMS) cd[t - N_ATOMS] = 0;
    else if (t < 2 * N_ATOMS + N_AMINO) ca[t - 2 * N_ATOMS] = 0;
    else if (t < 2 * N_ATOMS + 2 * N_AMINO) cl[t - 2 * N_ATOMS - N_AMINO] = 0;
}
__global__ __launch_bounds__(256) void k_csr_count(
    const int* __restrict__ esrc, const int* __restrict__ edst,
    const int* __restrict__ adst, const int* __restrict__ lbl,
    int* __restrict__ cs, int* __restrict__ cd,
    int* __restrict__ ca, int* __restrict__ cl) {
    int t = blockIdx.x * 256 + threadIdx.x;
    if (t < E_ATOMS) atomicAdd(cs + esrc[t], 1);
    else if (t < 2 * E_ATOMS) atomicAdd(cd + edst[t - E_ATOMS], 1);
    else if (t < 2 * E_ATOMS + E_AMINO) atomicAdd(ca + adst[t - 2 * E_ATOMS], 1);
    else if (t < 2 * E_ATOMS + E_AMINO + N_ATOMS) atomicAdd(cl + lbl[t - 2 * E_ATOMS - E_AMINO], 1);
}
__device__ __forceinline__ void seg_decode(int bx, int* blk, int* n, int* which) {
    if (bx < NBS)            { *which = 0; *blk = bx;             *n = N_ATOMS; }
    else if (bx < 2 * NBS)   { *which = 1; *blk = bx - NBS;       *n = N_ATOMS; }
    else if (bx < 2 * NBS + NBA) { *which = 2; *blk = bx - 2 * NBS; *n = N_AMINO; }
    else                     { *which = 3; *blk = bx - 2 * NBS - NBA; *n = N_AMINO; }
}
__global__ __launch_bounds__(256) void k_scan1(
    const int* __restrict__ cs, int* __restrict__ soff,
    const int* __restrict__ cd, int* __restrict__ doff,
    const int* __restrict__ ca, int* __restrict__ aoff,
    const int* __restrict__ cl, int* __restrict__ loff,
    int* __restrict__ bsum) {
    int blk, n, which;
    seg_decode(blockIdx.x, &blk, &n, &which);
    const int* c = which == 0 ? cs : which == 1 ? cd : which == 2 ? ca : cl;
    int* o = which == 0 ? soff : which == 1 ? doff : which == 2 ? aoff : loff;
    int tx = threadIdx.x, lane = tx & 63, w = tx >> 6;
    int i0 = blk * 1024 + tx * 4;
    int v[4];
#pragma unroll
    for (int q = 0; q < 4; ++q) v[q] = (i0 + q < n) ? c[i0 + q] : 0;
    int s = v[0] + v[1] + v[2] + v[3];
    int inc = s;
#pragma unroll
    for (int d = 1; d < 64; d <<= 1) {
        int u = __shfl_up(inc, d, 64);
        if (lane >= d) inc += u;
    }
    __shared__ int wsum[4];
    if (lane == 63) wsum[w] = inc;
    __syncthreads();
    int wo = 0;
    for (int i = 0; i < w; ++i) wo += wsum[i];
    int run = wo + inc - s;
#pragma unroll
    for (int q = 0; q < 4; ++q) {
        if (i0 + q < n) o[i0 + q] = run;
        run += v[q];
    }
    if (tx == 255) bsum[blockIdx.x] = wo + inc;
}
__global__ __launch_bounds__(128) void k_scan2(
    int* __restrict__ bsum, int* __restrict__ soff, int* __restrict__ doff,
    int* __restrict__ aoff, int* __restrict__ loff) {
    int bx = blockIdx.x;
    int nb   = (bx < 2) ? NBS : NBA;
    int base = (bx == 0) ? 0 : (bx == 1) ? NBS : (bx == 2) ? 2 * NBS : 2 * NBS + NBA;
    int* b = bsum + base;
    int tx = threadIdx.x, lane = tx & 63;
    int v = (tx < nb) ? b[tx] : 0;
    int inc = v;
#pragma unroll
    for (int d = 1; d < 64; d <<= 1) {
        int u = __shfl_up(inc, d, 64);
        if (lane >= d) inc += u;
    }
    __shared__ int w0;
    if (tx == 63) w0 = inc;
    __syncthreads();
    int excl = inc - v + ((tx >= 64) ? w0 : 0);
    if (tx < nb) b[tx] = excl;
    if (tx == nb - 1) {
        int tot = excl + v;
        if (bx == 0) soff[N_ATOMS] = tot;
        else if (bx == 1) doff[N_ATOMS] = tot;
        else if (bx == 2) aoff[N_AMINO] = tot;
        else loff[N_AMINO] = tot;
    }
}
__global__ __launch_bounds__(256) void k_scan3(
    int* __restrict__ soff, int* __restrict__ doff,
    int* __restrict__ aoff, int* __restrict__ loff,
    const int* __restrict__ bsum,
    int* __restrict__ us, int* __restrict__ ud,
    int* __restrict__ ua, int* __restrict__ ul) {
    int blk, n, which;
    seg_decode(blockIdx.x, &blk, &n, &which);
    int* o = which == 0 ? soff : which == 1 ? doff : which == 2 ? aoff : loff;
    int* cu = which == 0 ? us : which == 1 ? ud : which == 2 ? ua : ul;
    int add = bsum[blockIdx.x];
    int i0 = blk * 1024 + threadIdx.x * 4;
#pragma unroll
    for (int q = 0; q < 4; ++q)
        if (i0 + q < n) { int val = o[i0 + q] + add; o[i0 + q] = val; cu[i0 + q] = val; }
}
// fill: src slots -> srcP/eaP (permuted), dst->slot, amino eids + nrm, label->node
__global__ __launch_bounds__(256) void k_csr_fill(
    const int* __restrict__ esrc, const int* __restrict__ edst,
    const float* __restrict__ ea,
    int* __restrict__ us, int* __restrict__ srcP, float* __restrict__ eaP,
    int* __restrict__ ud, int* __restrict__ dslot,
    const int* __restrict__ aei, int* __restrict__ ua, int* __restrict__ aeid,
    const int* __restrict__ aoff, float* __restrict__ nrm,
    const int* __restrict__ lbl, int* __restrict__ ul, int* __restrict__ lnid) {
    int t = blockIdx.x * 256 + threadIdx.x;
    if (t < E_ATOMS) {
        int jj = atomicAdd(us + esrc[t], 1);
        srcP[jj] = esrc[t];
        const float* e0 = ea + (size_t)t * D_E;
        float* e1 = eaP + (size_t)jj * D_E;
#pragma unroll
        for (int k = 0; k < D_E; ++k) e1[k] = e0[k];
        int p = atomicAdd(ud + edst[t], 1);
        dslot[p] = jj;
    } else if (t < E_ATOMS + E_AMINO) {
        int e = t - E_ATOMS;
        int p = atomicAdd(ua + aei[E_AMINO + e], 1);
        aeid[p] = e;
    } else if (t < E_ATOMS + 2 * E_AMINO) {
        int e = t - E_ATOMS - E_AMINO;
        int s = aei[e], d = aei[E_AMINO + e];
        int ds = aoff[s + 1] - aoff[s], dd = aoff[d + 1] - aoff[d];
        float a = ds > 0 ? rsqrtf((float)ds) : 0.f;
        float b = dd > 0 ? rsqrtf((float)dd) : 0.f;
        nrm[e] = a * b;
    } else if (t < E_ATOMS + 2 * E_AMINO + N_ATOMS) {
        int n = t - E_ATOMS - 2 * E_AMINO;
        int p = atomicAdd(ul + lbl[n], 1);
        lnid[p] = n;
    }
}

// ---------------------------------------------------------------------------
// NNConv edge: 32-node tiles (30 KB LDS -> ~5 blocks/CU), permuted srcP/eaP
// (coalesced in jj), per-edge bf16 msg, no atomics.
template <int DIN, bool RAW>
__global__ __launch_bounds__(256) void nnconv_edge3(
    const void* __restrict__ xin, const float* __restrict__ eaP,
    const int* __restrict__ srcP, const int* __restrict__ soff,
    const float* __restrict__ Mg, u16* __restrict__ msg) {
    __shared__ float y[TILE * 240];
    int tx = threadIdx.x;
    int n0 = blockIdx.x * TILE;
    int nT = min(TILE, N_ATOMS - n0);
    if (tx < 240) {
        float m[DIN];
#pragma unroll
        for (int i = 0; i < DIN; ++i) m[i] = Mg[i * 240 + tx];
        for (int nl = 0; nl < nT; ++nl) {
            const float* xf = (const float*)xin + (size_t)(n0 + nl) * DIN;
            const u16*   xb = (const u16*)xin + (size_t)(n0 + nl) * DIN;
            float acc = 0.f;
#pragma unroll
            for (int i = 0; i < DIN; ++i)
                acc += (RAW ? xf[i] : b2f(xb[i])) * m[i];
            y[nl * 240 + tx] = acc;
        }
    }
    __syncthreads();
    int j0 = soff[n0], j1 = soff[n0 + nT];
    if (tx < 240) {
        int o = tx % 20, grp = tx / 20;
        for (int jj = j0 + grp; jj < j1; jj += 12) {
            int sl = srcP[jj] - n0;
            const float* er = eaP + (size_t)jj * D_E;
            float mv = y[sl * 240 + 220 + o];
#pragma unroll
            for (int k = 0; k < D_E; ++k) mv += er[k] * y[sl * 240 + k * HD + o];
            msg[(size_t)jj * 20 + o] = f2b(mv);
        }
    }
}

// NNConv reduce: per (n,o) gather msg via dst->slot CSR + root+bias+relu.
template <int DIN, bool RAW>
__global__ __launch_bounds__(256) void nnconv_reduce(
    const void* __restrict__ xin, const float* __restrict__ root,
    const float* __restrict__ bias, const int* __restrict__ doff,
    const int* __restrict__ dslot, const u16* __restrict__ msg,
    u16* __restrict__ hout) {
    __shared__ float Rl[DIN * HD + HD];
    for (int t = threadIdx.x; t < DIN * HD; t += 256) Rl[t] = root[t];
    if (threadIdx.x < HD) Rl[DIN * HD + threadIdx.x] = bias[threadIdx.x];
    __syncthreads();
    int t = blockIdx.x * 256 + threadIdx.x;
    if (t >= N_ATOMS * HD) return;
    int n = t / HD, o = t % HD;
    float acc = Rl[DIN * HD + o];
    int j1 = doff[n + 1];
    for (int j = doff[n]; j < j1; ++j)
        acc += b2f(msg[(size_t)dslot[j] * 20 + o]);
    const float* xf = (const float*)xin + (size_t)n * DIN;
    const u16*   xb = (const u16*)xin + (size_t)n * DIN;
#pragma unroll
    for (int i = 0; i < DIN; ++i)
        acc += (RAW ? xf[i] : b2f(xb[i])) * Rl[i * HD + o];
    hout[t] = f2b(fmaxf(acc, 0.f));
}

// aa gather: label-CSR segmented sum of h3 (no atomics)
__global__ __launch_bounds__(256) void aa_gather(
    const u16* __restrict__ h3, const int* __restrict__ loff,
    const int* __restrict__ lnid, float* __restrict__ aa) {
    int t = blockIdx.x * 256 + threadIdx.x;
    if (t >= N_AMINO * HD) return;
    int m = t / HD, o = t % HD;
    float s = 0.f;
    int j1 = loff[m + 1];
    for (int j = loff[m]; j < j1; ++j)
        s += b2f(h3[(size_t)lnid[j] * HD + o]);
    aa[m * 28 + o] = s;
}

// ---------------------------------------------------------------------------
// ARMA (K-parallel via blockIdx.y; no atomics)
__global__ __launch_bounds__(256) void arma_gemm28(
    const float* __restrict__ A, const float* __restrict__ W, size_t wstride,
    float* __restrict__ H, size_t hstride) {
    int t = blockIdx.x * 256 + threadIdx.x;
    int n = t >> 4, c0 = (t & 15) * 8;
    const float* Wk = W + blockIdx.y * wstride;
    float* Hk = H + blockIdx.y * hstride;
    float a[28];
    const float* ar = A + n * 28;
#pragma unroll
    for (int i = 0; i < 28; ++i) a[i] = ar[i];
    float acc[8];
#pragma unroll
    for (int j = 0; j < 8; ++j) acc[j] = 0.f;
    for (int f = 0; f < 28; ++f) {
        const float* wr = Wk + f * HA + c0;
        float4 w0 = *(const float4*)wr, w1 = *(const float4*)(wr + 4);
        float av = a[f];
        acc[0] += av * w0.x; acc[1] += av * w0.y; acc[2] += av * w0.z; acc[3] += av * w0.w;
        acc[4] += av * w1.x; acc[5] += av * w1.y; acc[6] += av * w1.z; acc[7] += av * w1.w;
    }
    float* hp = Hk + n * HA + c0;
    *(float4*)hp       = make_float4(acc[0], acc[1], acc[2], acc[3]);
    *(float4*)(hp + 4) = make_float4(acc[4], acc[5], acc[6], acc[7]);
}

__global__ __launch_bounds__(256) void arma_gemm128(
    const float* __restrict__ A, size_t astride,
    const float* __restrict__ W, size_t wstride,
    float* __restrict__ H, size_t hstride) {
    __shared__ float Al[16][HA + 1];
    const float* Ak = A + blockIdx.y * astride;
    const float* Wk = W + blockIdx.y * wstride;
    float* Hk = H + blockIdx.y * hstride;
    int row0 = blockIdx.x * 16;
    for (int t = threadIdx.x; t < 16 * HA; t += 256)
        Al[t >> 7][t & 127] = Ak[(size_t)(row0 + (t >> 7)) * HA + (t & 127)];
    __syncthreads();
    int r = threadIdx.x >> 4, c0 = (threadIdx.x & 15) * 8;
    float acc[8];
#pragma unroll
    for (int j = 0; j < 8; ++j) acc[j] = 0.f;
    for (int f = 0; f < HA; ++f) {
        float av = Al[r][f];
        const float* wr = Wk + f * HA + c0;
        float4 w0 = *(const float4*)wr, w1 = *(const float4*)(wr + 4);
        acc[0] += av * w0.x; acc[1] += av * w0.y; acc[2] += av * w0.z; acc[3] += av * w0.w;
        acc[4] += av * w1.x; acc[5] += av * w1.y; acc[6] += av * w1.z; acc[7] += av * w1.w;
    }
    float* hp = Hk + (size_t)(row0 + r) * HA + c0;
    *(float4*)hp       = make_float4(acc[0], acc[1], acc[2], acc[3]);
    *(float4*)(hp + 4) = make_float4(acc[4], acc[5], acc[6], acc[7]);
}

__global__ __launch_bounds__(256) void arma_out(
    const float* __restrict__ H, size_t hstride,
    const float* __restrict__ aa,
    const float* __restrict__ rw, size_t rstride,
    const float* __restrict__ bw, size_t bstride,
    const int* __restrict__ aei, const int* __restrict__ aoff,
    const int* __restrict__ aeid, const float* __restrict__ nrm,
    float* __restrict__ O, size_t ostride) {
    int t = blockIdx.x * 256 + threadIdx.x;
    int n = t >> 4, c0 = (t & 15) * 8;
    const float* Hk = H + blockIdx.y * hstride;
    const float* rwk = rw + blockIdx.y * rstride;
    const float* bwk = bw + blockIdx.y * bstride;
    float* Ok = O + blockIdx.y * ostride;
    float acc[8];
#pragma unroll
    for (int j = 0; j < 8; ++j) acc[j] = bwk[c0 + j];
    int j1 = aoff[n + 1];
    for (int jj = aoff[n]; jj < j1; ++jj) {
        int e = aeid[jj], s = aei[e];
        float nm = nrm[e];
        const float* hr = Hk + (size_t)s * HA + c0;
#pragma unroll
        for (int j = 0; j < 8; ++j) acc[j] += nm * hr[j];
    }
    float a[28];
    const float* ar = aa + n * 28;
#pragma unroll
    for (int i = 0; i < 28; ++i) a[i] = ar[i];
    for (int f = 0; f < 28; ++f) {
        const float* wr = rwk + f * HA + c0;
        float4 w0 = *(const float4*)wr, w1 = *(const float4*)(wr + 4);
        float av = a[f];
        acc[0] += av * w0.x; acc[1] += av * w0.y; acc[2] += av * w0.z; acc[3] += av * w0.w;
        acc[4] += av * w1.x; acc[5] += av * w1.y; acc[6] += av * w1.z; acc[7] += av * w1.w;
    }
#pragma unroll
    for (int j = 0; j < 8; ++j) acc[j] = fmaxf(acc[j], 0.f);
    float* op = Ok + (size_t)n * HA + c0;
    *(float4*)op       = make_float4(acc[0], acc[1], acc[2], acc[3]);
    *(float4*)(op + 4) = make_float4(acc[4], acc[5], acc[6], acc[7]);
}

// Readout: amino_batch is SORTED -> segmented sum per graph, no atomics.
__global__ __launch_bounds__(128) void k_readout(
    const float* __restrict__ O, size_t kstride,
    const int* __restrict__ bat, float* __restrict__ g) {
    int b = blockIdx.x, tx = threadIdx.x;
    int lo = 0, hi = N_AMINO;
    while (lo < hi) { int mid = (lo + hi) >> 1; if (bat[mid] < b) lo = mid + 1; else hi = mid; }
    int s = lo;
    lo = 0; hi = N_AMINO;
    while (lo < hi) { int mid = (lo + hi) >> 1; if (bat[mid] < b + 1) lo = mid + 1; else hi = mid; }
    int e = lo;
    float acc = 0.f;
    for (int n = s; n < e; ++n)
        acc += O[(size_t)n * HA + tx] + O[kstride + (size_t)n * HA + tx]
             + O[2 * kstride + (size_t)n * HA + tx];
    g[b * HA + tx] = acc * (1.f / 3.f);
}

// ---------------------------------------------------------------------------
__global__ __launch_bounds__(256) void head(
    const float* __restrict__ g,
    const float* __restrict__ l1w, const float* __restrict__ l1b,
    const float* __restrict__ l2w, const float* __restrict__ l2b,
    const float* __restrict__ l3w, const float* __restrict__ l3b,
    const float* __restrict__ l4w, const float* __restrict__ l4b,
    float* __restrict__ outp) {
    __shared__ float sg[HA], sp1[F1], sp2[F2], sp3[F3];
    int b = blockIdx.x, tx = threadIdx.x;
    if (tx < HA) sg[tx] = g[b * HA + tx];
    __syncthreads();
    {   float acc = l1b[tx];
        for (int f = 0; f < HA; ++f) acc += sg[f] * l1w[f * F1 + tx];
        sp1[tx] = fmaxf(acc, 0.f); }
    __syncthreads();
    if (tx < F2) {
        float acc = l2b[tx];
        for (int f = 0; f < F1; ++f) acc += sp1[f] * l2w[f * F2 + tx];
        sp2[tx] = fmaxf(acc, 0.f); }
    __syncthreads();
    if (tx < F3) {
        float acc = l3b[tx];
        for (int f = 0; f < F2; ++f) acc += sp2[f] * l3w[f * F3 + tx];
        sp3[tx] = fmaxf(acc, 0.f); }
    __syncthreads();
    if (tx < 64) {
        float p = sp3[tx] * l4w[tx];
        for (int off = 32; off > 0; off >>= 1) p += __shfl_down(p, off, 64);
        if (tx == 0) outp[b] = p + l4b[0];
    }
}

// ---------------------------------------------------------------------------
// Workspace (<= 34,348,288 B, proven available in round 10).
#define OFF_M1    ((size_t)0)
#define OFF_M2    ((size_t)38400)
#define OFF_M3    ((size_t)57600)
#define OFF_AOFF  ((size_t)76800)
#define OFF_AEID  ((size_t)118016)
#define OFF_NRM   ((size_t)199936)
#define OFF_AA    ((size_t)281856)
#define OFF_G     ((size_t)1428736)
#define OFF_HA    ((size_t)2891008)
#define OFF_HB    ((size_t)6891008)
#define OFF_MSG   ((size_t)10891008)
#define OFF_SOFF  ((size_t)18891008)
#define OFF_DOFF  ((size_t)19291136)
#define OFF_DSLOT ((size_t)19691264)
#define OFF_LOFF  ((size_t)20491264)
#define OFF_LNID  ((size_t)20532480)
#define OFF_CS    ((size_t)20932480)
#define OFF_CD    ((size_t)21332480)
#define OFF_CA    ((size_t)21732480)
#define OFF_CL    ((size_t)21773440)
#define OFF_US    ((size_t)21814400)
#define OFF_UD    ((size_t)22214400)
#define OFF_UA    ((size_t)22614400)
#define OFF_UL    ((size_t)22655360)
#define OFF_BSUM  ((size_t)22696320)
#define OFF_EAP   ((size_t)22697216)   // 8,800,000 -> 31,497,216
#define OFF_SRCP  ((size_t)31497216)   //   800,000 -> 32,297,216
// ARMA overlay: H 2,891,008..18,619,648; O 18,619,648..34,348,288.
// aa_gather (reads loff/lnid inside the future O region) runs BEFORE any
// O write (stream-ordered). eaP/srcP dead after last edge kernel.
#define OFF_ARH   ((size_t)2891008)
#define SZ_K3     ((size_t)KS * N_AMINO * HA * 4)
#define OFF_ARO   (OFF_ARH + SZ_K3)

extern "C" void kernel_launch(void* const* d_in, const int* in_sizes, int n_in,
                              void* d_out, int out_size, void* d_ws, size_t ws_size,
                              hipStream_t stream) {
    (void)in_sizes; (void)n_in; (void)out_size; (void)ws_size;
    const float* x   = (const float*)d_in[0];
    const int*   ei  = (const int*)d_in[1];
    const float* ea  = (const float*)d_in[2];
    const int*   lbl = (const int*)d_in[3];
    const float* af  = (const float*)d_in[4];
    const int*   aei = (const int*)d_in[5];
    const int*   bat = (const int*)d_in[6];
    const float* nn1w = (const float*)d_in[7];  const float* nn1b = (const float*)d_in[8];
    const float* rt1  = (const float*)d_in[9];  const float* b1   = (const float*)d_in[10];
    const float* nn2w = (const float*)d_in[11]; const float* nn2b = (const float*)d_in[12];
    const float* rt2  = (const float*)d_in[13]; const float* b2   = (const float*)d_in[14];
    const float* nn3w = (const float*)d_in[15]; const float* nn3b = (const float*)d_in[16];
    const float* rt3  = (const float*)d_in[17]; const float* b3   = (const float*)d_in[18];
    const float* ai   = (const float*)d_in[19]; const float* aw   = (const float*)d_in[20];
    const float* arw  = (const float*)d_in[21]; const float* abi  = (const float*)d_in[22];
    const float* l1w  = (const float*)d_in[23]; const float* l1b  = (const float*)d_in[24];
    const float* l2w  = (const float*)d_in[25]; const float* l2b  = (const float*)d_in[26];
    const float* l3w  = (const float*)d_in[27]; const float* l3b  = (const float*)d_in[28];
    const float* l4w  = (const float*)d_in[29]; const float* l4b  = (const float*)d_in[30];
    float* outp = (float*)d_out;

    char* ws = (char*)d_ws;
    float* M1    = (float*)(ws + OFF_M1);
    float* M2    = (float*)(ws + OFF_M2);
    float* M3    = (float*)(ws + OFF_M3);
    int*   aoff  = (int*)(ws + OFF_AOFF);
    int*   aeid  = (int*)(ws + OFF_AEID);
    float* nrm   = (float*)(ws + OFF_NRM);
    float* aa    = (float*)(ws + OFF_AA);
    float* g     = (float*)(ws + OFF_G);
    u16*   hA    = (u16*)(ws + OFF_HA);
    u16*   hB    = (u16*)(ws + OFF_HB);
    u16*   msg   = (u16*)(ws + OFF_MSG);
    int*   soff  = (int*)(ws + OFF_SOFF);
    int*   doff  = (int*)(ws + OFF_DOFF);
    int*   dslot = (int*)(ws + OFF_DSLOT);
    int*   loff  = (int*)(ws + OFF_LOFF);
    int*   lnid  = (int*)(ws + OFF_LNID);
    int*   cs    = (int*)(ws + OFF_CS);
    int*   cd    = (int*)(ws + OFF_CD);
    int*   ca    = (int*)(ws + OFF_CA);
    int*   cl    = (int*)(ws + OFF_CL);
    int*   us    = (int*)(ws + OFF_US);
    int*   ud    = (int*)(ws + OFF_UD);
    int*   ua    = (int*)(ws + OFF_UA);
    int*   ul    = (int*)(ws + OFF_UL);
    int*   bsum  = (int*)(ws + OFF_BSUM);
    float* eaP   = (float*)(ws + OFF_EAP);
    int*   srcP  = (int*)(ws + OFF_SRCP);
    float* Hb    = (float*)(ws + OFF_ARH);
    float* Ob    = (float*)(ws + OFF_ARO);

    const int* esrc = ei;
    const int* edst = ei + E_ATOMS;
    const int* adst = aei + E_AMINO;

    // prep: params + 4 CSRs (+ permuted srcP/eaP)
    k_prep0<<<(19200 + N_AMINO * D_AA + 255) / 256, 256, 0, stream>>>(
        nn1w, nn1b, nn2w, nn2b, nn3w, nn3b, M1, M2, M3, af, aa);
    k_csr_zero<<<(2 * N_ATOMS + 2 * N_AMINO + 255) / 256, 256, 0, stream>>>(cs, cd, ca, cl);
    k_csr_count<<<(2 * E_ATOMS + E_AMINO + N_ATOMS + 255) / 256, 256, 0, stream>>>(
        esrc, edst, adst, lbl, cs, cd, ca, cl);
    k_scan1<<<2 * NBS + 2 * NBA, 256, 0, stream>>>(cs, soff, cd, doff, ca, aoff, cl, loff, bsum);
    k_scan2<<<4, 128, 0, stream>>>(bsum, soff, doff, aoff, loff);
    k_scan3<<<2 * NBS + 2 * NBA, 256, 0, stream>>>(soff, doff, aoff, loff, bsum, us, ud, ua, ul);
    k_csr_fill<<<(E_ATOMS + 2 * E_AMINO + N_ATOMS + 255) / 256, 256, 0, stream>>>(
        esrc, edst, ea, us, srcP, eaP, ud, dslot, aei, ua, aeid, aoff, nrm, lbl, ul, lnid);

    // NNConv: edge(msg) + reduce, atomic-free
    const int GT = (N_ATOMS + TILE - 1) / TILE;   // 3125
    const int GF = (N_ATOMS * HD + 255) / 256;    // 7813
    nnconv_edge3<DIN0, true ><<<GT, 256, 0, stream>>>(x,  eaP, srcP, soff, M1, msg);
    nnconv_reduce<DIN0, true ><<<GF, 256, 0, stream>>>(x,  rt1, b1, doff, dslot, msg, hA);
    nnconv_edge3<HD,   false><<<GT, 256, 0, stream>>>(hA, eaP, srcP, soff, M2, msg);
    nnconv_reduce<HD,   false><<<GF, 256, 0, stream>>>(hA, rt2, b2, doff, dslot, msg, hB);
    nnconv_edge3<HD,   false><<<GT, 256, 0, stream>>>(hB, eaP, srcP, soff, M3, msg);
    nnconv_reduce<HD,   false><<<GF, 256, 0, stream>>>(hB, rt3, b3, doff, dslot, msg, hA);
    aa_gather<<<(N_AMINO * HD + 255) / 256, 256, 0, stream>>>(hA, loff, lnid, aa);

    // ARMA: K-parallel, T layers (regular launches — proven path)
    const size_t KH = (size_t)N_AMINO * HA;
    for (int t = 0; t < TL; ++t) {
        if (t == 0)
            arma_gemm28<<<dim3(640, KS), 256, 0, stream>>>(aa, ai, 28 * HA, Hb, KH);
        else
            arma_gemm128<<<dim3(640, KS), 256, 0, stream>>>(
                Ob, KH, aw + (size_t)(t - 1) * KS * HA * HA, HA * HA, Hb, KH);
        arma_out<<<dim3(640, KS), 256, 0, stream>>>(
            Hb, KH, aa, arw + (size_t)t * KS * 28 * HA, 28 * HA,
            abi + (size_t)t * KS * HA, HA, aei, aoff, aeid, nrm, Ob, KH);
    }

    k_readout<<<NGRAPH, 128, 0, stream>>>(Ob, KH, bat, g);
    head<<<NGRAPH, 256, 0, stream>>>(g, l1w, l1b, l2w, l2b, l3w, l3b, l4w, l4b, outp);
}

// Round 13
// 705.643 us; speedup vs baseline: 3.2784x; 1.4602x over previous
//
#include <hip/hip_runtime.h>

#define N_ATOMS 100000
#define E_ATOMS 200000
#define N_AMINO 10240
#define E_AMINO 20480
#define NGRAPH 512
#define DIN0 40
#define D_E 11
#define HD 20
#define D_AA 8
#define HA 128
#define KS 3
#define TL 7
#define F1 256
#define F2 128
#define F3 64
#define TILE 32

typedef unsigned short u16;
typedef unsigned int u32;

__device__ __forceinline__ float b2f(u16 u) {
    union { u32 i; float f; } v; v.i = ((u32)u) << 16; return v.f;
}
__device__ __forceinline__ u16 f2b(float f) {
    union { float f; u32 i; } v; v.f = f;
    u32 x = v.i;
    return (u16)((x + (((x >> 16) & 1u) + 0x7fffu)) >> 16);
}

// ---------------------------------------------------------------------------
// prep0: M matrices + aa feature columns + zero the 4 CSR count arrays.
__global__ __launch_bounds__(256) void k_prep0(
    const float* __restrict__ w1, const float* __restrict__ b1,
    const float* __restrict__ w2, const float* __restrict__ b2,
    const float* __restrict__ w3, const float* __restrict__ b3,
    float* __restrict__ M1, float* __restrict__ M2, float* __restrict__ M3,
    const float* __restrict__ af, float* __restrict__ aa,
    int* __restrict__ cs, int* __restrict__ cd,
    int* __restrict__ ca, int* __restrict__ cl) {
    int t = blockIdx.x * 256 + threadIdx.x;
    if (t < 9600) {
        int i = t / 240, c = t % 240;
        M1[t] = (c < 220) ? w1[(c / 20) * 800 + i * 20 + (c % 20)] : b1[i * 20 + (c - 220)];
    } else if (t < 14400) {
        int tt = t - 9600, i = tt / 240, c = tt % 240;
        M2[tt] = (c < 220) ? w2[(c / 20) * 400 + i * 20 + (c % 20)] : b2[i * 20 + (c - 220)];
    } else if (t < 19200) {
        int tt = t - 14400, i = tt / 240, c = tt % 240;
        M3[tt] = (c < 220) ? w3[(c / 20) * 400 + i * 20 + (c % 20)] : b3[i * 20 + (c - 220)];
    } else if (t < 19200 + N_AMINO * D_AA) {
        int idx = t - 19200, m = idx / D_AA, j = idx % D_AA;
        aa[m * 28 + HD + j] = af[idx];
    } else {
        int z = t - 19200 - N_AMINO * D_AA;
        if (z < N_ATOMS) cs[z] = 0;
        else if (z < 2 * N_ATOMS) cd[z - N_ATOMS] = 0;
        else if (z < 2 * N_ATOMS + N_AMINO) ca[z - 2 * N_ATOMS] = 0;
        else if (z < 2 * N_ATOMS + 2 * N_AMINO) cl[z - 2 * N_ATOMS - N_AMINO] = 0;
    }
}
#define PREP0_N (19200 + N_AMINO * D_AA + 2 * N_ATOMS + 2 * N_AMINO)

// ---------------------------------------------------------------------------
// CSR builds: src(atom), dst(atom->slot), amino(dst), label(atom)
#define NBS 98
#define NBA 10

__global__ __launch_bounds__(256) void k_csr_count(
    const int* __restrict__ esrc, const int* __restrict__ edst,
    const int* __restrict__ adst, const int* __restrict__ lbl,
    int* __restrict__ cs, int* __restrict__ cd,
    int* __restrict__ ca, int* __restrict__ cl) {
    int t = blockIdx.x * 256 + threadIdx.x;
    if (t < E_ATOMS) atomicAdd(cs + esrc[t], 1);
    else if (t < 2 * E_ATOMS) atomicAdd(cd + edst[t - E_ATOMS], 1);
    else if (t < 2 * E_ATOMS + E_AMINO) atomicAdd(ca + adst[t - 2 * E_ATOMS], 1);
    else if (t < 2 * E_ATOMS + E_AMINO + N_ATOMS) atomicAdd(cl + lbl[t - 2 * E_ATOMS - E_AMINO], 1);
}
__device__ __forceinline__ void seg_decode(int bx, int* blk, int* n, int* which) {
    if (bx < NBS)            { *which = 0; *blk = bx;             *n = N_ATOMS; }
    else if (bx < 2 * NBS)   { *which = 1; *blk = bx - NBS;       *n = N_ATOMS; }
    else if (bx < 2 * NBS + NBA) { *which = 2; *blk = bx - 2 * NBS; *n = N_AMINO; }
    else                     { *which = 3; *blk = bx - 2 * NBS - NBA; *n = N_AMINO; }
}
__global__ __launch_bounds__(256) void k_scan1(
    const int* __restrict__ cs, int* __restrict__ soff,
    const int* __restrict__ cd, int* __restrict__ doff,
    const int* __restrict__ ca, int* __restrict__ aoff,
    const int* __restrict__ cl, int* __restrict__ loff,
    int* __restrict__ bsum) {
    int blk, n, which;
    seg_decode(blockIdx.x, &blk, &n, &which);
    const int* c = which == 0 ? cs : which == 1 ? cd : which == 2 ? ca : cl;
    int* o = which == 0 ? soff : which == 1 ? doff : which == 2 ? aoff : loff;
    int tx = threadIdx.x, lane = tx & 63, w = tx >> 6;
    int i0 = blk * 1024 + tx * 4;
    int v[4];
#pragma unroll
    for (int q = 0; q < 4; ++q) v[q] = (i0 + q < n) ? c[i0 + q] : 0;
    int s = v[0] + v[1] + v[2] + v[3];
    int inc = s;
#pragma unroll
    for (int d = 1; d < 64; d <<= 1) {
        int u = __shfl_up(inc, d, 64);
        if (lane >= d) inc += u;
    }
    __shared__ int wsum[4];
    if (lane == 63) wsum[w] = inc;
    __syncthreads();
    int wo = 0;
    for (int i = 0; i < w; ++i) wo += wsum[i];
    int run = wo + inc - s;
#pragma unroll
    for (int q = 0; q < 4; ++q) {
        if (i0 + q < n) o[i0 + q] = run;
        run += v[q];
    }
    if (tx == 255) bsum[blockIdx.x] = wo + inc;
}
__global__ __launch_bounds__(128) void k_scan2(
    int* __restrict__ bsum, int* __restrict__ soff, int* __restrict__ doff,
    int* __restrict__ aoff, int* __restrict__ loff) {
    int bx = blockIdx.x;
    int nb   = (bx < 2) ? NBS : NBA;
    int base = (bx == 0) ? 0 : (bx == 1) ? NBS : (bx == 2) ? 2 * NBS : 2 * NBS + NBA;
    int* b = bsum + base;
    int tx = threadIdx.x, lane = tx & 63;
    int v = (tx < nb) ? b[tx] : 0;
    int inc = v;
#pragma unroll
    for (int d = 1; d < 64; d <<= 1) {
        int u = __shfl_up(inc, d, 64);
        if (lane >= d) inc += u;
    }
    __shared__ int w0;
    if (tx == 63) w0 = inc;
    __syncthreads();
    int excl = inc - v + ((tx >= 64) ? w0 : 0);
    if (tx < nb) b[tx] = excl;
    if (tx == nb - 1) {
        int tot = excl + v;
        if (bx == 0) soff[N_ATOMS] = tot;
        else if (bx == 1) doff[N_ATOMS] = tot;
        else if (bx == 2) aoff[N_AMINO] = tot;
        else loff[N_AMINO] = tot;
    }
}
__global__ __launch_bounds__(256) void k_scan3(
    int* __restrict__ soff, int* __restrict__ doff,
    int* __restrict__ aoff, int* __restrict__ loff,
    const int* __restrict__ bsum,
    int* __restrict__ us, int* __restrict__ ud,
    int* __restrict__ ua, int* __restrict__ ul) {
    int blk, n, which;
    seg_decode(blockIdx.x, &blk, &n, &which);
    int* o = which == 0 ? soff : which == 1 ? doff : which == 2 ? aoff : loff;
    int* cu = which == 0 ? us : which == 1 ? ud : which == 2 ? ua : ul;
    int add = bsum[blockIdx.x];
    int i0 = blk * 1024 + threadIdx.x * 4;
#pragma unroll
    for (int q = 0; q < 4; ++q)
        if (i0 + q < n) { int val = o[i0 + q] + add; o[i0 + q] = val; cu[i0 + q] = val; }
}
__global__ __launch_bounds__(256) void k_csr_fill(
    const int* __restrict__ esrc, const int* __restrict__ edst,
    const float* __restrict__ ea,
    int* __restrict__ us, int* __restrict__ srcP, float* __restrict__ eaP,
    int* __restrict__ ud, int* __restrict__ dslot,
    const int* __restrict__ aei, int* __restrict__ ua, int* __restrict__ aeid,
    const int* __restrict__ aoff, float* __restrict__ nrm,
    const int* __restrict__ lbl, int* __restrict__ ul, int* __restrict__ lnid) {
    int t = blockIdx.x * 256 + threadIdx.x;
    if (t < E_ATOMS) {
        int jj = atomicAdd(us + esrc[t], 1);
        srcP[jj] = esrc[t];
        const float* e0 = ea + (size_t)t * D_E;
        float* e1 = eaP + (size_t)jj * D_E;
#pragma unroll
        for (int k = 0; k < D_E; ++k) e1[k] = e0[k];
        int p = atomicAdd(ud + edst[t], 1);
        dslot[p] = jj;
    } else if (t < E_ATOMS + E_AMINO) {
        int e = t - E_ATOMS;
        int p = atomicAdd(ua + aei[E_AMINO + e], 1);
        aeid[p] = e;
    } else if (t < E_ATOMS + 2 * E_AMINO) {
        int e = t - E_ATOMS - E_AMINO;
        int s = aei[e], d = aei[E_AMINO + e];
        int ds = aoff[s + 1] - aoff[s], dd = aoff[d + 1] - aoff[d];
        float a = ds > 0 ? rsqrtf((float)ds) : 0.f;
        float b = dd > 0 ? rsqrtf((float)dd) : 0.f;
        nrm[e] = a * b;
    } else if (t < E_ATOMS + 2 * E_AMINO + N_ATOMS) {
        int n = t - E_ATOMS - 2 * E_AMINO;
        int p = atomicAdd(ul + lbl[n], 1);
        lnid[p] = n;
    }
}

// ---------------------------------------------------------------------------
// NNConv edge: 32-node tiles, permuted srcP/eaP, bf16 msg, no atomics.
template <int DIN, bool RAW>
__global__ __launch_bounds__(256) void nnconv_edge3(
    const void* __restrict__ xin, const float* __restrict__ eaP,
    const int* __restrict__ srcP, const int* __restrict__ soff,
    const float* __restrict__ Mg, u16* __restrict__ msg) {
    __shared__ float y[TILE * 240];
    int tx = threadIdx.x;
    int n0 = blockIdx.x * TILE;
    int nT = min(TILE, N_ATOMS - n0);
    if (tx < 240) {
        float m[DIN];
#pragma unroll
        for (int i = 0; i < DIN; ++i) m[i] = Mg[i * 240 + tx];
        for (int nl = 0; nl < nT; ++nl) {
            const float* xf = (const float*)xin + (size_t)(n0 + nl) * DIN;
            const u16*   xb = (const u16*)xin + (size_t)(n0 + nl) * DIN;
            float acc = 0.f;
#pragma unroll
            for (int i = 0; i < DIN; ++i)
                acc += (RAW ? xf[i] : b2f(xb[i])) * m[i];
            y[nl * 240 + tx] = acc;
        }
    }
    __syncthreads();
    int j0 = soff[n0], j1 = soff[n0 + nT];
    if (tx < 240) {
        int o = tx % 20, grp = tx / 20;
        for (int jj = j0 + grp; jj < j1; jj += 12) {
            int sl = srcP[jj] - n0;
            const float* er = eaP + (size_t)jj * D_E;
            float mv = y[sl * 240 + 220 + o];
#pragma unroll
            for (int k = 0; k < D_E; ++k) mv += er[k] * y[sl * 240 + k * HD + o];
            msg[(size_t)jj * 20 + o] = f2b(mv);
        }
    }
}

// NNConv reduce: per (n,o) gather msg via dst->slot CSR + root+bias+relu.
template <int DIN, bool RAW>
__global__ __launch_bounds__(256) void nnconv_reduce(
    const void* __restrict__ xin, const float* __restrict__ root,
    const float* __restrict__ bias, const int* __restrict__ doff,
    const int* __restrict__ dslot, const u16* __restrict__ msg,
    u16* __restrict__ hout) {
    __shared__ float Rl[DIN * HD + HD];
    for (int t = threadIdx.x; t < DIN * HD; t += 256) Rl[t] = root[t];
    if (threadIdx.x < HD) Rl[DIN * HD + threadIdx.x] = bias[threadIdx.x];
    __syncthreads();
    int t = blockIdx.x * 256 + threadIdx.x;
    if (t >= N_ATOMS * HD) return;
    int n = t / HD, o = t % HD;
    float acc = Rl[DIN * HD + o];
    int j1 = doff[n + 1];
    for (int j = doff[n]; j < j1; ++j)
        acc += b2f(msg[(size_t)dslot[j] * 20 + o]);
    const float* xf = (const float*)xin + (size_t)n * DIN;
    const u16*   xb = (const u16*)xin + (size_t)n * DIN;
#pragma unroll
    for (int i = 0; i < DIN; ++i)
        acc += (RAW ? xf[i] : b2f(xb[i])) * Rl[i * HD + o];
    hout[t] = f2b(fmaxf(acc, 0.f));
}

// aa gather: label-CSR segmented sum of h3
__global__ __launch_bounds__(256) void aa_gather(
    const u16* __restrict__ h3, const int* __restrict__ loff,
    const int* __restrict__ lnid, float* __restrict__ aa) {
    int t = blockIdx.x * 256 + threadIdx.x;
    if (t >= N_AMINO * HD) return;
    int m = t / HD, o = t % HD;
    float s = 0.f;
    int j1 = loff[m + 1];
    for (int j = loff[m]; j < j1; ++j)
        s += b2f(h3[(size_t)lnid[j] * HD + o]);
    aa[m * 28 + o] = s;
}

// ---------------------------------------------------------------------------
// ARMA gemm28: H = aa @ W[k], W + aa-tile staged in LDS.
__global__ __launch_bounds__(256) void arma_gemm28(
    const float* __restrict__ A, const float* __restrict__ W, size_t wstride,
    float* __restrict__ H, size_t hstride) {
    __shared__ float Wl[28 * 128];
    __shared__ float Aas[16][28];
    int tx = threadIdx.x;
    const float* Wk = W + blockIdx.y * wstride;
    int n0 = blockIdx.x * 16;
    for (int i = tx; i < 28 * 128; i += 256) Wl[i] = Wk[i];
    for (int i = tx; i < 16 * 28; i += 256)
        Aas[i / 28][i % 28] = A[(size_t)(n0 + i / 28) * 28 + i % 28];
    __syncthreads();
    int nl = tx >> 4, c0 = (tx & 15) * 8;
    float* Hk = H + blockIdx.y * hstride;
    float acc[8];
#pragma unroll
    for (int j = 0; j < 8; ++j) acc[j] = 0.f;
    for (int f = 0; f < 28; ++f) {
        float av = Aas[nl][f];
        const float* wr = &Wl[f * 128 + c0];
        float4 w0 = *(const float4*)wr, w1 = *(const float4*)(wr + 4);
        acc[0] += av * w0.x; acc[1] += av * w0.y; acc[2] += av * w0.z; acc[3] += av * w0.w;
        acc[4] += av * w1.x; acc[5] += av * w1.y; acc[6] += av * w1.z; acc[7] += av * w1.w;
    }
    float* hp = Hk + (size_t)(n0 + nl) * HA + c0;
    *(float4*)hp       = make_float4(acc[0], acc[1], acc[2], acc[3]);
    *(float4*)(hp + 4) = make_float4(acc[4], acc[5], acc[6], acc[7]);
}

// ARMA gemm128, tiled: 64x64 tile, 4x4/thread, K-tiles of 32 in LDS.
// A reads 16-way broadcast, W reads 4-way broadcast -> VALU-bound.
__global__ __launch_bounds__(256) void arma_gemm128t(
    const float* __restrict__ A, size_t astride,
    const float* __restrict__ W, size_t wstride,
    float* __restrict__ H, size_t hstride) {
    __shared__ float As[32][68];
    __shared__ float Ws[32][68];
    const float* Ak = A + blockIdx.z * astride;
    const float* Wk = W + blockIdx.z * wstride;
    float* Hk = H + blockIdx.z * hstride;
    int row0 = blockIdx.x * 64;
    int col0 = blockIdx.y * 64;
    int tx = threadIdx.x;
    int tr = tx >> 4, tc = tx & 15;
    float acc[4][4];
#pragma unroll
    for (int i = 0; i < 4; ++i)
#pragma unroll
        for (int j = 0; j < 4; ++j) acc[i][j] = 0.f;
    int rA = tx >> 3;             // 0..31
    int kA = (tx & 7) * 4;        // 0..28
    int kW = tx >> 3;             // 0..31
    int cW = (tx & 7) * 8;        // 0..56
    for (int k0 = 0; k0 < HA; k0 += 32) {
        __syncthreads();
        // stage A transposed: As[kk][r]
        float4 a0 = *(const float4*)(Ak + (size_t)(row0 + rA) * HA + k0 + kA);
        float4 a1 = *(const float4*)(Ak + (size_t)(row0 + rA + 32) * HA + k0 + kA);
        As[kA + 0][rA] = a0.x; As[kA + 1][rA] = a0.y;
        As[kA + 2][rA] = a0.z; As[kA + 3][rA] = a0.w;
        As[kA + 0][rA + 32] = a1.x; As[kA + 1][rA + 32] = a1.y;
        As[kA + 2][rA + 32] = a1.z; As[kA + 3][rA + 32] = a1.w;
        // stage W: Ws[kk][c]
        float4 w0 = *(const float4*)(Wk + (size_t)(k0 + kW) * HA + col0 + cW);
        float4 w1 = *(const float4*)(Wk + (size_t)(k0 + kW) * HA + col0 + cW + 4);
        *(float4*)&Ws[kW][cW]     = w0;
        *(float4*)&Ws[kW][cW + 4] = w1;
        __syncthreads();
#pragma unroll
        for (int kk = 0; kk < 32; ++kk) {
            float4 av = *(const float4*)&As[kk][tr * 4];
            float4 wv = *(const float4*)&Ws[kk][tc * 4];
            acc[0][0] += av.x * wv.x; acc[0][1] += av.x * wv.y;
            acc[0][2] += av.x * wv.z; acc[0][3] += av.x * wv.w;
            acc[1][0] += av.y * wv.x; acc[1][1] += av.y * wv.y;
            acc[1][2] += av.y * wv.z; acc[1][3] += av.y * wv.w;
            acc[2][0] += av.z * wv.x; acc[2][1] += av.z * wv.y;
            acc[2][2] += av.z * wv.z; acc[2][3] += av.z * wv.w;
            acc[3][0] += av.w * wv.x; acc[3][1] += av.w * wv.y;
            acc[3][2] += av.w * wv.z; acc[3][3] += av.w * wv.w;
        }
    }
#pragma unroll
    for (int i = 0; i < 4; ++i) {
        float* hp = Hk + (size_t)(row0 + tr * 4 + i) * HA + col0 + tc * 4;
        *(float4*)hp = make_float4(acc[i][0], acc[i][1], acc[i][2], acc[i][3]);
    }
}

// ARMA out: gather + root-gemm (rw/bias/aa staged in LDS) + relu.
__global__ __launch_bounds__(256) void arma_out(
    const float* __restrict__ H, size_t hstride,
    const float* __restrict__ aa,
    const float* __restrict__ rw, size_t rstride,
    const float* __restrict__ bw, size_t bstride,
    const int* __restrict__ aei, const int* __restrict__ aoff,
    const int* __restrict__ aeid, const float* __restrict__ nrm,
    float* __restrict__ O, size_t ostride) {
    __shared__ float Rw[28 * 128];
    __shared__ float Bw[128];
    __shared__ float Aas[16][28];
    int tx = threadIdx.x;
    const float* rwk = rw + blockIdx.y * rstride;
    const float* bwk = bw + blockIdx.y * bstride;
    int n0 = blockIdx.x * 16;
    for (int i = tx; i < 28 * 128; i += 256) Rw[i] = rwk[i];
    if (tx < 128) Bw[tx] = bwk[tx];
    for (int i = tx; i < 16 * 28; i += 256)
        Aas[i / 28][i % 28] = aa[(size_t)(n0 + i / 28) * 28 + i % 28];
    __syncthreads();
    int nl = tx >> 4, c0 = (tx & 15) * 8;
    int n = n0 + nl;
    const float* Hk = H + blockIdx.y * hstride;
    float* Ok = O + blockIdx.y * ostride;
    float acc[8];
#pragma unroll
    for (int j = 0; j < 8; ++j) acc[j] = Bw[c0 + j];
    int j1 = aoff[n + 1];
    for (int jj = aoff[n]; jj < j1; ++jj) {
        int e = aeid[jj], s = aei[e];
        float nm = nrm[e];
        const float* hr = Hk + (size_t)s * HA + c0;
#pragma unroll
        for (int j = 0; j < 8; ++j) acc[j] += nm * hr[j];
    }
    for (int f = 0; f < 28; ++f) {
        float av = Aas[nl][f];
        const float* wr = &Rw[f * 128 + c0];
        float4 w0 = *(const float4*)wr, w1 = *(const float4*)(wr + 4);
        acc[0] += av * w0.x; acc[1] += av * w0.y; acc[2] += av * w0.z; acc[3] += av * w0.w;
        acc[4] += av * w1.x; acc[5] += av * w1.y; acc[6] += av * w1.z; acc[7] += av * w1.w;
    }
#pragma unroll
    for (int j = 0; j < 8; ++j) acc[j] = fmaxf(acc[j], 0.f);
    float* op = Ok + (size_t)n * HA + c0;
    *(float4*)op       = make_float4(acc[0], acc[1], acc[2], acc[3]);
    *(float4*)(op + 4) = make_float4(acc[4], acc[5], acc[6], acc[7]);
}

// Readout: amino_batch sorted -> segmented sum per graph.
__global__ __launch_bounds__(128) void k_readout(
    const float* __restrict__ O, size_t kstride,
    const int* __restrict__ bat, float* __restrict__ g) {
    int b = blockIdx.x, tx = threadIdx.x;
    int lo = 0, hi = N_AMINO;
    while (lo < hi) { int mid = (lo + hi) >> 1; if (bat[mid] < b) lo = mid + 1; else hi = mid; }
    int s = lo;
    lo = 0; hi = N_AMINO;
    while (lo < hi) { int mid = (lo + hi) >> 1; if (bat[mid] < b + 1) lo = mid + 1; else hi = mid; }
    int e = lo;
    float acc = 0.f;
    for (int n = s; n < e; ++n)
        acc += O[(size_t)n * HA + tx] + O[kstride + (size_t)n * HA + tx]
             + O[2 * kstride + (size_t)n * HA + tx];
    g[b * HA + tx] = acc * (1.f / 3.f);
}

// ---------------------------------------------------------------------------
__global__ __launch_bounds__(256) void head(
    const float* __restrict__ g,
    const float* __restrict__ l1w, const float* __restrict__ l1b,
    const float* __restrict__ l2w, const float* __restrict__ l2b,
    const float* __restrict__ l3w, const float* __restrict__ l3b,
    const float* __restrict__ l4w, const float* __restrict__ l4b,
    float* __restrict__ outp) {
    __shared__ float sg[HA], sp1[F1], sp2[F2], sp3[F3];
    int b = blockIdx.x, tx = threadIdx.x;
    if (tx < HA) sg[tx] = g[b * HA + tx];
    __syncthreads();
    {   float acc = l1b[tx];
        for (int f = 0; f < HA; ++f) acc += sg[f] * l1w[f * F1 + tx];
        sp1[tx] = fmaxf(acc, 0.f); }
    __syncthreads();
    if (tx < F2) {
        float acc = l2b[tx];
        for (int f = 0; f < F1; ++f) acc += sp1[f] * l2w[f * F2 + tx];
        sp2[tx] = fmaxf(acc, 0.f); }
    __syncthreads();
    if (tx < F3) {
        float acc = l3b[tx];
        for (int f = 0; f < F2; ++f) acc += sp2[f] * l3w[f * F3 + tx];
        sp3[tx] = fmaxf(acc, 0.f); }
    __syncthreads();
    if (tx < 64) {
        float p = sp3[tx] * l4w[tx];
        for (int off = 32; off > 0; off >>= 1) p += __shfl_down(p, off, 64);
        if (tx == 0) outp[b] = p + l4b[0];
    }
}

// ---------------------------------------------------------------------------
// Workspace (<= 34,348,288 B, proven available).
#define OFF_M1    ((size_t)0)
#define OFF_M2    ((size_t)38400)
#define OFF_M3    ((size_t)57600)
#define OFF_AOFF  ((size_t)76800)
#define OFF_AEID  ((size_t)118016)
#define OFF_NRM   ((size_t)199936)
#define OFF_AA    ((size_t)281856)
#define OFF_G     ((size_t)1428736)
#define OFF_HA    ((size_t)2891008)
#define OFF_HB    ((size_t)6891008)
#define OFF_MSG   ((size_t)10891008)
#define OFF_SOFF  ((size_t)18891008)
#define OFF_DOFF  ((size_t)19291136)
#define OFF_DSLOT ((size_t)19691264)
#define OFF_LOFF  ((size_t)20491264)
#define OFF_LNID  ((size_t)20532480)
#define OFF_CS    ((size_t)20932480)
#define OFF_CD    ((size_t)21332480)
#define OFF_CA    ((size_t)21732480)
#define OFF_CL    ((size_t)21773440)
#define OFF_US    ((size_t)21814400)
#define OFF_UD    ((size_t)22214400)
#define OFF_UA    ((size_t)22614400)
#define OFF_UL    ((size_t)22655360)
#define OFF_BSUM  ((size_t)22696320)
#define OFF_EAP   ((size_t)22697216)
#define OFF_SRCP  ((size_t)31497216)
#define OFF_ARH   ((size_t)2891008)
#define SZ_K3     ((size_t)KS * N_AMINO * HA * 4)
#define OFF_ARO   (OFF_ARH + SZ_K3)

extern "C" void kernel_launch(void* const* d_in, const int* in_sizes, int n_in,
                              void* d_out, int out_size, void* d_ws, size_t ws_size,
                              hipStream_t stream) {
    (void)in_sizes; (void)n_in; (void)out_size; (void)ws_size;
    const float* x   = (const float*)d_in[0];
    const int*   ei  = (const int*)d_in[1];
    const float* ea  = (const float*)d_in[2];
    const int*   lbl = (const int*)d_in[3];
    const float* af  = (const float*)d_in[4];
    const int*   aei = (const int*)d_in[5];
    const int*   bat = (const int*)d_in[6];
    const float* nn1w = (const float*)d_in[7];  const float* nn1b = (const float*)d_in[8];
    const float* rt1  = (const float*)d_in[9];  const float* b1   = (const float*)d_in[10];
    const float* nn2w = (const float*)d_in[11]; const float* nn2b = (const float*)d_in[12];
    const float* rt2  = (const float*)d_in[13]; const float* b2   = (const float*)d_in[14];
    const float* nn3w = (const float*)d_in[15]; const float* nn3b = (const float*)d_in[16];
    const float* rt3  = (const float*)d_in[17]; const float* b3   = (const float*)d_in[18];
    const float* ai   = (const float*)d_in[19]; const float* aw   = (const float*)d_in[20];
    const float* arw  = (const float*)d_in[21]; const float* abi  = (const float*)d_in[22];
    const float* l1w  = (const float*)d_in[23]; const float* l1b  = (const float*)d_in[24];
    const float* l2w  = (const float*)d_in[25]; const float* l2b  = (const float*)d_in[26];
    const float* l3w  = (const float*)d_in[27]; const float* l3b  = (const float*)d_in[28];
    const float* l4w  = (const float*)d_in[29]; const float* l4b  = (const float*)d_in[30];
    float* outp = (float*)d_out;

    char* ws = (char*)d_ws;
    float* M1    = (float*)(ws + OFF_M1);
    float* M2    = (float*)(ws + OFF_M2);
    float* M3    = (float*)(ws + OFF_M3);
    int*   aoff  = (int*)(ws + OFF_AOFF);
    int*   aeid  = (int*)(ws + OFF_AEID);
    float* nrm   = (float*)(ws + OFF_NRM);
    float* aa    = (float*)(ws + OFF_AA);
    float* g     = (float*)(ws + OFF_G);
    u16*   hA    = (u16*)(ws + OFF_HA);
    u16*   hB    = (u16*)(ws + OFF_HB);
    u16*   msg   = (u16*)(ws + OFF_MSG);
    int*   soff  = (int*)(ws + OFF_SOFF);
    int*   doff  = (int*)(ws + OFF_DOFF);
    int*   dslot = (int*)(ws + OFF_DSLOT);
    int*   loff  = (int*)(ws + OFF_LOFF);
    int*   lnid  = (int*)(ws + OFF_LNID);
    int*   cs    = (int*)(ws + OFF_CS);
    int*   cd    = (int*)(ws + OFF_CD);
    int*   ca    = (int*)(ws + OFF_CA);
    int*   cl    = (int*)(ws + OFF_CL);
    int*   us    = (int*)(ws + OFF_US);
    int*   ud    = (int*)(ws + OFF_UD);
    int*   ua    = (int*)(ws + OFF_UA);
    int*   ul    = (int*)(ws + OFF_UL);
    int*   bsum  = (int*)(ws + OFF_BSUM);
    float* eaP   = (float*)(ws + OFF_EAP);
    int*   srcP  = (int*)(ws + OFF_SRCP);
    float* Hb    = (float*)(ws + OFF_ARH);
    float* Ob    = (float*)(ws + OFF_ARO);

    const int* esrc = ei;
    const int* edst = ei + E_ATOMS;
    const int* adst = aei + E_AMINO;

    // prep: params + CSR-count zero folded into prep0
    k_prep0<<<(PREP0_N + 255) / 256, 256, 0, stream>>>(
        nn1w, nn1b, nn2w, nn2b, nn3w, nn3b, M1, M2, M3, af, aa, cs, cd, ca, cl);
    k_csr_count<<<(2 * E_ATOMS + E_AMINO + N_ATOMS + 255) / 256, 256, 0, stream>>>(
        esrc, edst, adst, lbl, cs, cd, ca, cl);
    k_scan1<<<2 * NBS + 2 * NBA, 256, 0, stream>>>(cs, soff, cd, doff, ca, aoff, cl, loff, bsum);
    k_scan2<<<4, 128, 0, stream>>>(bsum, soff, doff, aoff, loff);
    k_scan3<<<2 * NBS + 2 * NBA, 256, 0, stream>>>(soff, doff, aoff, loff, bsum, us, ud, ua, ul);
    k_csr_fill<<<(E_ATOMS + 2 * E_AMINO + N_ATOMS + 255) / 256, 256, 0, stream>>>(
        esrc, edst, ea, us, srcP, eaP, ud, dslot, aei, ua, aeid, aoff, nrm, lbl, ul, lnid);

    // NNConv
    const int GT = (N_ATOMS + TILE - 1) / TILE;   // 3125
    const int GF = (N_ATOMS * HD + 255) / 256;    // 7813
    nnconv_edge3<DIN0, true ><<<GT, 256, 0, stream>>>(x,  eaP, srcP, soff, M1, msg);
    nnconv_reduce<DIN0, true ><<<GF, 256, 0, stream>>>(x,  rt1, b1, doff, dslot, msg, hA);
    nnconv_edge3<HD,   false><<<GT, 256, 0, stream>>>(hA, eaP, srcP, soff, M2, msg);
    nnconv_reduce<HD,   false><<<GF, 256, 0, stream>>>(hA, rt2, b2, doff, dslot, msg, hB);
    nnconv_edge3<HD,   false><<<GT, 256, 0, stream>>>(hB, eaP, srcP, soff, M3, msg);
    nnconv_reduce<HD,   false><<<GF, 256, 0, stream>>>(hB, rt3, b3, doff, dslot, msg, hA);
    aa_gather<<<(N_AMINO * HD + 255) / 256, 256, 0, stream>>>(hA, loff, lnid, aa);

    // ARMA: K-parallel, T layers
    const size_t KH = (size_t)N_AMINO * HA;
    for (int t = 0; t < TL; ++t) {
        if (t == 0)
            arma_gemm28<<<dim3(640, KS), 256, 0, stream>>>(aa, ai, 28 * HA, Hb, KH);
        else
            arma_gemm128t<<<dim3(160, 2, KS), 256, 0, stream>>>(
                Ob, KH, aw + (size_t)(t - 1) * KS * HA * HA, HA * HA, Hb, KH);
        arma_out<<<dim3(640, KS), 256, 0, stream>>>(
            Hb, KH, aa, arw + (size_t)t * KS * 28 * HA, 28 * HA,
            abi + (size_t)t * KS * HA, HA, aei, aoff, aeid, nrm, Ob, KH);
    }

    k_readout<<<NGRAPH, 128, 0, stream>>>(Ob, KH, bat, g);
    head<<<NGRAPH, 256, 0, stream>>>(g, l1w, l1b, l2w, l2b, l3w, l3b, l4w, l4b, outp);
}

// Round 14
// 664.664 us; speedup vs baseline: 3.4805x; 1.0617x over previous
//
#include <hip/hip_runtime.h>

#define N_ATOMS 100000
#define E_ATOMS 200000
#define N_AMINO 10240
#define E_AMINO 20480
#define NGRAPH 512
#define DIN0 40
#define D_E 11
#define HD 20
#define D_AA 8
#define HA 128
#define KS 3
#define TL 7
#define F1 256
#define F2 128
#define F3 64
#define TILE 32

typedef unsigned short u16;
typedef unsigned int u32;
typedef __attribute__((ext_vector_type(8))) short short8;
typedef __attribute__((ext_vector_type(4))) float f32x4;

__device__ __forceinline__ float b2f(u16 u) {
    union { u32 i; float f; } v; v.i = ((u32)u) << 16; return v.f;
}
__device__ __forceinline__ u16 f2b(float f) {
    union { float f; u32 i; } v; v.f = f;
    u32 x = v.i;
    return (u16)((x + (((x >> 16) & 1u) + 0x7fffu)) >> 16);
}

// ---------------------------------------------------------------------------
// prep0: M matrices + aa feature columns + zero CSR count arrays.
__global__ __launch_bounds__(256) void k_prep0(
    const float* __restrict__ w1, const float* __restrict__ b1,
    const float* __restrict__ w2, const float* __restrict__ b2,
    const float* __restrict__ w3, const float* __restrict__ b3,
    float* __restrict__ M1, float* __restrict__ M2, float* __restrict__ M3,
    const float* __restrict__ af, float* __restrict__ aa,
    int* __restrict__ cs, int* __restrict__ cd,
    int* __restrict__ ca, int* __restrict__ cl) {
    int t = blockIdx.x * 256 + threadIdx.x;
    if (t < 9600) {
        int i = t / 240, c = t % 240;
        M1[t] = (c < 220) ? w1[(c / 20) * 800 + i * 20 + (c % 20)] : b1[i * 20 + (c - 220)];
    } else if (t < 14400) {
        int tt = t - 9600, i = tt / 240, c = tt % 240;
        M2[tt] = (c < 220) ? w2[(c / 20) * 400 + i * 20 + (c % 20)] : b2[i * 20 + (c - 220)];
    } else if (t < 19200) {
        int tt = t - 14400, i = tt / 240, c = tt % 240;
        M3[tt] = (c < 220) ? w3[(c / 20) * 400 + i * 20 + (c % 20)] : b3[i * 20 + (c - 220)];
    } else if (t < 19200 + N_AMINO * D_AA) {
        int idx = t - 19200, m = idx / D_AA, j = idx % D_AA;
        aa[m * 28 + HD + j] = af[idx];
    } else {
        int z = t - 19200 - N_AMINO * D_AA;
        if (z < N_ATOMS) cs[z] = 0;
        else if (z < 2 * N_ATOMS) cd[z - N_ATOMS] = 0;
        else if (z < 2 * N_ATOMS + N_AMINO) ca[z - 2 * N_ATOMS] = 0;
        else if (z < 2 * N_ATOMS + 2 * N_AMINO) cl[z - 2 * N_ATOMS - N_AMINO] = 0;
    }
}
#define PREP0_N (19200 + N_AMINO * D_AA + 2 * N_ATOMS + 2 * N_AMINO)

// Pack arma_w (18 matrices 128x128 fp32) into MFMA B-fragment order, bf16:
// Wp[mat][(kb*128 + c)*32 + q*8 + j] = W[mat][kb*32 + q*8 + j][c]
__global__ __launch_bounds__(256) void k_cvtwp(const float* __restrict__ aw,
                                               u16* __restrict__ Wp) {
    int g = blockIdx.x * 256 + threadIdx.x;
    if (g >= (TL - 1) * KS * 16384) return;
    int mat = g >> 14, r = g & 16383;
    int kb = r >> 12, rem = r & 4095;
    int c = rem >> 5, qj = rem & 31;
    Wp[g] = f2b(aw[(size_t)mat * 16384 + (size_t)(kb * 32 + qj) * HA + c]);
}

// ---------------------------------------------------------------------------
// CSR builds: src(atom), dst(atom->slot), amino(dst), label(atom)
#define NBS 98
#define NBA 10

__global__ __launch_bounds__(256) void k_csr_count(
    const int* __restrict__ esrc, const int* __restrict__ edst,
    const int* __restrict__ adst, const int* __restrict__ lbl,
    int* __restrict__ cs, int* __restrict__ cd,
    int* __restrict__ ca, int* __restrict__ cl) {
    int t = blockIdx.x * 256 + threadIdx.x;
    if (t < E_ATOMS) atomicAdd(cs + esrc[t], 1);
    else if (t < 2 * E_ATOMS) atomicAdd(cd + edst[t - E_ATOMS], 1);
    else if (t < 2 * E_ATOMS + E_AMINO) atomicAdd(ca + adst[t - 2 * E_ATOMS], 1);
    else if (t < 2 * E_ATOMS + E_AMINO + N_ATOMS) atomicAdd(cl + lbl[t - 2 * E_ATOMS - E_AMINO], 1);
}
__device__ __forceinline__ void seg_decode(int bx, int* blk, int* n, int* which) {
    if (bx < NBS)            { *which = 0; *blk = bx;             *n = N_ATOMS; }
    else if (bx < 2 * NBS)   { *which = 1; *blk = bx - NBS;       *n = N_ATOMS; }
    else if (bx < 2 * NBS + NBA) { *which = 2; *blk = bx - 2 * NBS; *n = N_AMINO; }
    else                     { *which = 3; *blk = bx - 2 * NBS - NBA; *n = N_AMINO; }
}
__global__ __launch_bounds__(256) void k_scan1(
    const int* __restrict__ cs, int* __restrict__ soff,
    const int* __restrict__ cd, int* __restrict__ doff,
    const int* __restrict__ ca, int* __restrict__ aoff,
    const int* __restrict__ cl, int* __restrict__ loff,
    int* __restrict__ bsum) {
    int blk, n, which;
    seg_decode(blockIdx.x, &blk, &n, &which);
    const int* c = which == 0 ? cs : which == 1 ? cd : which == 2 ? ca : cl;
    int* o = which == 0 ? soff : which == 1 ? doff : which == 2 ? aoff : loff;
    int tx = threadIdx.x, lane = tx & 63, w = tx >> 6;
    int i0 = blk * 1024 + tx * 4;
    int v[4];
#pragma unroll
    for (int q = 0; q < 4; ++q) v[q] = (i0 + q < n) ? c[i0 + q] : 0;
    int s = v[0] + v[1] + v[2] + v[3];
    int inc = s;
#pragma unroll
    for (int d = 1; d < 64; d <<= 1) {
        int u = __shfl_up(inc, d, 64);
        if (lane >= d) inc += u;
    }
    __shared__ int wsum[4];
    if (lane == 63) wsum[w] = inc;
    __syncthreads();
    int wo = 0;
    for (int i = 0; i < w; ++i) wo += wsum[i];
    int run = wo + inc - s;
#pragma unroll
    for (int q = 0; q < 4; ++q) {
        if (i0 + q < n) o[i0 + q] = run;
        run += v[q];
    }
    if (tx == 255) bsum[blockIdx.x] = wo + inc;
}
__global__ __launch_bounds__(128) void k_scan2(
    int* __restrict__ bsum, int* __restrict__ soff, int* __restrict__ doff,
    int* __restrict__ aoff, int* __restrict__ loff) {
    int bx = blockIdx.x;
    int nb   = (bx < 2) ? NBS : NBA;
    int base = (bx == 0) ? 0 : (bx == 1) ? NBS : (bx == 2) ? 2 * NBS : 2 * NBS + NBA;
    int* b = bsum + base;
    int tx = threadIdx.x, lane = tx & 63;
    int v = (tx < nb) ? b[tx] : 0;
    int inc = v;
#pragma unroll
    for (int d = 1; d < 64; d <<= 1) {
        int u = __shfl_up(inc, d, 64);
        if (lane >= d) inc += u;
    }
    __shared__ int w0;
    if (tx == 63) w0 = inc;
    __syncthreads();
    int excl = inc - v + ((tx >= 64) ? w0 : 0);
    if (tx < nb) b[tx] = excl;
    if (tx == nb - 1) {
        int tot = excl + v;
        if (bx == 0) soff[N_ATOMS] = tot;
        else if (bx == 1) doff[N_ATOMS] = tot;
        else if (bx == 2) aoff[N_AMINO] = tot;
        else loff[N_AMINO] = tot;
    }
}
__global__ __launch_bounds__(256) void k_scan3(
    int* __restrict__ soff, int* __restrict__ doff,
    int* __restrict__ aoff, int* __restrict__ loff,
    const int* __restrict__ bsum,
    int* __restrict__ us, int* __restrict__ ud,
    int* __restrict__ ua, int* __restrict__ ul) {
    int blk, n, which;
    seg_decode(blockIdx.x, &blk, &n, &which);
    int* o = which == 0 ? soff : which == 1 ? doff : which == 2 ? aoff : loff;
    int* cu = which == 0 ? us : which == 1 ? ud : which == 2 ? ua : ul;
    int add = bsum[blockIdx.x];
    int i0 = blk * 1024 + threadIdx.x * 4;
#pragma unroll
    for (int q = 0; q < 4; ++q)
        if (i0 + q < n) { int val = o[i0 + q] + add; o[i0 + q] = val; cu[i0 + q] = val; }
}
__global__ __launch_bounds__(256) void k_csr_fill(
    const int* __restrict__ esrc, const int* __restrict__ edst,
    const float* __restrict__ ea,
    int* __restrict__ us, int* __restrict__ srcP, float* __restrict__ eaP,
    int* __restrict__ ud, int* __restrict__ dslot,
    const int* __restrict__ aei, int* __restrict__ ua, int* __restrict__ aeid,
    const int* __restrict__ aoff, float* __restrict__ nrm,
    const int* __restrict__ lbl, int* __restrict__ ul, int* __restrict__ lnid) {
    int t = blockIdx.x * 256 + threadIdx.x;
    if (t < E_ATOMS) {
        int jj = atomicAdd(us + esrc[t], 1);
        srcP[jj] = esrc[t];
        const float* e0 = ea + (size_t)t * D_E;
        float* e1 = eaP + (size_t)jj * D_E;
#pragma unroll
        for (int k = 0; k < D_E; ++k) e1[k] = e0[k];
        int p = atomicAdd(ud + edst[t], 1);
        dslot[p] = jj;
    } else if (t < E_ATOMS + E_AMINO) {
        int e = t - E_ATOMS;
        int p = atomicAdd(ua + aei[E_AMINO + e], 1);
        aeid[p] = e;
    } else if (t < E_ATOMS + 2 * E_AMINO) {
        int e = t - E_ATOMS - E_AMINO;
        int s = aei[e], d = aei[E_AMINO + e];
        int ds = aoff[s + 1] - aoff[s], dd = aoff[d + 1] - aoff[d];
        float a = ds > 0 ? rsqrtf((float)ds) : 0.f;
        float b = dd > 0 ? rsqrtf((float)dd) : 0.f;
        nrm[e] = a * b;
    } else if (t < E_ATOMS + 2 * E_AMINO + N_ATOMS) {
        int n = t - E_ATOMS - 2 * E_AMINO;
        int p = atomicAdd(ul + lbl[n], 1);
        lnid[p] = n;
    }
}

// ---------------------------------------------------------------------------
// NNConv edge: 32-node tiles, permuted srcP/eaP, bf16 msg, no atomics.
template <int DIN, bool RAW>
__global__ __launch_bounds__(256) void nnconv_edge3(
    const void* __restrict__ xin, const float* __restrict__ eaP,
    const int* __restrict__ srcP, const int* __restrict__ soff,
    const float* __restrict__ Mg, u16* __restrict__ msg) {
    __shared__ float y[TILE * 240];
    int tx = threadIdx.x;
    int n0 = blockIdx.x * TILE;
    int nT = min(TILE, N_ATOMS - n0);
    if (tx < 240) {
        float m[DIN];
#pragma unroll
        for (int i = 0; i < DIN; ++i) m[i] = Mg[i * 240 + tx];
        for (int nl = 0; nl < nT; ++nl) {
            const float* xf = (const float*)xin + (size_t)(n0 + nl) * DIN;
            const u16*   xb = (const u16*)xin + (size_t)(n0 + nl) * DIN;
            float acc = 0.f;
#pragma unroll
            for (int i = 0; i < DIN; ++i)
                acc += (RAW ? xf[i] : b2f(xb[i])) * m[i];
            y[nl * 240 + tx] = acc;
        }
    }
    __syncthreads();
    int j0 = soff[n0], j1 = soff[n0 + nT];
    if (tx < 240) {
        int o = tx % 20, grp = tx / 20;
        for (int jj = j0 + grp; jj < j1; jj += 12) {
            int sl = srcP[jj] - n0;
            const float* er = eaP + (size_t)jj * D_E;
            float mv = y[sl * 240 + 220 + o];
#pragma unroll
            for (int k = 0; k < D_E; ++k) mv += er[k] * y[sl * 240 + k * HD + o];
            msg[(size_t)jj * 20 + o] = f2b(mv);
        }
    }
}

// NNConv reduce: per (n,o) gather msg via dst->slot CSR + root+bias+relu.
template <int DIN, bool RAW>
__global__ __launch_bounds__(256) void nnconv_reduce(
    const void* __restrict__ xin, const float* __restrict__ root,
    const float* __restrict__ bias, const int* __restrict__ doff,
    const int* __restrict__ dslot, const u16* __restrict__ msg,
    u16* __restrict__ hout) {
    __shared__ float Rl[DIN * HD + HD];
    for (int t = threadIdx.x; t < DIN * HD; t += 256) Rl[t] = root[t];
    if (threadIdx.x < HD) Rl[DIN * HD + threadIdx.x] = bias[threadIdx.x];
    __syncthreads();
    int t = blockIdx.x * 256 + threadIdx.x;
    if (t >= N_ATOMS * HD) return;
    int n = t / HD, o = t % HD;
    float acc = Rl[DIN * HD + o];
    int j1 = doff[n + 1];
    for (int j = doff[n]; j < j1; ++j)
        acc += b2f(msg[(size_t)dslot[j] * 20 + o]);
    const float* xf = (const float*)xin + (size_t)n * DIN;
    const u16*   xb = (const u16*)xin + (size_t)n * DIN;
#pragma unroll
    for (int i = 0; i < DIN; ++i)
        acc += (RAW ? xf[i] : b2f(xb[i])) * Rl[i * HD + o];
    hout[t] = f2b(fmaxf(acc, 0.f));
}

// aa gather: label-CSR segmented sum of h3
__global__ __launch_bounds__(256) void aa_gather(
    const u16* __restrict__ h3, const int* __restrict__ loff,
    const int* __restrict__ lnid, float* __restrict__ aa) {
    int t = blockIdx.x * 256 + threadIdx.x;
    if (t >= N_AMINO * HD) return;
    int m = t / HD, o = t % HD;
    float s = 0.f;
    int j1 = loff[m + 1];
    for (int j = loff[m]; j < j1; ++j)
        s += b2f(h3[(size_t)lnid[j] * HD + o]);
    aa[m * 28 + o] = s;
}

// ---------------------------------------------------------------------------
// ARMA gemm28: H = aa @ W[k] (fp32 VALU), W + aa-tile in LDS.
__global__ __launch_bounds__(256) void arma_gemm28(
    const float* __restrict__ A, const float* __restrict__ W, size_t wstride,
    float* __restrict__ H, size_t hstride) {
    __shared__ float Wl[28 * 128];
    __shared__ float Aas[16][28];
    int tx = threadIdx.x;
    const float* Wk = W + blockIdx.y * wstride;
    int n0 = blockIdx.x * 16;
    for (int i = tx; i < 28 * 128; i += 256) Wl[i] = Wk[i];
    for (int i = tx; i < 16 * 28; i += 256)
        Aas[i / 28][i % 28] = A[(size_t)(n0 + i / 28) * 28 + i % 28];
    __syncthreads();
    int nl = tx >> 4, c0 = (tx & 15) * 8;
    float* Hk = H + blockIdx.y * hstride;
    float acc[8];
#pragma unroll
    for (int j = 0; j < 8; ++j) acc[j] = 0.f;
    for (int f = 0; f < 28; ++f) {
        float av = Aas[nl][f];
        const float* wr = &Wl[f * 128 + c0];
        float4 w0 = *(const float4*)wr, w1 = *(const float4*)(wr + 4);
        acc[0] += av * w0.x; acc[1] += av * w0.y; acc[2] += av * w0.z; acc[3] += av * w0.w;
        acc[4] += av * w1.x; acc[5] += av * w1.y; acc[6] += av * w1.z; acc[7] += av * w1.w;
    }
    float* hp = Hk + (size_t)(n0 + nl) * HA + c0;
    *(float4*)hp       = make_float4(acc[0], acc[1], acc[2], acc[3]);
    *(float4*)(hp + 4) = make_float4(acc[4], acc[5], acc[6], acc[7]);
}

// ARMA gemm via MFMA bf16: H[n,c] = sum_f O_bf16[n,f] * Wp_bf16[f,c].
// Wave = 16-row strip x 128 cols; layouts per m89/m91/m120:
//   A[m=lane&15][k=quad*8+j]; B[k=quad*8+j][n=lane&15]; D col=lane&15,row=quad*4+reg.
__global__ __launch_bounds__(256) void arma_gemm_mf(
    const u16* __restrict__ Obh, size_t astride,
    const u16* __restrict__ Wp,
    float* __restrict__ H, size_t hstride) {
    int wave = threadIdx.x >> 6, lane = threadIdx.x & 63;
    int k = blockIdx.y;
    const u16* A = Obh + (size_t)k * astride;
    const u16* W = Wp + (size_t)k * 16384;
    float* Hk = H + (size_t)k * hstride;
    int n0 = (blockIdx.x * 4 + wave) * 16;
    int m = lane & 15, q = lane >> 4;
    short8 aF[4];
#pragma unroll
    for (int kb = 0; kb < 4; ++kb)
        aF[kb] = *(const short8*)(A + (size_t)(n0 + m) * HA + kb * 32 + q * 8);
#pragma unroll
    for (int ct = 0; ct < 8; ++ct) {
        int c0 = ct * 16;
        f32x4 acc = {0.f, 0.f, 0.f, 0.f};
#pragma unroll
        for (int kb = 0; kb < 4; ++kb) {
            short8 bF = *(const short8*)(W + (size_t)((kb * 128 + c0 + m) * 32 + q * 8));
            acc = __builtin_amdgcn_mfma_f32_16x16x32_bf16(aF[kb], bF, acc, 0, 0, 0);
        }
#pragma unroll
        for (int r = 0; r < 4; ++r)
            Hk[(size_t)(n0 + q * 4 + r) * HA + c0 + m] = acc[r];
    }
}

// ARMA out: gather + root-gemm (LDS-staged) + relu; O written bf16.
__global__ __launch_bounds__(256) void arma_out(
    const float* __restrict__ H, size_t hstride,
    const float* __restrict__ aa,
    const float* __restrict__ rw, size_t rstride,
    const float* __restrict__ bw, size_t bstride,
    const int* __restrict__ aei, const int* __restrict__ aoff,
    const int* __restrict__ aeid, const float* __restrict__ nrm,
    u16* __restrict__ O, size_t ostride) {
    __shared__ float Rw[28 * 128];
    __shared__ float Bw[128];
    __shared__ float Aas[16][28];
    int tx = threadIdx.x;
    const float* rwk = rw + blockIdx.y * rstride;
    const float* bwk = bw + blockIdx.y * bstride;
    int n0 = blockIdx.x * 16;
    for (int i = tx; i < 28 * 128; i += 256) Rw[i] = rwk[i];
    if (tx < 128) Bw[tx] = bwk[tx];
    for (int i = tx; i < 16 * 28; i += 256)
        Aas[i / 28][i % 28] = aa[(size_t)(n0 + i / 28) * 28 + i % 28];
    __syncthreads();
    int nl = tx >> 4, c0 = (tx & 15) * 8;
    int n = n0 + nl;
    const float* Hk = H + blockIdx.y * hstride;
    u16* Ok = O + blockIdx.y * ostride;
    float acc[8];
#pragma unroll
    for (int j = 0; j < 8; ++j) acc[j] = Bw[c0 + j];
    int j1 = aoff[n + 1];
    for (int jj = aoff[n]; jj < j1; ++jj) {
        int e = aeid[jj], s = aei[e];
        float nm = nrm[e];
        const float* hr = Hk + (size_t)s * HA + c0;
#pragma unroll
        for (int j = 0; j < 8; ++j) acc[j] += nm * hr[j];
    }
    for (int f = 0; f < 28; ++f) {
        float av = Aas[nl][f];
        const float* wr = &Rw[f * 128 + c0];
        float4 w0 = *(const float4*)wr, w1 = *(const float4*)(wr + 4);
        acc[0] += av * w0.x; acc[1] += av * w0.y; acc[2] += av * w0.z; acc[3] += av * w0.w;
        acc[4] += av * w1.x; acc[5] += av * w1.y; acc[6] += av * w1.z; acc[7] += av * w1.w;
    }
#pragma unroll
    for (int j = 0; j < 8; ++j) acc[j] = fmaxf(acc[j], 0.f);
    uint4 pk;
    pk.x = (u32)f2b(acc[0]) | ((u32)f2b(acc[1]) << 16);
    pk.y = (u32)f2b(acc[2]) | ((u32)f2b(acc[3]) << 16);
    pk.z = (u32)f2b(acc[4]) | ((u32)f2b(acc[5]) << 16);
    pk.w = (u32)f2b(acc[6]) | ((u32)f2b(acc[7]) << 16);
    *(uint4*)(Ok + (size_t)n * HA + c0) = pk;
}

// ---------------------------------------------------------------------------
// head2: fused readout (sorted amino_batch segmented sum over bf16 O) + MLP.
__global__ __launch_bounds__(256) void head2(
    const u16* __restrict__ O, size_t kstride, const int* __restrict__ bat,
    const float* __restrict__ l1w, const float* __restrict__ l1b,
    const float* __restrict__ l2w, const float* __restrict__ l2b,
    const float* __restrict__ l3w, const float* __restrict__ l3b,
    const float* __restrict__ l4w, const float* __restrict__ l4b,
    float* __restrict__ outp) {
    __shared__ float sg[HA], sp1[F1], sp2[F2], sp3[F3];
    int b = blockIdx.x, tx = threadIdx.x;
    int lo = 0, hi = N_AMINO;
    while (lo < hi) { int mid = (lo + hi) >> 1; if (bat[mid] < b) lo = mid + 1; else hi = mid; }
    int s = lo;
    lo = 0; hi = N_AMINO;
    while (lo < hi) { int mid = (lo + hi) >> 1; if (bat[mid] < b + 1) lo = mid + 1; else hi = mid; }
    int e = lo;
    if (tx < HA) {
        float acc = 0.f;
        for (int n = s; n < e; ++n)
            acc += b2f(O[(size_t)n * HA + tx]) + b2f(O[kstride + (size_t)n * HA + tx])
                 + b2f(O[2 * kstride + (size_t)n * HA + tx]);
        sg[tx] = acc * (1.f / 3.f);
    }
    __syncthreads();
    {   float acc = l1b[tx];
        for (int f = 0; f < HA; ++f) acc += sg[f] * l1w[f * F1 + tx];
        sp1[tx] = fmaxf(acc, 0.f); }
    __syncthreads();
    if (tx < F2) {
        float acc = l2b[tx];
        for (int f = 0; f < F1; ++f) acc += sp1[f] * l2w[f * F2 + tx];
        sp2[tx] = fmaxf(acc, 0.f); }
    __syncthreads();
    if (tx < F3) {
        float acc = l3b[tx];
        for (int f = 0; f < F2; ++f) acc += sp2[f] * l3w[f * F3 + tx];
        sp3[tx] = fmaxf(acc, 0.f); }
    __syncthreads();
    if (tx < 64) {
        float p = sp3[tx] * l4w[tx];
        for (int off = 32; off > 0; off >>= 1) p += __shfl_down(p, off, 64);
        if (tx == 0) outp[b] = p + l4b[0];
    }
}

// ---------------------------------------------------------------------------
// Workspace (<= 34,348,288 B, proven available).
#define OFF_M1    ((size_t)0)
#define OFF_M2    ((size_t)38400)
#define OFF_M3    ((size_t)57600)
#define OFF_AOFF  ((size_t)76800)
#define OFF_AEID  ((size_t)118016)
#define OFF_NRM   ((size_t)199936)
#define OFF_AA    ((size_t)281856)
#define OFF_G     ((size_t)1428736)
#define OFF_HA    ((size_t)2891008)
#define OFF_HB    ((size_t)6891008)
#define OFF_MSG   ((size_t)10891008)
#define OFF_SOFF  ((size_t)18891008)
#define OFF_DOFF  ((size_t)19291136)
#define OFF_DSLOT ((size_t)19691264)
#define OFF_LOFF  ((size_t)20491264)
#define OFF_LNID  ((size_t)20532480)
#define OFF_CS    ((size_t)20932480)
#define OFF_CD    ((size_t)21332480)
#define OFF_CA    ((size_t)21732480)
#define OFF_CL    ((size_t)21773440)
#define OFF_US    ((size_t)21814400)
#define OFF_UD    ((size_t)22214400)
#define OFF_UA    ((size_t)22614400)
#define OFF_UL    ((size_t)22655360)
#define OFF_BSUM  ((size_t)22696320)
#define OFF_EAP   ((size_t)22697216)   // 8,800,000 -> 31,497,216
#define OFF_SRCP  ((size_t)31497216)   //   800,000 -> 32,297,216
#define OFF_WP    ((size_t)32297216)   //   589,824 -> 32,887,040 (persists; no overlap)
// ARMA overlay: H fp32 2,891,008..18,619,648; O bf16 18,619,648..26,483,968.
#define OFF_ARH   ((size_t)2891008)
#define OFF_ARO   ((size_t)18619648)

extern "C" void kernel_launch(void* const* d_in, const int* in_sizes, int n_in,
                              void* d_out, int out_size, void* d_ws, size_t ws_size,
                              hipStream_t stream) {
    (void)in_sizes; (void)n_in; (void)out_size; (void)ws_size;
    const float* x   = (const float*)d_in[0];
    const int*   ei  = (const int*)d_in[1];
    const float* ea  = (const float*)d_in[2];
    const int*   lbl = (const int*)d_in[3];
    const float* af  = (const float*)d_in[4];
    const int*   aei = (const int*)d_in[5];
    const int*   bat = (const int*)d_in[6];
    const float* nn1w = (const float*)d_in[7];  const float* nn1b = (const float*)d_in[8];
    const float* rt1  = (const float*)d_in[9];  const float* b1   = (const float*)d_in[10];
    const float* nn2w = (const float*)d_in[11]; const float* nn2b = (const float*)d_in[12];
    const float* rt2  = (const float*)d_in[13]; const float* b2   = (const float*)d_in[14];
    const float* nn3w = (const float*)d_in[15]; const float* nn3b = (const float*)d_in[16];
    const float* rt3  = (const float*)d_in[17]; const float* b3   = (const float*)d_in[18];
    const float* ai   = (const float*)d_in[19]; const float* aw   = (const float*)d_in[20];
    const float* arw  = (const float*)d_in[21]; const float* abi  = (const float*)d_in[22];
    const float* l1w  = (const float*)d_in[23]; const float* l1b  = (const float*)d_in[24];
    const float* l2w  = (const float*)d_in[25]; const float* l2b  = (const float*)d_in[26];
    const float* l3w  = (const float*)d_in[27]; const float* l3b  = (const float*)d_in[28];
    const float* l4w  = (const float*)d_in[29]; const float* l4b  = (const float*)d_in[30];
    float* outp = (float*)d_out;

    char* ws = (char*)d_ws;
    float* M1    = (float*)(ws + OFF_M1);
    float* M2    = (float*)(ws + OFF_M2);
    float* M3    = (float*)(ws + OFF_M3);
    int*   aoff  = (int*)(ws + OFF_AOFF);
    int*   aeid  = (int*)(ws + OFF_AEID);
    float* nrm   = (float*)(ws + OFF_NRM);
    float* aa    = (float*)(ws + OFF_AA);
    u16*   hA    = (u16*)(ws + OFF_HA);
    u16*   hB    = (u16*)(ws + OFF_HB);
    u16*   msg   = (u16*)(ws + OFF_MSG);
    int*   soff  = (int*)(ws + OFF_SOFF);
    int*   doff  = (int*)(ws + OFF_DOFF);
    int*   dslot = (int*)(ws + OFF_DSLOT);
    int*   loff  = (int*)(ws + OFF_LOFF);
    int*   lnid  = (int*)(ws + OFF_LNID);
    int*   cs    = (int*)(ws + OFF_CS);
    int*   cd    = (int*)(ws + OFF_CD);
    int*   ca    = (int*)(ws + OFF_CA);
    int*   cl    = (int*)(ws + OFF_CL);
    int*   us    = (int*)(ws + OFF_US);
    int*   ud    = (int*)(ws + OFF_UD);
    int*   ua    = (int*)(ws + OFF_UA);
    int*   ul    = (int*)(ws + OFF_UL);
    int*   bsum  = (int*)(ws + OFF_BSUM);
    float* eaP   = (float*)(ws + OFF_EAP);
    int*   srcP  = (int*)(ws + OFF_SRCP);
    u16*   Wp    = (u16*)(ws + OFF_WP);
    float* Hb    = (float*)(ws + OFF_ARH);
    u16*   Obh   = (u16*)(ws + OFF_ARO);

    const int* esrc = ei;
    const int* edst = ei + E_ATOMS;
    const int* adst = aei + E_AMINO;

    // prep
    k_prep0<<<(PREP0_N + 255) / 256, 256, 0, stream>>>(
        nn1w, nn1b, nn2w, nn2b, nn3w, nn3b, M1, M2, M3, af, aa, cs, cd, ca, cl);
    k_cvtwp<<<((TL - 1) * KS * 16384 + 255) / 256, 256, 0, stream>>>(aw, Wp);
    k_csr_count<<<(2 * E_ATOMS + E_AMINO + N_ATOMS + 255) / 256, 256, 0, stream>>>(
        esrc, edst, adst, lbl, cs, cd, ca, cl);
    k_scan1<<<2 * NBS + 2 * NBA, 256, 0, stream>>>(cs, soff, cd, doff, ca, aoff, cl, loff, bsum);
    k_scan2<<<4, 128, 0, stream>>>(bsum, soff, doff, aoff, loff);
    k_scan3<<<2 * NBS + 2 * NBA, 256, 0, stream>>>(soff, doff, aoff, loff, bsum, us, ud, ua, ul);
    k_csr_fill<<<(E_ATOMS + 2 * E_AMINO + N_ATOMS + 255) / 256, 256, 0, stream>>>(
        esrc, edst, ea, us, srcP, eaP, ud, dslot, aei, ua, aeid, aoff, nrm, lbl, ul, lnid);

    // NNConv
    const int GT = (N_ATOMS + TILE - 1) / TILE;   // 3125
    const int GF = (N_ATOMS * HD + 255) / 256;    // 7813
    nnconv_edge3<DIN0, true ><<<GT, 256, 0, stream>>>(x,  eaP, srcP, soff, M1, msg);
    nnconv_reduce<DIN0, true ><<<GF, 256, 0, stream>>>(x,  rt1, b1, doff, dslot, msg, hA);
    nnconv_edge3<HD,   false><<<GT, 256, 0, stream>>>(hA, eaP, srcP, soff, M2, msg);
    nnconv_reduce<HD,   false><<<GF, 256, 0, stream>>>(hA, rt2, b2, doff, dslot, msg, hB);
    nnconv_edge3<HD,   false><<<GT, 256, 0, stream>>>(hB, eaP, srcP, soff, M3, msg);
    nnconv_reduce<HD,   false><<<GF, 256, 0, stream>>>(hB, rt3, b3, doff, dslot, msg, hA);
    aa_gather<<<(N_AMINO * HD + 255) / 256, 256, 0, stream>>>(hA, loff, lnid, aa);

    // ARMA: K-parallel, T layers; gemm via MFMA (t>=1)
    const size_t KH = (size_t)N_AMINO * HA;
    for (int t = 0; t < TL; ++t) {
        if (t == 0)
            arma_gemm28<<<dim3(640, KS), 256, 0, stream>>>(aa, ai, 28 * HA, Hb, KH);
        else
            arma_gemm_mf<<<dim3(160, KS), 256, 0, stream>>>(
                Obh, KH, Wp + (size_t)(t - 1) * KS * 16384, Hb, KH);
        arma_out<<<dim3(640, KS), 256, 0, stream>>>(
            Hb, KH, aa, arw + (size_t)t * KS * 28 * HA, 28 * HA,
            abi + (size_t)t * KS * HA, HA, aei, aoff, aeid, nrm, Obh, KH);
    }

    head2<<<NGRAPH, 256, 0, stream>>>(Obh, KH, bat, l1w, l1b, l2w, l2b,
                                      l3w, l3b, l4w, l4b, outp);
}